// Round 2
// baseline (793.207 us; speedup 1.0000x reference)
//
#include <hip/hip_runtime.h>
#include <hip/hip_bf16.h>

// GRN_GAT_Encoder: 2-layer edge-featured GAT + projection head.
// Round 1: ALL float tensors are fp32 (reference is jnp.float32; the "bf16" in
// the harness error label is a hardcoded f-string, not a dtype signal).
// Round-0 NaN root cause: read fp32 as bf16 -> random NaN bit patterns.
// Algebraic trick: (ea@We * ae).sum(-1) == ea @ v where v[f,h]=sum_c We[f,h*C+c]*ae[h,c]
// -> kills the 21 GF he-GEMM. Aggregation via device-built dst-CSR, no atomics in hot path.

#define NN    20000
#define EE    320000
#define E2    640000
#define FIN   256
#define FE    32
#define HIDD  128
#define NHEAD 4
#define HH    512   // NHEAD*HIDD

__device__ inline float wave_max(float v){
  #pragma unroll
  for(int o=32;o>0;o>>=1) v = fmaxf(v, __shfl_xor(v, o, 64));
  return v;
}
__device__ inline float wave_sum(float v){
  #pragma unroll
  for(int o=32;o>0;o>>=1) v += __shfl_xor(v, o, 64);
  return v;
}

// ---------------- CSR build ----------------

__global__ void count_edges(const int* __restrict__ ei, int* __restrict__ cnt){
  int e = blockIdx.x*256 + threadIdx.x;            // grid is exactly E2/256
  int dst = (e < EE) ? ei[EE + e] : ei[e - EE];    // fwd: dst=row1; rev: dst=row0
  atomicAdd(&cnt[dst], 1);
}

__global__ void scan_k(const int* __restrict__ cnt, int* __restrict__ rowptr){
  __shared__ int sums[1024];
  int tid = threadIdx.x;
  const int per = (NN + 1023)/1024;  // 20
  int base = tid*per;
  int s = 0;
  for(int i=0;i<per;i++){ int idx=base+i; if(idx<NN) s += cnt[idx]; }
  sums[tid] = s; __syncthreads();
  for(int off=1; off<1024; off<<=1){
    int v = (tid>=off)? sums[tid-off] : 0;
    __syncthreads();
    sums[tid] += v;
    __syncthreads();
  }
  int run = (tid==0)? 0 : sums[tid-1];
  for(int i=0;i<per;i++){
    int idx = base+i;
    if(idx<=NN) rowptr[idx] = run;
    if(idx<NN)  run += cnt[idx];
  }
}

// v1[f,h] = sum_c We1[f, h*128+c]*ae1[h,c];  v2[f] = sum_c We2[f,c]*ae2[c]
__global__ void compute_v(const float* __restrict__ We1, const float* __restrict__ ae1,
                          const float* __restrict__ We2, const float* __restrict__ ae2,
                          float* __restrict__ v1, float* __restrict__ v2){
  int tid = threadIdx.x;
  if(tid < FE*NHEAD){
    int f = tid>>2, h = tid&3;
    float s = 0.f;
    for(int c=0;c<HIDD;c++) s += We1[f*HH + h*HIDD + c] * ae1[h*HIDD + c];
    v1[f*4+h] = s;
  } else if(tid < FE*NHEAD + FE){
    int f = tid - FE*NHEAD;
    float s = 0.f;
    for(int c=0;c<HIDD;c++) s += We2[f*HIDD + c] * ae2[c];
    v2[f] = s;
  }
}

__global__ void csr_fill(const int* __restrict__ ei, const float* __restrict__ ea,
                         const float* __restrict__ v1, const float* __restrict__ v2,
                         const int* __restrict__ rowptr, int* __restrict__ fcnt,
                         int* __restrict__ csrc, float* __restrict__ cae1, float* __restrict__ cae2){
  __shared__ float sv1[FE*NHEAD];
  __shared__ float sv2[FE];
  int tid = threadIdx.x;
  if(tid < FE*NHEAD) sv1[tid] = v1[tid];
  if(tid < FE)       sv2[tid] = v2[tid];
  __syncthreads();
  int e = blockIdx.x*256 + tid;                    // grid exactly E2/256
  int src, dst, row;
  if(e < EE){ src = ei[e];       dst = ei[EE+e]; row = e; }
  else      { int e0=e-EE; src = ei[EE+e0]; dst = ei[e0]; row = e0; }
  const float* er = ea + (long)row*FE;
  float a0=0,a1=0,a2=0,a3=0,ab=0;
  #pragma unroll
  for(int f=0; f<FE; f++){
    float t = er[f];
    a0 += t*sv1[f*4+0]; a1 += t*sv1[f*4+1]; a2 += t*sv1[f*4+2]; a3 += t*sv1[f*4+3];
    ab += t*sv2[f];
  }
  int pos = rowptr[dst] + atomicAdd(&fcnt[dst], 1);
  csrc[pos] = src;
  cae1[pos*4+0]=a0; cae1[pos*4+1]=a1; cae1[pos*4+2]=a2; cae1[pos*4+3]=a3;
  cae2[pos] = ab;
}

// ---------------- generic tiled GEMM (fp32) ----------------
// C[M,N] = A[M,K] @ B[K,N]; N%64==0, K%16==0 required; M guarded.
// epi: 0 none; 1 bias+PReLU; 2 bias only.
__global__ __launch_bounds__(256) void gemm_tile(const float* __restrict__ A, const float* __restrict__ B,
                                                 float* __restrict__ C, int M, int N, int K,
                                                 const float* __restrict__ bias,
                                                 const float* __restrict__ prelu_a, int epi){
  __shared__ float As[16][64];
  __shared__ float Bs[16][64];
  int tid = threadIdx.x;
  int m0 = blockIdx.y*64, n0 = blockIdx.x*64;
  int tm = (tid>>4)<<2, tn = (tid&15)<<2;
  float acc[4][4] = {};
  for(int k0=0; k0<K; k0+=16){
    #pragma unroll
    for(int i=0;i<4;i++){
      int idx = tid + i*256;
      int r = idx>>4, c = idx&15;
      int gr = m0 + r;
      As[c][r] = (gr<M)? A[(long)gr*K + k0 + c] : 0.f;
    }
    #pragma unroll
    for(int i=0;i<4;i++){
      int idx = tid + i*256;
      int r = idx>>6, c = idx&63;
      Bs[r][c] = B[(long)(k0+r)*N + n0 + c];
    }
    __syncthreads();
    #pragma unroll
    for(int k=0;k<16;k++){
      float a0=As[k][tm+0],a1=As[k][tm+1],a2=As[k][tm+2],a3=As[k][tm+3];
      float b0=Bs[k][tn+0],b1=Bs[k][tn+1],b2=Bs[k][tn+2],b3=Bs[k][tn+3];
      acc[0][0]+=a0*b0; acc[0][1]+=a0*b1; acc[0][2]+=a0*b2; acc[0][3]+=a0*b3;
      acc[1][0]+=a1*b0; acc[1][1]+=a1*b1; acc[1][2]+=a1*b2; acc[1][3]+=a1*b3;
      acc[2][0]+=a2*b0; acc[2][1]+=a2*b1; acc[2][2]+=a2*b2; acc[2][3]+=a2*b3;
      acc[3][0]+=a3*b0; acc[3][1]+=a3*b1; acc[3][2]+=a3*b2; acc[3][3]+=a3*b3;
    }
    __syncthreads();
  }
  float ap = (epi==1)? prelu_a[0] : 0.f;
  #pragma unroll
  for(int i=0;i<4;i++){
    int gr = m0+tm+i;
    if(gr>=M) continue;
    #pragma unroll
    for(int j=0;j<4;j++){
      int gc = n0+tn+j;
      float v = acc[i][j];
      if(epi>=1) v += bias[gc];
      if(epi==1) v = v>0.f? v : ap*v;
      C[(long)gr*N+gc] = v;
    }
  }
}

// ---------------- per-node attention scalars ----------------

__global__ void node_attn1(const float* __restrict__ h1, const float* __restrict__ as1,
                           const float* __restrict__ ad1, float* __restrict__ s1n, float* __restrict__ d1n){
  int n = blockIdx.x;
  int wv = threadIdx.x>>6, lane = threadIdx.x&63;
  const float* row = h1 + (long)n*HH + wv*HIDD;
  float v0 = row[lane], v1_ = row[64+lane];
  float s = wave_sum(v0*as1[wv*HIDD+lane] + v1_*as1[wv*HIDD+64+lane]);
  float d = wave_sum(v0*ad1[wv*HIDD+lane] + v1_*ad1[wv*HIDD+64+lane]);
  if(lane==0){ s1n[n*4+wv]=s; d1n[n*4+wv]=d; }
}

__global__ void node_attn2(const float* __restrict__ h2, const float* __restrict__ as2,
                           const float* __restrict__ ad2, float* __restrict__ s2n, float* __restrict__ d2n){
  int n = blockIdx.x*4 + (threadIdx.x>>6);
  int lane = threadIdx.x&63;
  const float* row = h2 + (long)n*HIDD;
  float v0 = row[lane], v1_ = row[64+lane];
  float s = wave_sum(v0*as2[lane] + v1_*as2[64+lane]);
  float d = wave_sum(v0*ad2[lane] + v1_*ad2[64+lane]);
  if(lane==0){ s2n[n]=s; d2n[n]=d; }
}

// ---------------- softmax + aggregate (gather over dst-CSR) ----------------

__global__ void agg1(const float* __restrict__ h1, const float* __restrict__ s1n, const float* __restrict__ d1n,
                     const int* __restrict__ rowptr, const int* __restrict__ csrc, const float* __restrict__ cae1,
                     const float* __restrict__ b1, float* __restrict__ out1){
  int n = blockIdx.x;
  int h = threadIdx.x>>6, lane = threadIdx.x&63;
  int beg = rowptr[n], end = rowptr[n+1];
  float dn = d1n[n*4+h];
  float m = -1e30f;
  for(int i=beg+lane; i<end; i+=64){
    float a = s1n[csrc[i]*4+h] + dn + cae1[i*4+h];
    a = a>0.f? a : 0.2f*a;
    m = fmaxf(m, a);
  }
  m = wave_max(m);
  float ss = 0.f;
  for(int i=beg+lane; i<end; i+=64){
    float a = s1n[csrc[i]*4+h] + dn + cae1[i*4+h];
    a = a>0.f? a : 0.2f*a;
    ss += __expf(a-m);
  }
  ss = wave_sum(ss);
  float inv = ss>0.f ? 1.f/ss : 0.f;
  float acc0=0.f, acc1=0.f;
  for(int i=beg; i<end; i++){
    int s = csrc[i];
    float a = s1n[s*4+h] + dn + cae1[i*4+h];
    a = a>0.f? a : 0.2f*a;
    float wgt = __expf(a-m)*inv;
    const float* hr = h1 + (long)s*HH + h*HIDD;
    acc0 += wgt*hr[lane];
    acc1 += wgt*hr[64+lane];
  }
  float o0 = acc0 + b1[h*HIDD+lane];
  float o1 = acc1 + b1[h*HIDD+64+lane];
  out1[(long)n*HH + h*HIDD + lane]      = o0>0.f? o0 : __expf(o0)-1.f;   // ELU
  out1[(long)n*HH + h*HIDD + 64 + lane] = o1>0.f? o1 : __expf(o1)-1.f;
}

__global__ void agg2(const float* __restrict__ h2, const float* __restrict__ s2n, const float* __restrict__ d2n,
                     const int* __restrict__ rowptr, const int* __restrict__ csrc, const float* __restrict__ cae2,
                     const float* __restrict__ b2, float* __restrict__ out2){
  int n = blockIdx.x*4 + (threadIdx.x>>6);
  int lane = threadIdx.x&63;
  int beg = rowptr[n], end = rowptr[n+1];
  float dn = d2n[n];
  float m = -1e30f;
  for(int i=beg+lane; i<end; i+=64){
    float a = s2n[csrc[i]] + dn + cae2[i];
    a = a>0.f? a : 0.2f*a;
    m = fmaxf(m, a);
  }
  m = wave_max(m);
  float ss = 0.f;
  for(int i=beg+lane; i<end; i+=64){
    float a = s2n[csrc[i]] + dn + cae2[i];
    a = a>0.f? a : 0.2f*a;
    ss += __expf(a-m);
  }
  ss = wave_sum(ss);
  float inv = ss>0.f ? 1.f/ss : 0.f;
  float acc0=0.f, acc1=0.f;
  for(int i=beg; i<end; i++){
    int s = csrc[i];
    float a = s2n[s] + dn + cae2[i];
    a = a>0.f? a : 0.2f*a;
    float wgt = __expf(a-m)*inv;
    acc0 += wgt*h2[(long)s*HIDD + lane];
    acc1 += wgt*h2[(long)s*HIDD + 64 + lane];
  }
  float o0 = acc0 + b2[lane];
  float o1 = acc1 + b2[64+lane];
  out2[(long)n*HIDD + lane]      = o0>0.f? o0 : __expf(o0)-1.f;
  out2[(long)n*HIDD + 64 + lane] = o1>0.f? o1 : __expf(o1)-1.f;
}

// ---------------- readout ----------------

__global__ void colsum(const float* __restrict__ hp, float* __restrict__ gbuf){
  int c = threadIdx.x;  // 128 threads
  float acc = 0.f;
  for(int r = blockIdx.x; r < NN; r += gridDim.x) acc += hp[(long)r*HIDD + c];
  atomicAdd(&gbuf[c], acc);
}

__global__ void sigmoid_g(const float* __restrict__ gbuf, float* __restrict__ gout){
  int c = threadIdx.x;
  float m = gbuf[c] * (1.0f/NN);
  gout[c] = 1.f/(1.f+__expf(-m));
}

// ---------------- launch ----------------

extern "C" void kernel_launch(void* const* d_in, const int* in_sizes, int n_in,
                              void* d_out, int out_size, void* d_ws, size_t ws_size,
                              hipStream_t stream){
  const float* x    = (const float*)d_in[0];
  const int*   ei   = (const int*)  d_in[1];
  const float* ea   = (const float*)d_in[2];
  const float* W1   = (const float*)d_in[3];
  const float* We1  = (const float*)d_in[4];
  const float* as1  = (const float*)d_in[5];
  const float* ad1  = (const float*)d_in[6];
  const float* ae1  = (const float*)d_in[7];
  const float* b1   = (const float*)d_in[8];
  const float* W2   = (const float*)d_in[9];
  const float* We2  = (const float*)d_in[10];
  const float* as2  = (const float*)d_in[11];
  const float* ad2  = (const float*)d_in[12];
  const float* ae2  = (const float*)d_in[13];
  const float* b2   = (const float*)d_in[14];
  const float* P1   = (const float*)d_in[15];
  const float* pb1  = (const float*)d_in[16];
  const float* pra  = (const float*)d_in[17];
  const float* P2   = (const float*)d_in[18];
  const float* pb2  = (const float*)d_in[19];
  float* out = (float*)d_out;

  char* wsp = (char*)d_ws;
  size_t off = 0;
  auto alloc = [&](size_t bytes)->char*{
    char* p = wsp + off;
    off += (bytes + 255) & ~(size_t)255;
    return p;
  };
  float* h1    = (float*)alloc(sizeof(float)*(size_t)NN*HH);     // 41 MB
  float* out1  = (float*)alloc(sizeof(float)*(size_t)NN*HH);     // 41 MB
  float* h2    = (float*)alloc(sizeof(float)*(size_t)NN*HIDD);   // 10 MB
  float* out2  = (float*)alloc(sizeof(float)*(size_t)NN*HIDD);   // 10 MB
  float* s1n   = (float*)alloc(sizeof(float)*NN*NHEAD);
  float* d1n   = (float*)alloc(sizeof(float)*NN*NHEAD);
  float* s2n   = (float*)alloc(sizeof(float)*NN);
  float* d2n   = (float*)alloc(sizeof(float)*NN);
  float* v1    = (float*)alloc(sizeof(float)*FE*NHEAD);
  float* v2    = (float*)alloc(sizeof(float)*FE);
  float* gbuf  = (float*)alloc(sizeof(float)*HIDD);
  float* cae1  = (float*)alloc(sizeof(float)*(size_t)E2*NHEAD);  // 10 MB
  float* cae2  = (float*)alloc(sizeof(float)*(size_t)E2);        // 2.6 MB
  int*   rowptr= (int*)  alloc(sizeof(int)*(NN+1));
  int*   cnt   = (int*)  alloc(sizeof(int)*NN);
  int*   fcnt  = (int*)  alloc(sizeof(int)*NN);
  int*   csrc  = (int*)  alloc(sizeof(int)*(size_t)E2);          // 2.6 MB
  float* zb = h1;  // reuse: h1 dead after layer-2 GEMM inputs are built

  hipMemsetAsync(cnt,  0, sizeof(int)*NN, stream);
  hipMemsetAsync(fcnt, 0, sizeof(int)*NN, stream);
  hipMemsetAsync(gbuf, 0, sizeof(float)*HIDD, stream);

  count_edges<<<E2/256, 256, 0, stream>>>(ei, cnt);
  scan_k     <<<1, 1024, 0, stream>>>(cnt, rowptr);
  compute_v  <<<1, 192, 0, stream>>>(We1, ae1, We2, ae2, v1, v2);
  csr_fill   <<<E2/256, 256, 0, stream>>>(ei, ea, v1, v2, rowptr, fcnt, csrc, cae1, cae2);

  // layer 1
  gemm_tile<<<dim3(HH/64, (NN+63)/64), 256, 0, stream>>>(x, W1, h1, NN, HH, FIN, nullptr, nullptr, 0);
  node_attn1<<<NN, 256, 0, stream>>>(h1, as1, ad1, s1n, d1n);
  agg1      <<<NN, 256, 0, stream>>>(h1, s1n, d1n, rowptr, csrc, cae1, b1, out1);

  // layer 2
  gemm_tile<<<dim3(HIDD/64, (NN+63)/64), 256, 0, stream>>>(out1, W2, h2, NN, HIDD, HH, nullptr, nullptr, 0);
  node_attn2<<<NN/4, 256, 0, stream>>>(h2, as2, ad2, s2n, d2n);
  agg2      <<<NN/4, 256, 0, stream>>>(h2, s2n, d2n, rowptr, csrc, cae2, b2, out2);

  // projection head
  gemm_tile<<<dim3(HIDD/64, (NN+63)/64), 256, 0, stream>>>(out2, P1, zb, NN, HIDD, HIDD, pb1, pra, 1);
  gemm_tile<<<dim3(HIDD/64, (NN+63)/64), 256, 0, stream>>>(zb, P2, out, NN, HIDD, HIDD, pb2, nullptr, 2);

  // g = sigmoid(mean(h_proj, axis=0))
  colsum   <<<256, 128, 0, stream>>>(out, gbuf);
  sigmoid_g<<<1, 128, 0, stream>>>(gbuf, out + (size_t)NN*HIDD);
}

// Round 3
// 598.816 us; speedup vs baseline: 1.3246x; 1.3246x over previous
//
#include <hip/hip_runtime.h>
#include <hip/hip_bf16.h>

// GRN_GAT_Encoder round 2:
//  - bf16 storage for h1/out1/h2 (halves the gather traffic that dominated r1: agg1 192us, 614MB FETCH)
//  - MFMA bf16 GEMMs (m97-verified fragment layouts) for x@W1 and out1@W2; W pre-transposed+cast on device
//  - fp32 vector GEMMs kept for the output-facing projection head (precision budget)
//  - csr_fill float4 ea loads; fp32 GEMM LDS write-conflict pad
// fp32 everywhere else. CSR-gather aggregation, no atomics in hot paths.

#define NN    20000
#define EE    320000
#define E2    640000
#define FIN   256
#define FE    32
#define HIDD  128
#define NHEAD 4
#define HH    512   // NHEAD*HIDD

typedef unsigned short ushort_t;
typedef short frag8 __attribute__((ext_vector_type(8)));   // 8 bf16 (4 VGPRs)
typedef float f32x4 __attribute__((ext_vector_type(4)));   // 4 fp32 acc

__device__ inline ushort_t f2bf(float f){               // RNE fp32->bf16
  unsigned x = __float_as_uint(f);
  unsigned r = (x + 0x7fffu + ((x>>16)&1u)) >> 16;
  return (ushort_t)r;
}
__device__ inline float bf2f(ushort_t u){ return __uint_as_float(((unsigned)u)<<16); }
__device__ inline float lo_of(unsigned v){ return __uint_as_float(v<<16); }
__device__ inline float hi_of(unsigned v){ return __uint_as_float(v & 0xffff0000u); }

__device__ inline float wave_max(float v){
  #pragma unroll
  for(int o=32;o>0;o>>=1) v = fmaxf(v, __shfl_xor(v, o, 64));
  return v;
}
__device__ inline float wave_sum(float v){
  #pragma unroll
  for(int o=32;o>0;o>>=1) v += __shfl_xor(v, o, 64);
  return v;
}

// ---------------- CSR build ----------------

__global__ void count_edges(const int* __restrict__ ei, int* __restrict__ cnt){
  int e = blockIdx.x*256 + threadIdx.x;
  int dst = (e < EE) ? ei[EE + e] : ei[e - EE];
  atomicAdd(&cnt[dst], 1);
}

__global__ void scan_k(const int* __restrict__ cnt, int* __restrict__ rowptr){
  __shared__ int sums[1024];
  int tid = threadIdx.x;
  const int per = (NN + 1023)/1024;  // 20
  int base = tid*per;
  int s = 0;
  for(int i=0;i<per;i++){ int idx=base+i; if(idx<NN) s += cnt[idx]; }
  sums[tid] = s; __syncthreads();
  for(int off=1; off<1024; off<<=1){
    int v = (tid>=off)? sums[tid-off] : 0;
    __syncthreads();
    sums[tid] += v;
    __syncthreads();
  }
  int run = (tid==0)? 0 : sums[tid-1];
  for(int i=0;i<per;i++){
    int idx = base+i;
    if(idx<=NN) rowptr[idx] = run;
    if(idx<NN)  run += cnt[idx];
  }
}

__global__ void compute_v(const float* __restrict__ We1, const float* __restrict__ ae1,
                          const float* __restrict__ We2, const float* __restrict__ ae2,
                          float* __restrict__ v1, float* __restrict__ v2){
  int tid = threadIdx.x;
  if(tid < FE*NHEAD){
    int f = tid>>2, h = tid&3;
    float s = 0.f;
    for(int c=0;c<HIDD;c++) s += We1[f*HH + h*HIDD + c] * ae1[h*HIDD + c];
    v1[f*4+h] = s;
  } else if(tid < FE*NHEAD + FE){
    int f = tid - FE*NHEAD;
    float s = 0.f;
    for(int c=0;c<HIDD;c++) s += We2[f*HIDD + c] * ae2[c];
    v2[f] = s;
  }
}

__global__ void csr_fill(const int* __restrict__ ei, const float* __restrict__ ea,
                         const float* __restrict__ v1, const float* __restrict__ v2,
                         const int* __restrict__ rowptr, int* __restrict__ fcnt,
                         int* __restrict__ csrc, float* __restrict__ cae1, float* __restrict__ cae2){
  __shared__ float sv1[FE*NHEAD];
  __shared__ float sv2[FE];
  int tid = threadIdx.x;
  if(tid < FE*NHEAD) sv1[tid] = v1[tid];
  if(tid < FE)       sv2[tid] = v2[tid];
  __syncthreads();
  int e = blockIdx.x*256 + tid;
  int src, dst, row;
  if(e < EE){ src = ei[e];       dst = ei[EE+e]; row = e; }
  else      { int e0=e-EE; src = ei[EE+e0]; dst = ei[e0]; row = e0; }
  const float4* er4 = (const float4*)(ea + (long)row*FE);
  float a0=0,a1=0,a2=0,a3=0,ab=0;
  #pragma unroll
  for(int f4=0; f4<FE/4; f4++){
    float4 t = er4[f4];
    float tv[4] = {t.x, t.y, t.z, t.w};
    #pragma unroll
    for(int c=0;c<4;c++){
      int f = f4*4+c;
      float t1 = tv[c];
      a0 += t1*sv1[f*4+0]; a1 += t1*sv1[f*4+1]; a2 += t1*sv1[f*4+2]; a3 += t1*sv1[f*4+3];
      ab += t1*sv2[f];
    }
  }
  int pos = rowptr[dst] + atomicAdd(&fcnt[dst], 1);
  csrc[pos] = src;
  cae1[pos*4+0]=a0; cae1[pos*4+1]=a1; cae1[pos*4+2]=a2; cae1[pos*4+3]=a3;
  cae2[pos] = ab;
}

// ---------------- casts ----------------

__global__ void cast_x(const float* __restrict__ x, ushort_t* __restrict__ xb, int n4){
  int i = blockIdx.x*256 + threadIdx.x;
  if(i>=n4) return;
  float4 v = ((const float4*)x)[i];
  ushort4 o; o.x=f2bf(v.x); o.y=f2bf(v.y); o.z=f2bf(v.z); o.w=f2bf(v.w);
  ((ushort4*)xb)[i] = o;
}

// W [K][N] fp32 -> Wt [N][K] bf16
__global__ void castT(const float* __restrict__ W, ushort_t* __restrict__ Wt, int K, int N){
  int idx = blockIdx.x*256 + threadIdx.x;
  if(idx >= K*N) return;
  int k = idx / N, n = idx - k*N;
  Wt[n*K + k] = f2bf(W[idx]);
}

// ---------------- MFMA bf16 GEMM: C[M,N] = A[M,K] @ Bt[N,K]^T ----------------
// 128x128 tile, BK=32, 256 threads (4 waves, 64x64 quadrant each), 16x16x32 mfma.
// A,Bt bf16 (ushort); C bf16. M guarded; N%128==0, K%32==0.
__global__ __launch_bounds__(256) void mfma_gemm(const ushort_t* __restrict__ A, const ushort_t* __restrict__ Bt,
                                                 ushort_t* __restrict__ C, int M, int N, int K){
  __shared__ ushort_t As[128*32];
  __shared__ ushort_t Bs[128*32];
  int tid = threadIdx.x;
  int m0 = blockIdx.y*128, n0 = blockIdx.x*128;
  int w = tid>>6, lane = tid&63;
  int qr = (w>>1)*64, qc = (w&1)*64;
  int lrow = lane&15, koff = (lane>>4)*8;
  f32x4 acc[4][4] = {};
  for(int k0=0; k0<K; k0+=32){
    #pragma unroll
    for(int rep=0;rep<2;rep++){
      int segid = tid + rep*256;          // 512 segments of 8 bf16 (16B)
      int row = segid>>2, off = (segid&3)*8;
      int gr = m0 + row;
      int4 va = (gr<M) ? *(const int4*)(A + (long)gr*K + k0 + off) : int4{0,0,0,0};
      *(int4*)&As[row*32 + off] = va;
      int4 vb = *(const int4*)(Bt + (long)(n0+row)*K + k0 + off);
      *(int4*)&Bs[row*32 + off] = vb;
    }
    __syncthreads();
    frag8 af[4], bfr[4];
    #pragma unroll
    for(int i=0;i<4;i++) af[i]  = *(const frag8*)&As[(qr + i*16 + lrow)*32 + koff];
    #pragma unroll
    for(int j=0;j<4;j++) bfr[j] = *(const frag8*)&Bs[(qc + j*16 + lrow)*32 + koff];
    #pragma unroll
    for(int i=0;i<4;i++)
      #pragma unroll
      for(int j=0;j<4;j++)
        acc[i][j] = __builtin_amdgcn_mfma_f32_16x16x32_bf16(af[i], bfr[j], acc[i][j], 0,0,0);
    __syncthreads();
  }
  // C/D: col = lane&15, row = (lane>>4)*4 + reg   [m89/m91 verified]
  #pragma unroll
  for(int i=0;i<4;i++){
    #pragma unroll
    for(int j=0;j<4;j++){
      #pragma unroll
      for(int r=0;r<4;r++){
        int row = m0 + qr + i*16 + (lane>>4)*4 + r;
        int col = n0 + qc + j*16 + (lane&15);
        if(row<M) C[(long)row*N + col] = f2bf(acc[i][j][r]);
      }
    }
  }
}

// ---------------- per-node attention scalars (bf16 h) ----------------

__global__ void node_attn1(const ushort_t* __restrict__ h1b, const float* __restrict__ as1,
                           const float* __restrict__ ad1, float* __restrict__ s1n, float* __restrict__ d1n){
  int n = blockIdx.x;
  int wv = threadIdx.x>>6, lane = threadIdx.x&63;
  unsigned v = *(const unsigned*)(h1b + (long)n*HH + wv*HIDD + 2*lane);
  float f0 = lo_of(v), f1 = hi_of(v);
  float s = wave_sum(f0*as1[wv*HIDD+2*lane] + f1*as1[wv*HIDD+2*lane+1]);
  float d = wave_sum(f0*ad1[wv*HIDD+2*lane] + f1*ad1[wv*HIDD+2*lane+1]);
  if(lane==0){ s1n[n*4+wv]=s; d1n[n*4+wv]=d; }
}

__global__ void node_attn2(const ushort_t* __restrict__ h2b, const float* __restrict__ as2,
                           const float* __restrict__ ad2, float* __restrict__ s2n, float* __restrict__ d2n){
  int n = blockIdx.x*4 + (threadIdx.x>>6);
  int lane = threadIdx.x&63;
  unsigned v = *(const unsigned*)(h2b + (long)n*HIDD + 2*lane);
  float f0 = lo_of(v), f1 = hi_of(v);
  float s = wave_sum(f0*as2[2*lane] + f1*as2[2*lane+1]);
  float d = wave_sum(f0*ad2[2*lane] + f1*ad2[2*lane+1]);
  if(lane==0){ s2n[n]=s; d2n[n]=d; }
}

// ---------------- softmax + aggregate (gather over dst-CSR, bf16 h) ----------------

__global__ void agg1(const ushort_t* __restrict__ h1b, const float* __restrict__ s1n, const float* __restrict__ d1n,
                     const int* __restrict__ rowptr, const int* __restrict__ csrc, const float* __restrict__ cae1,
                     const float* __restrict__ b1, ushort_t* __restrict__ out1b){
  int n = blockIdx.x;
  int h = threadIdx.x>>6, lane = threadIdx.x&63;
  int beg = rowptr[n], end = rowptr[n+1];
  float dn = d1n[n*4+h];
  float m = -1e30f;
  for(int i=beg+lane; i<end; i+=64){
    float a = s1n[csrc[i]*4+h] + dn + cae1[i*4+h];
    a = a>0.f? a : 0.2f*a;
    m = fmaxf(m, a);
  }
  m = wave_max(m);
  float ss = 0.f;
  for(int i=beg+lane; i<end; i+=64){
    float a = s1n[csrc[i]*4+h] + dn + cae1[i*4+h];
    a = a>0.f? a : 0.2f*a;
    ss += __expf(a-m);
  }
  ss = wave_sum(ss);
  float inv = ss>0.f ? 1.f/ss : 0.f;
  float acc0=0.f, acc1=0.f;
  for(int i=beg; i<end; i++){
    int s = csrc[i];
    float a = s1n[s*4+h] + dn + cae1[i*4+h];
    a = a>0.f? a : 0.2f*a;
    float wgt = __expf(a-m)*inv;
    unsigned v = *(const unsigned*)(h1b + (long)s*HH + h*HIDD + 2*lane);
    acc0 += wgt*lo_of(v);
    acc1 += wgt*hi_of(v);
  }
  float o0 = acc0 + b1[h*HIDD+2*lane];
  float o1 = acc1 + b1[h*HIDD+2*lane+1];
  o0 = o0>0.f? o0 : __expf(o0)-1.f;   // ELU
  o1 = o1>0.f? o1 : __expf(o1)-1.f;
  unsigned pk = (unsigned)f2bf(o0) | ((unsigned)f2bf(o1)<<16);
  *(unsigned*)(out1b + (long)n*HH + h*HIDD + 2*lane) = pk;
}

__global__ void agg2(const ushort_t* __restrict__ h2b, const float* __restrict__ s2n, const float* __restrict__ d2n,
                     const int* __restrict__ rowptr, const int* __restrict__ csrc, const float* __restrict__ cae2,
                     const float* __restrict__ b2, float* __restrict__ out2){
  int n = blockIdx.x*4 + (threadIdx.x>>6);
  int lane = threadIdx.x&63;
  int beg = rowptr[n], end = rowptr[n+1];
  float dn = d2n[n];
  float m = -1e30f;
  for(int i=beg+lane; i<end; i+=64){
    float a = s2n[csrc[i]] + dn + cae2[i];
    a = a>0.f? a : 0.2f*a;
    m = fmaxf(m, a);
  }
  m = wave_max(m);
  float ss = 0.f;
  for(int i=beg+lane; i<end; i+=64){
    float a = s2n[csrc[i]] + dn + cae2[i];
    a = a>0.f? a : 0.2f*a;
    ss += __expf(a-m);
  }
  ss = wave_sum(ss);
  float inv = ss>0.f ? 1.f/ss : 0.f;
  float acc0=0.f, acc1=0.f;
  for(int i=beg; i<end; i++){
    int s = csrc[i];
    float a = s2n[s] + dn + cae2[i];
    a = a>0.f? a : 0.2f*a;
    float wgt = __expf(a-m)*inv;
    unsigned v = *(const unsigned*)(h2b + (long)s*HIDD + 2*lane);
    acc0 += wgt*lo_of(v);
    acc1 += wgt*hi_of(v);
  }
  float o0 = acc0 + b2[2*lane];
  float o1 = acc1 + b2[2*lane+1];
  o0 = o0>0.f? o0 : __expf(o0)-1.f;
  o1 = o1>0.f? o1 : __expf(o1)-1.f;
  float2 pk; pk.x = o0; pk.y = o1;
  *(float2*)(out2 + (long)n*HIDD + 2*lane) = pk;
}

// ---------------- fp32 projection GEMM (output-facing, keep fp32) ----------------
// C[M,N] = A[M,K] @ B[K,N]; epi: 1 bias+PReLU; 2 bias only.
__global__ __launch_bounds__(256) void gemm_tile(const float* __restrict__ A, const float* __restrict__ B,
                                                 float* __restrict__ C, int M, int N, int K,
                                                 const float* __restrict__ bias,
                                                 const float* __restrict__ prelu_a, int epi){
  __shared__ float As[16][66];   // pad 66: kills the 16-way write conflict on As[c][r]
  __shared__ float Bs[16][64];
  int tid = threadIdx.x;
  int m0 = blockIdx.y*64, n0 = blockIdx.x*64;
  int tm = (tid>>4)<<2, tn = (tid&15)<<2;
  float acc[4][4] = {};
  for(int k0=0; k0<K; k0+=16){
    #pragma unroll
    for(int i=0;i<4;i++){
      int idx = tid + i*256;
      int r = idx>>4, c = idx&15;
      int gr = m0 + r;
      As[c][r] = (gr<M)? A[(long)gr*K + k0 + c] : 0.f;
    }
    #pragma unroll
    for(int i=0;i<4;i++){
      int idx = tid + i*256;
      int r = idx>>6, c = idx&63;
      Bs[r][c] = B[(long)(k0+r)*N + n0 + c];
    }
    __syncthreads();
    #pragma unroll
    for(int k=0;k<16;k++){
      float a0=As[k][tm+0],a1=As[k][tm+1],a2=As[k][tm+2],a3=As[k][tm+3];
      float b0=Bs[k][tn+0],b1=Bs[k][tn+1],b2=Bs[k][tn+2],b3=Bs[k][tn+3];
      acc[0][0]+=a0*b0; acc[0][1]+=a0*b1; acc[0][2]+=a0*b2; acc[0][3]+=a0*b3;
      acc[1][0]+=a1*b0; acc[1][1]+=a1*b1; acc[1][2]+=a1*b2; acc[1][3]+=a1*b3;
      acc[2][0]+=a2*b0; acc[2][1]+=a2*b1; acc[2][2]+=a2*b2; acc[2][3]+=a2*b3;
      acc[3][0]+=a3*b0; acc[3][1]+=a3*b1; acc[3][2]+=a3*b2; acc[3][3]+=a3*b3;
    }
    __syncthreads();
  }
  float ap = (epi==1)? prelu_a[0] : 0.f;
  #pragma unroll
  for(int i=0;i<4;i++){
    int gr = m0+tm+i;
    if(gr>=M) continue;
    #pragma unroll
    for(int j=0;j<4;j++){
      int gc = n0+tn+j;
      float v = acc[i][j];
      if(epi>=1) v += bias[gc];
      if(epi==1) v = v>0.f? v : ap*v;
      C[(long)gr*N+gc] = v;
    }
  }
}

// ---------------- readout ----------------

__global__ void colsum(const float* __restrict__ hp, float* __restrict__ gbuf){
  int c = threadIdx.x;
  float acc = 0.f;
  for(int r = blockIdx.x; r < NN; r += gridDim.x) acc += hp[(long)r*HIDD + c];
  atomicAdd(&gbuf[c], acc);
}

__global__ void sigmoid_g(const float* __restrict__ gbuf, float* __restrict__ gout){
  int c = threadIdx.x;
  float m = gbuf[c] * (1.0f/NN);
  gout[c] = 1.f/(1.f+__expf(-m));
}

// ---------------- launch ----------------

extern "C" void kernel_launch(void* const* d_in, const int* in_sizes, int n_in,
                              void* d_out, int out_size, void* d_ws, size_t ws_size,
                              hipStream_t stream){
  const float* x    = (const float*)d_in[0];
  const int*   ei   = (const int*)  d_in[1];
  const float* ea   = (const float*)d_in[2];
  const float* W1   = (const float*)d_in[3];
  const float* We1  = (const float*)d_in[4];
  const float* as1  = (const float*)d_in[5];
  const float* ad1  = (const float*)d_in[6];
  const float* ae1  = (const float*)d_in[7];
  const float* b1   = (const float*)d_in[8];
  const float* W2   = (const float*)d_in[9];
  const float* We2  = (const float*)d_in[10];
  const float* as2  = (const float*)d_in[11];
  const float* ad2  = (const float*)d_in[12];
  const float* ae2  = (const float*)d_in[13];
  const float* b2   = (const float*)d_in[14];
  const float* P1   = (const float*)d_in[15];
  const float* pb1  = (const float*)d_in[16];
  const float* pra  = (const float*)d_in[17];
  const float* P2   = (const float*)d_in[18];
  const float* pb2  = (const float*)d_in[19];
  float* out = (float*)d_out;

  char* wsp = (char*)d_ws;
  size_t off = 0;
  auto alloc = [&](size_t bytes)->char*{
    char* p = wsp + off;
    off += (bytes + 255) & ~(size_t)255;
    return p;
  };
  ushort_t* h1b  = (ushort_t*)alloc(sizeof(ushort_t)*(size_t)NN*HH);    // 20.5 MB
  ushort_t* out1b= (ushort_t*)alloc(sizeof(ushort_t)*(size_t)NN*HH);    // 20.5 MB
  ushort_t* h2b  = (ushort_t*)alloc(sizeof(ushort_t)*(size_t)NN*HIDD);  // 5.1 MB
  float*    out2 = (float*)  alloc(sizeof(float)*(size_t)NN*HIDD);      // 10.2 MB
  float*    zb   = (float*)  alloc(sizeof(float)*(size_t)NN*HIDD);      // 10.2 MB
  ushort_t* xb   = (ushort_t*)alloc(sizeof(ushort_t)*(size_t)NN*FIN);   // 10.2 MB
  ushort_t* W1t  = (ushort_t*)alloc(sizeof(ushort_t)*(size_t)HH*FIN);   // 0.26 MB [512][256]
  ushort_t* W2t  = (ushort_t*)alloc(sizeof(ushort_t)*(size_t)HIDD*HH);  // 0.13 MB [128][512]
  float* s1n   = (float*)alloc(sizeof(float)*NN*NHEAD);
  float* d1n   = (float*)alloc(sizeof(float)*NN*NHEAD);
  float* s2n   = (float*)alloc(sizeof(float)*NN);
  float* d2n   = (float*)alloc(sizeof(float)*NN);
  float* v1    = (float*)alloc(sizeof(float)*FE*NHEAD);
  float* v2    = (float*)alloc(sizeof(float)*FE);
  float* gbuf  = (float*)alloc(sizeof(float)*HIDD);
  float* cae1  = (float*)alloc(sizeof(float)*(size_t)E2*NHEAD);  // 10.2 MB
  float* cae2  = (float*)alloc(sizeof(float)*(size_t)E2);        // 2.6 MB
  int*   rowptr= (int*)  alloc(sizeof(int)*(NN+1));
  int*   cnt   = (int*)  alloc(sizeof(int)*NN);
  int*   fcnt  = (int*)  alloc(sizeof(int)*NN);
  int*   csrc  = (int*)  alloc(sizeof(int)*(size_t)E2);          // 2.6 MB

  hipMemsetAsync(cnt,  0, sizeof(int)*NN, stream);
  hipMemsetAsync(fcnt, 0, sizeof(int)*NN, stream);
  hipMemsetAsync(gbuf, 0, sizeof(float)*HIDD, stream);

  // graph structure + edge logit terms
  count_edges<<<E2/256, 256, 0, stream>>>(ei, cnt);
  scan_k     <<<1, 1024, 0, stream>>>(cnt, rowptr);
  compute_v  <<<1, 192, 0, stream>>>(We1, ae1, We2, ae2, v1, v2);
  csr_fill   <<<E2/256, 256, 0, stream>>>(ei, ea, v1, v2, rowptr, fcnt, csrc, cae1, cae2);

  // casts
  cast_x<<<(NN*FIN/4 + 255)/256, 256, 0, stream>>>(x, xb, NN*FIN/4);
  castT <<<(FIN*HH + 255)/256, 256, 0, stream>>>(W1, W1t, FIN, HH);
  castT <<<(HH*HIDD + 255)/256, 256, 0, stream>>>(W2, W2t, HH, HIDD);

  // layer 1
  mfma_gemm<<<dim3(HH/128, (NN+127)/128), 256, 0, stream>>>(xb, W1t, h1b, NN, HH, FIN);
  node_attn1<<<NN, 256, 0, stream>>>(h1b, as1, ad1, s1n, d1n);
  agg1      <<<NN, 256, 0, stream>>>(h1b, s1n, d1n, rowptr, csrc, cae1, b1, out1b);

  // layer 2
  mfma_gemm<<<dim3(HIDD/128, (NN+127)/128), 256, 0, stream>>>(out1b, W2t, h2b, NN, HIDD, HH);
  node_attn2<<<NN/4, 256, 0, stream>>>(h2b, as2, ad2, s2n, d2n);
  agg2      <<<NN/4, 256, 0, stream>>>(h2b, s2n, d2n, rowptr, csrc, cae2, b2, out2);

  // projection head (fp32)
  gemm_tile<<<dim3(HIDD/64, (NN+63)/64), 256, 0, stream>>>(out2, P1, zb, NN, HIDD, HIDD, pb1, pra, 1);
  gemm_tile<<<dim3(HIDD/64, (NN+63)/64), 256, 0, stream>>>(zb, P2, out, NN, HIDD, HIDD, pb2, nullptr, 2);

  // g = sigmoid(mean(h_proj, axis=0))
  colsum   <<<256, 128, 0, stream>>>(out, gbuf);
  sigmoid_g<<<1, 128, 0, stream>>>(gbuf, out + (size_t)NN*HIDD);
}

// Round 4
// 549.596 us; speedup vs baseline: 1.4433x; 1.0896x over previous
//
#include <hip/hip_runtime.h>
#include <hip/hip_bf16.h>

// GRN_GAT_Encoder round 3:
// r2 post-mortem: agg1 VALU-bound (VALUBusy 63%, hbm 23%) — 3-loop structure recomputed
// the logit chain (gather+lrelu+exp) per edge per head in the serial gather loop.
// r3: edge-parallel logit pass (coalesced, s1n/d1n L2-resident) -> agg loops read stored
// logits coalesced; loop2 writes unnormalized exp in place; gather loop is wave-per-node
// (all 4 heads, 16B/lane dwordx4) with broadcast weight loads. Same math, ~3x fewer VALU.

#define NN    20000
#define EE    320000
#define E2    640000
#define FIN   256
#define FE    32
#define HIDD  128
#define NHEAD 4
#define HH    512   // NHEAD*HIDD

typedef unsigned short ushort_t;
typedef short frag8 __attribute__((ext_vector_type(8)));   // 8 bf16 (4 VGPRs)
typedef float f32x4 __attribute__((ext_vector_type(4)));   // 4 fp32 acc

__device__ inline ushort_t f2bf(float f){               // RNE fp32->bf16
  unsigned x = __float_as_uint(f);
  unsigned r = (x + 0x7fffu + ((x>>16)&1u)) >> 16;
  return (ushort_t)r;
}
__device__ inline float lo_of(unsigned v){ return __uint_as_float(v<<16); }
__device__ inline float hi_of(unsigned v){ return __uint_as_float(v & 0xffff0000u); }

__device__ inline float wave_max(float v){
  #pragma unroll
  for(int o=32;o>0;o>>=1) v = fmaxf(v, __shfl_xor(v, o, 64));
  return v;
}
__device__ inline float wave_sum(float v){
  #pragma unroll
  for(int o=32;o>0;o>>=1) v += __shfl_xor(v, o, 64);
  return v;
}

// ---------------- CSR build ----------------

__global__ void count_edges(const int* __restrict__ ei, int* __restrict__ cnt){
  int e = blockIdx.x*256 + threadIdx.x;
  int dst = (e < EE) ? ei[EE + e] : ei[e - EE];
  atomicAdd(&cnt[dst], 1);
}

__global__ void scan_k(const int* __restrict__ cnt, int* __restrict__ rowptr){
  __shared__ int sums[1024];
  int tid = threadIdx.x;
  const int per = (NN + 1023)/1024;  // 20
  int base = tid*per;
  int s = 0;
  for(int i=0;i<per;i++){ int idx=base+i; if(idx<NN) s += cnt[idx]; }
  sums[tid] = s; __syncthreads();
  for(int off=1; off<1024; off<<=1){
    int v = (tid>=off)? sums[tid-off] : 0;
    __syncthreads();
    sums[tid] += v;
    __syncthreads();
  }
  int run = (tid==0)? 0 : sums[tid-1];
  for(int i=0;i<per;i++){
    int idx = base+i;
    if(idx<=NN) rowptr[idx] = run;
    if(idx<NN)  run += cnt[idx];
  }
}

__global__ void compute_v(const float* __restrict__ We1, const float* __restrict__ ae1,
                          const float* __restrict__ We2, const float* __restrict__ ae2,
                          float* __restrict__ v1, float* __restrict__ v2){
  int tid = threadIdx.x;
  if(tid < FE*NHEAD){
    int f = tid>>2, h = tid&3;
    float s = 0.f;
    for(int c=0;c<HIDD;c++) s += We1[f*HH + h*HIDD + c] * ae1[h*HIDD + c];
    v1[f*4+h] = s;
  } else if(tid < FE*NHEAD + FE){
    int f = tid - FE*NHEAD;
    float s = 0.f;
    for(int c=0;c<HIDD;c++) s += We2[f*HIDD + c] * ae2[c];
    v2[f] = s;
  }
}

__global__ void csr_fill(const int* __restrict__ ei, const float* __restrict__ ea,
                         const float* __restrict__ v1, const float* __restrict__ v2,
                         const int* __restrict__ rowptr, int* __restrict__ fcnt,
                         int* __restrict__ csrc, int* __restrict__ cdst,
                         float* __restrict__ cae1, float* __restrict__ cae2){
  __shared__ float sv1[FE*NHEAD];
  __shared__ float sv2[FE];
  int tid = threadIdx.x;
  if(tid < FE*NHEAD) sv1[tid] = v1[tid];
  if(tid < FE)       sv2[tid] = v2[tid];
  __syncthreads();
  int e = blockIdx.x*256 + tid;
  int src, dst, row;
  if(e < EE){ src = ei[e];       dst = ei[EE+e]; row = e; }
  else      { int e0=e-EE; src = ei[EE+e0]; dst = ei[e0]; row = e0; }
  const float4* er4 = (const float4*)(ea + (long)row*FE);
  float a0=0,a1=0,a2=0,a3=0,ab=0;
  #pragma unroll
  for(int f4=0; f4<FE/4; f4++){
    float4 t = er4[f4];
    float tv[4] = {t.x, t.y, t.z, t.w};
    #pragma unroll
    for(int c=0;c<4;c++){
      int f = f4*4+c;
      float t1 = tv[c];
      a0 += t1*sv1[f*4+0]; a1 += t1*sv1[f*4+1]; a2 += t1*sv1[f*4+2]; a3 += t1*sv1[f*4+3];
      ab += t1*sv2[f];
    }
  }
  int pos = rowptr[dst] + atomicAdd(&fcnt[dst], 1);
  csrc[pos] = src;
  cdst[pos] = dst;
  cae1[pos*4+0]=a0; cae1[pos*4+1]=a1; cae1[pos*4+2]=a2; cae1[pos*4+3]=a3;
  cae2[pos] = ab;
}

// ---------------- casts ----------------

__global__ void cast_x(const float* __restrict__ x, ushort_t* __restrict__ xb, int n4){
  int i = blockIdx.x*256 + threadIdx.x;
  if(i>=n4) return;
  float4 v = ((const float4*)x)[i];
  ushort4 o; o.x=f2bf(v.x); o.y=f2bf(v.y); o.z=f2bf(v.z); o.w=f2bf(v.w);
  ((ushort4*)xb)[i] = o;
}

// W [K][N] fp32 -> Wt [N][K] bf16
__global__ void castT(const float* __restrict__ W, ushort_t* __restrict__ Wt, int K, int N){
  int idx = blockIdx.x*256 + threadIdx.x;
  if(idx >= K*N) return;
  int k = idx / N, n = idx - k*N;
  Wt[n*K + k] = f2bf(W[idx]);
}

// ---------------- MFMA bf16 GEMM: C[M,N] = A[M,K] @ Bt[N,K]^T ----------------
__global__ __launch_bounds__(256) void mfma_gemm(const ushort_t* __restrict__ A, const ushort_t* __restrict__ Bt,
                                                 ushort_t* __restrict__ C, int M, int N, int K){
  __shared__ ushort_t As[128*32];
  __shared__ ushort_t Bs[128*32];
  int tid = threadIdx.x;
  int m0 = blockIdx.y*128, n0 = blockIdx.x*128;
  int w = tid>>6, lane = tid&63;
  int qr = (w>>1)*64, qc = (w&1)*64;
  int lrow = lane&15, koff = (lane>>4)*8;
  f32x4 acc[4][4] = {};
  for(int k0=0; k0<K; k0+=32){
    #pragma unroll
    for(int rep=0;rep<2;rep++){
      int segid = tid + rep*256;          // 512 segments of 8 bf16 (16B)
      int row = segid>>2, off = (segid&3)*8;
      int gr = m0 + row;
      int4 va = (gr<M) ? *(const int4*)(A + (long)gr*K + k0 + off) : int4{0,0,0,0};
      *(int4*)&As[row*32 + off] = va;
      int4 vb = *(const int4*)(Bt + (long)(n0+row)*K + k0 + off);
      *(int4*)&Bs[row*32 + off] = vb;
    }
    __syncthreads();
    frag8 af[4], bfr[4];
    #pragma unroll
    for(int i=0;i<4;i++) af[i]  = *(const frag8*)&As[(qr + i*16 + lrow)*32 + koff];
    #pragma unroll
    for(int j=0;j<4;j++) bfr[j] = *(const frag8*)&Bs[(qc + j*16 + lrow)*32 + koff];
    #pragma unroll
    for(int i=0;i<4;i++)
      #pragma unroll
      for(int j=0;j<4;j++)
        acc[i][j] = __builtin_amdgcn_mfma_f32_16x16x32_bf16(af[i], bfr[j], acc[i][j], 0,0,0);
    __syncthreads();
  }
  #pragma unroll
  for(int i=0;i<4;i++){
    #pragma unroll
    for(int j=0;j<4;j++){
      #pragma unroll
      for(int r=0;r<4;r++){
        int row = m0 + qr + i*16 + (lane>>4)*4 + r;
        int col = n0 + qc + j*16 + (lane&15);
        if(row<M) C[(long)row*N + col] = f2bf(acc[i][j][r]);
      }
    }
  }
}

// ---------------- per-node attention scalars (bf16 h) ----------------

__global__ void node_attn1(const ushort_t* __restrict__ h1b, const float* __restrict__ as1,
                           const float* __restrict__ ad1, float* __restrict__ s1n, float* __restrict__ d1n){
  int n = blockIdx.x;
  int wv = threadIdx.x>>6, lane = threadIdx.x&63;
  unsigned v = *(const unsigned*)(h1b + (long)n*HH + wv*HIDD + 2*lane);
  float f0 = lo_of(v), f1 = hi_of(v);
  float s = wave_sum(f0*as1[wv*HIDD+2*lane] + f1*as1[wv*HIDD+2*lane+1]);
  float d = wave_sum(f0*ad1[wv*HIDD+2*lane] + f1*ad1[wv*HIDD+2*lane+1]);
  if(lane==0){ s1n[n*4+wv]=s; d1n[n*4+wv]=d; }
}

__global__ void node_attn2(const ushort_t* __restrict__ h2b, const float* __restrict__ as2,
                           const float* __restrict__ ad2, float* __restrict__ s2n, float* __restrict__ d2n){
  int n = blockIdx.x*4 + (threadIdx.x>>6);
  int lane = threadIdx.x&63;
  unsigned v = *(const unsigned*)(h2b + (long)n*HIDD + 2*lane);
  float f0 = lo_of(v), f1 = hi_of(v);
  float s = wave_sum(f0*as2[2*lane] + f1*as2[2*lane+1]);
  float d = wave_sum(f0*ad2[2*lane] + f1*ad2[2*lane+1]);
  if(lane==0){ s2n[n]=s; d2n[n]=d; }
}

// ---------------- edge-parallel logits (computed ONCE per edge) ----------------
// cae1[i*4+h] := leakyrelu( s1n[src,h] + d1n[dst,h] + cae1[i*4+h] )
__global__ void edge_logits1(const int* __restrict__ csrc, const int* __restrict__ cdst,
                             const float* __restrict__ s1n, const float* __restrict__ d1n,
                             float* __restrict__ cae1){
  int i = blockIdx.x*256 + threadIdx.x;       // grid exactly E2/256
  int s = csrc[i], d = cdst[i];
  float4 sv = ((const float4*)s1n)[s];
  float4 dv = ((const float4*)d1n)[d];
  float4 av = ((float4*)cae1)[i];
  float4 r;
  float t;
  t = sv.x+dv.x+av.x; r.x = t>0.f? t : 0.2f*t;
  t = sv.y+dv.y+av.y; r.y = t>0.f? t : 0.2f*t;
  t = sv.z+dv.z+av.z; r.z = t>0.f? t : 0.2f*t;
  t = sv.w+dv.w+av.w; r.w = t>0.f? t : 0.2f*t;
  ((float4*)cae1)[i] = r;
}

__global__ void edge_logits2(const int* __restrict__ csrc, const int* __restrict__ cdst,
                             const float* __restrict__ s2n, const float* __restrict__ d2n,
                             float* __restrict__ cae2){
  int i = blockIdx.x*256 + threadIdx.x;
  float t = s2n[csrc[i]] + d2n[cdst[i]] + cae2[i];
  cae2[i] = t>0.f? t : 0.2f*t;
}

// ---------------- softmax + aggregate (gather over dst-CSR, bf16 h) ----------------
// wave = node, all 4 heads. loops 1-2 coalesced over stored logits; loop2 writes
// unnormalized exp in place; loop3 gathers 16B/lane, weight via 16-lane broadcast.

__global__ void agg1(const ushort_t* __restrict__ h1b, const int* __restrict__ rowptr,
                     const int* __restrict__ csrc, float* cae1,
                     const float* __restrict__ b1, ushort_t* __restrict__ out1b){
  int n = blockIdx.x*4 + (threadIdx.x>>6);    // 4 nodes/block
  int lane = threadIdx.x&63;
  int beg = rowptr[n], end = rowptr[n+1];
  int h12 = lane&3;
  // pass 1: per-head max (lane l covers edge beg+(l>>2), head l&3 -> contiguous reads)
  float m = -1e30f;
  for(int base=beg; base<end; base+=16){
    int e = base + (lane>>2);
    if(e<end) m = fmaxf(m, cae1[e*4 + h12]);
  }
  #pragma unroll
  for(int o=4;o<=32;o<<=1) m = fmaxf(m, __shfl_xor(m, o, 64));
  // pass 2: sum exp, write unnormalized exp back
  float ss = 0.f;
  for(int base=beg; base<end; base+=16){
    int e = base + (lane>>2);
    if(e<end){
      float ex = __expf(cae1[e*4 + h12] - m);
      cae1[e*4 + h12] = ex;
      ss += ex;
    }
  }
  #pragma unroll
  for(int o=4;o<=32;o<<=1) ss += __shfl_xor(ss, o, 64);
  float inv = ss>0.f ? 1.f/ss : 0.f;
  // gather layout: lane covers channels 8*lane..8*lane+7; head = lane>>4
  float invq = __shfl(inv, lane>>4, 64);      // lanes 0..3 hold heads 0..3
  float acc[8] = {};
  for(int i=beg; i<end; i++){
    int s = csrc[i];
    float w = cae1[i*4 + (lane>>4)] * invq;   // broadcast within 16-lane group
    uint4 v = *(const uint4*)(h1b + (long)s*HH + lane*8);
    acc[0] += w*lo_of(v.x); acc[1] += w*hi_of(v.x);
    acc[2] += w*lo_of(v.y); acc[3] += w*hi_of(v.y);
    acc[4] += w*lo_of(v.z); acc[5] += w*hi_of(v.z);
    acc[6] += w*lo_of(v.w); acc[7] += w*hi_of(v.w);
  }
  float4 bl = ((const float4*)b1)[lane*2];
  float4 bh = ((const float4*)b1)[lane*2+1];
  float bb[8] = {bl.x,bl.y,bl.z,bl.w,bh.x,bh.y,bh.z,bh.w};
  ushort_t o8[8];
  #pragma unroll
  for(int c=0;c<8;c++){
    float o = acc[c] + bb[c];
    o8[c] = f2bf(o>0.f? o : __expf(o)-1.f);   // ELU
  }
  uint4 pk;
  pk.x = (unsigned)o8[0] | ((unsigned)o8[1]<<16);
  pk.y = (unsigned)o8[2] | ((unsigned)o8[3]<<16);
  pk.z = (unsigned)o8[4] | ((unsigned)o8[5]<<16);
  pk.w = (unsigned)o8[6] | ((unsigned)o8[7]<<16);
  *(uint4*)(out1b + (long)n*HH + lane*8) = pk;
}

__global__ void agg2(const ushort_t* __restrict__ h2b, const int* __restrict__ rowptr,
                     const int* __restrict__ csrc, float* cae2,
                     const float* __restrict__ b2, float* __restrict__ out2){
  int n = blockIdx.x*4 + (threadIdx.x>>6);
  int lane = threadIdx.x&63;
  int beg = rowptr[n], end = rowptr[n+1];
  float m = -1e30f;
  for(int i=beg+lane; i<end; i+=64) m = fmaxf(m, cae2[i]);
  m = wave_max(m);
  float ss = 0.f;
  for(int i=beg+lane; i<end; i+=64){
    float ex = __expf(cae2[i]-m);
    cae2[i] = ex;
    ss += ex;
  }
  ss = wave_sum(ss);
  float inv = ss>0.f ? 1.f/ss : 0.f;
  float a0=0.f, a1=0.f;
  for(int i=beg; i<end; i++){
    float w = cae2[i]*inv;
    unsigned v = *(const unsigned*)(h2b + (long)csrc[i]*HIDD + 2*lane);
    a0 += w*lo_of(v); a1 += w*hi_of(v);
  }
  float o0 = a0 + b2[2*lane];
  float o1 = a1 + b2[2*lane+1];
  float2 pk;
  pk.x = o0>0.f? o0 : __expf(o0)-1.f;
  pk.y = o1>0.f? o1 : __expf(o1)-1.f;
  *(float2*)(out2 + (long)n*HIDD + 2*lane) = pk;
}

// ---------------- fp32 projection GEMM (output-facing, keep fp32) ----------------
__global__ __launch_bounds__(256) void gemm_tile(const float* __restrict__ A, const float* __restrict__ B,
                                                 float* __restrict__ C, int M, int N, int K,
                                                 const float* __restrict__ bias,
                                                 const float* __restrict__ prelu_a, int epi){
  __shared__ float As[16][66];
  __shared__ float Bs[16][64];
  int tid = threadIdx.x;
  int m0 = blockIdx.y*64, n0 = blockIdx.x*64;
  int tm = (tid>>4)<<2, tn = (tid&15)<<2;
  float acc[4][4] = {};
  for(int k0=0; k0<K; k0+=16){
    #pragma unroll
    for(int i=0;i<4;i++){
      int idx = tid + i*256;
      int r = idx>>4, c = idx&15;
      int gr = m0 + r;
      As[c][r] = (gr<M)? A[(long)gr*K + k0 + c] : 0.f;
    }
    #pragma unroll
    for(int i=0;i<4;i++){
      int idx = tid + i*256;
      int r = idx>>6, c = idx&63;
      Bs[r][c] = B[(long)(k0+r)*N + n0 + c];
    }
    __syncthreads();
    #pragma unroll
    for(int k=0;k<16;k++){
      float a0=As[k][tm+0],a1=As[k][tm+1],a2=As[k][tm+2],a3=As[k][tm+3];
      float b0=Bs[k][tn+0],b1=Bs[k][tn+1],b2=Bs[k][tn+2],b3=Bs[k][tn+3];
      acc[0][0]+=a0*b0; acc[0][1]+=a0*b1; acc[0][2]+=a0*b2; acc[0][3]+=a0*b3;
      acc[1][0]+=a1*b0; acc[1][1]+=a1*b1; acc[1][2]+=a1*b2; acc[1][3]+=a1*b3;
      acc[2][0]+=a2*b0; acc[2][1]+=a2*b1; acc[2][2]+=a2*b2; acc[2][3]+=a2*b3;
      acc[3][0]+=a3*b0; acc[3][1]+=a3*b1; acc[3][2]+=a3*b2; acc[3][3]+=a3*b3;
    }
    __syncthreads();
  }
  float ap = (epi==1)? prelu_a[0] : 0.f;
  #pragma unroll
  for(int i=0;i<4;i++){
    int gr = m0+tm+i;
    if(gr>=M) continue;
    #pragma unroll
    for(int j=0;j<4;j++){
      int gc = n0+tn+j;
      float v = acc[i][j];
      if(epi>=1) v += bias[gc];
      if(epi==1) v = v>0.f? v : ap*v;
      C[(long)gr*N+gc] = v;
    }
  }
}

// ---------------- readout ----------------

__global__ void colsum(const float* __restrict__ hp, float* __restrict__ gbuf){
  int c = threadIdx.x;
  float acc = 0.f;
  for(int r = blockIdx.x; r < NN; r += gridDim.x) acc += hp[(long)r*HIDD + c];
  atomicAdd(&gbuf[c], acc);
}

__global__ void sigmoid_g(const float* __restrict__ gbuf, float* __restrict__ gout){
  int c = threadIdx.x;
  float m = gbuf[c] * (1.0f/NN);
  gout[c] = 1.f/(1.f+__expf(-m));
}

// ---------------- launch ----------------

extern "C" void kernel_launch(void* const* d_in, const int* in_sizes, int n_in,
                              void* d_out, int out_size, void* d_ws, size_t ws_size,
                              hipStream_t stream){
  const float* x    = (const float*)d_in[0];
  const int*   ei   = (const int*)  d_in[1];
  const float* ea   = (const float*)d_in[2];
  const float* W1   = (const float*)d_in[3];
  const float* We1  = (const float*)d_in[4];
  const float* as1  = (const float*)d_in[5];
  const float* ad1  = (const float*)d_in[6];
  const float* ae1  = (const float*)d_in[7];
  const float* b1   = (const float*)d_in[8];
  const float* W2   = (const float*)d_in[9];
  const float* We2  = (const float*)d_in[10];
  const float* as2  = (const float*)d_in[11];
  const float* ad2  = (const float*)d_in[12];
  const float* ae2  = (const float*)d_in[13];
  const float* b2   = (const float*)d_in[14];
  const float* P1   = (const float*)d_in[15];
  const float* pb1  = (const float*)d_in[16];
  const float* pra  = (const float*)d_in[17];
  const float* P2   = (const float*)d_in[18];
  const float* pb2  = (const float*)d_in[19];
  float* out = (float*)d_out;

  char* wsp = (char*)d_ws;
  size_t off = 0;
  auto alloc = [&](size_t bytes)->char*{
    char* p = wsp + off;
    off += (bytes + 255) & ~(size_t)255;
    return p;
  };
  ushort_t* h1b  = (ushort_t*)alloc(sizeof(ushort_t)*(size_t)NN*HH);    // 20.5 MB
  ushort_t* out1b= (ushort_t*)alloc(sizeof(ushort_t)*(size_t)NN*HH);    // 20.5 MB
  ushort_t* h2b  = (ushort_t*)alloc(sizeof(ushort_t)*(size_t)NN*HIDD);  // 5.1 MB
  float*    out2 = (float*)  alloc(sizeof(float)*(size_t)NN*HIDD);      // 10.2 MB
  float*    zb   = (float*)  alloc(sizeof(float)*(size_t)NN*HIDD);      // 10.2 MB
  ushort_t* xb   = (ushort_t*)alloc(sizeof(ushort_t)*(size_t)NN*FIN);   // 10.2 MB
  ushort_t* W1t  = (ushort_t*)alloc(sizeof(ushort_t)*(size_t)HH*FIN);
  ushort_t* W2t  = (ushort_t*)alloc(sizeof(ushort_t)*(size_t)HIDD*HH);
  float* s1n   = (float*)alloc(sizeof(float)*NN*NHEAD);
  float* d1n   = (float*)alloc(sizeof(float)*NN*NHEAD);
  float* s2n   = (float*)alloc(sizeof(float)*NN);
  float* d2n   = (float*)alloc(sizeof(float)*NN);
  float* v1    = (float*)alloc(sizeof(float)*FE*NHEAD);
  float* v2    = (float*)alloc(sizeof(float)*FE);
  float* gbuf  = (float*)alloc(sizeof(float)*HIDD);
  float* cae1  = (float*)alloc(sizeof(float)*(size_t)E2*NHEAD);  // 10.2 MB
  float* cae2  = (float*)alloc(sizeof(float)*(size_t)E2);        // 2.6 MB
  int*   rowptr= (int*)  alloc(sizeof(int)*(NN+1));
  int*   cnt   = (int*)  alloc(sizeof(int)*NN);
  int*   fcnt  = (int*)  alloc(sizeof(int)*NN);
  int*   csrc  = (int*)  alloc(sizeof(int)*(size_t)E2);          // 2.6 MB
  int*   cdst  = (int*)  alloc(sizeof(int)*(size_t)E2);          // 2.6 MB

  hipMemsetAsync(cnt,  0, sizeof(int)*NN, stream);
  hipMemsetAsync(fcnt, 0, sizeof(int)*NN, stream);
  hipMemsetAsync(gbuf, 0, sizeof(float)*HIDD, stream);

  // graph structure + edge logit terms
  count_edges<<<E2/256, 256, 0, stream>>>(ei, cnt);
  scan_k     <<<1, 1024, 0, stream>>>(cnt, rowptr);
  compute_v  <<<1, 192, 0, stream>>>(We1, ae1, We2, ae2, v1, v2);
  csr_fill   <<<E2/256, 256, 0, stream>>>(ei, ea, v1, v2, rowptr, fcnt, csrc, cdst, cae1, cae2);

  // casts
  cast_x<<<(NN*FIN/4 + 255)/256, 256, 0, stream>>>(x, xb, NN*FIN/4);
  castT <<<(FIN*HH + 255)/256, 256, 0, stream>>>(W1, W1t, FIN, HH);
  castT <<<(HH*HIDD + 255)/256, 256, 0, stream>>>(W2, W2t, HH, HIDD);

  // layer 1
  mfma_gemm   <<<dim3(HH/128, (NN+127)/128), 256, 0, stream>>>(xb, W1t, h1b, NN, HH, FIN);
  node_attn1  <<<NN, 256, 0, stream>>>(h1b, as1, ad1, s1n, d1n);
  edge_logits1<<<E2/256, 256, 0, stream>>>(csrc, cdst, s1n, d1n, cae1);
  agg1        <<<NN/4, 256, 0, stream>>>(h1b, rowptr, csrc, cae1, b1, out1b);

  // layer 2
  mfma_gemm   <<<dim3(HIDD/128, (NN+127)/128), 256, 0, stream>>>(out1b, W2t, h2b, NN, HIDD, HH);
  node_attn2  <<<NN/4, 256, 0, stream>>>(h2b, as2, ad2, s2n, d2n);
  edge_logits2<<<E2/256, 256, 0, stream>>>(csrc, cdst, s2n, d2n, cae2);
  agg2        <<<NN/4, 256, 0, stream>>>(h2b, rowptr, csrc, cae2, b2, out2);

  // projection head (fp32)
  gemm_tile<<<dim3(HIDD/64, (NN+63)/64), 256, 0, stream>>>(out2, P1, zb, NN, HIDD, HIDD, pb1, pra, 1);
  gemm_tile<<<dim3(HIDD/64, (NN+63)/64), 256, 0, stream>>>(zb, P2, out, NN, HIDD, HIDD, pb2, nullptr, 2);

  // g = sigmoid(mean(h_proj, axis=0))
  colsum   <<<256, 128, 0, stream>>>(out, gbuf);
  sigmoid_g<<<1, 128, 0, stream>>>(gbuf, out + (size_t)NN*HIDD);
}

// Round 5
// 488.346 us; speedup vs baseline: 1.6243x; 1.1254x over previous
//
#include <hip/hip_runtime.h>
#include <hip/hip_bf16.h>

// GRN_GAT_Encoder round 4:
// r3 post-mortem: agg1 latency-bound (VALU 29%, HBM 39%, both low) — serial gather loop
// lacks MLP. This round: online-softmax fused logit pass (kills edge_logits kernels +
// one cae1 sweep), gather loop unrolled x2 (dual outstanding 16B gathers), separate
// __restrict__ logit buffer to avoid may-alias store->load serialization.
// Also: 64x128 MFMA tile for layer-2 GEMM (157->313 blocks), prep-kernel fusion
// (count+casts+compute_v in one launch), one memset, cdst dropped. 21 -> 14 dispatches.

#define NN    20000
#define EE    320000
#define E2    640000
#define FIN   256
#define FE    32
#define HIDD  128
#define NHEAD 4
#define HH    512   // NHEAD*HIDD

typedef unsigned short ushort_t;
typedef short frag8 __attribute__((ext_vector_type(8)));   // 8 bf16 (4 VGPRs)
typedef float f32x4 __attribute__((ext_vector_type(4)));   // 4 fp32 acc

__device__ inline ushort_t f2bf(float f){               // RNE fp32->bf16
  unsigned x = __float_as_uint(f);
  unsigned r = (x + 0x7fffu + ((x>>16)&1u)) >> 16;
  return (ushort_t)r;
}
__device__ inline float lo_of(unsigned v){ return __uint_as_float(v<<16); }
__device__ inline float hi_of(unsigned v){ return __uint_as_float(v & 0xffff0000u); }

// ---------------- fused prep: count_edges | cast_x | castT(W1) | castT(W2) | compute_v ----
// blocks: [0,2500) count, [2500,7500) cast_x, [7500,8012) W1t, [8012,8268) W2t, 8268 v1/v2
__global__ void prep(const int* __restrict__ ei, int* __restrict__ cnt,
                     const float* __restrict__ x, ushort_t* __restrict__ xb,
                     const float* __restrict__ W1, ushort_t* __restrict__ W1t,
                     const float* __restrict__ W2, ushort_t* __restrict__ W2t,
                     const float* __restrict__ We1, const float* __restrict__ ae1,
                     const float* __restrict__ We2, const float* __restrict__ ae2,
                     float* __restrict__ v1, float* __restrict__ v2){
  int b = blockIdx.x, tid = threadIdx.x;
  if(b < 2500){
    int e = b*256 + tid;
    int dst = (e < EE) ? ei[EE + e] : ei[e - EE];
    atomicAdd(&cnt[dst], 1);
  } else if(b < 7500){
    int i = (b-2500)*256 + tid;                 // NN*FIN/4 = 1,280,000 exactly
    float4 v = ((const float4*)x)[i];
    ushort4 o; o.x=f2bf(v.x); o.y=f2bf(v.y); o.z=f2bf(v.z); o.w=f2bf(v.w);
    ((ushort4*)xb)[i] = o;
  } else if(b < 8012){
    int idx = (b-7500)*256 + tid;               // FIN*HH = 131072 exactly
    int k = idx>>9, n = idx&511;
    W1t[n*FIN + k] = f2bf(W1[idx]);
  } else if(b < 8268){
    int idx = (b-8012)*256 + tid;               // HH*HIDD = 65536 exactly
    int k = idx>>7, n = idx&127;
    W2t[n*HH + k] = f2bf(W2[idx]);
  } else {
    if(tid < FE*NHEAD){
      int f = tid>>2, h = tid&3;
      float s = 0.f;
      for(int c=0;c<HIDD;c++) s += We1[f*HH + h*HIDD + c] * ae1[h*HIDD + c];
      v1[f*4+h] = s;
    } else if(tid < FE*NHEAD + FE){
      int f = tid - FE*NHEAD;
      float s = 0.f;
      for(int c=0;c<HIDD;c++) s += We2[f*HIDD + c] * ae2[c];
      v2[f] = s;
    }
  }
}

__global__ void scan_k(const int* __restrict__ cnt, int* __restrict__ rowptr){
  __shared__ int sums[1024];
  int tid = threadIdx.x;
  const int per = (NN + 1023)/1024;  // 20
  int base = tid*per;
  int s = 0;
  for(int i=0;i<per;i++){ int idx=base+i; if(idx<NN) s += cnt[idx]; }
  sums[tid] = s; __syncthreads();
  for(int off=1; off<1024; off<<=1){
    int v = (tid>=off)? sums[tid-off] : 0;
    __syncthreads();
    sums[tid] += v;
    __syncthreads();
  }
  int run = (tid==0)? 0 : sums[tid-1];
  for(int i=0;i<per;i++){
    int idx = base+i;
    if(idx<=NN) rowptr[idx] = run;
    if(idx<NN)  run += cnt[idx];
  }
}

__global__ void csr_fill(const int* __restrict__ ei, const float* __restrict__ ea,
                         const float* __restrict__ v1, const float* __restrict__ v2,
                         const int* __restrict__ rowptr, int* __restrict__ fcnt,
                         int* __restrict__ csrc, float* __restrict__ cae1, float* __restrict__ cae2){
  __shared__ float sv1[FE*NHEAD];
  __shared__ float sv2[FE];
  int tid = threadIdx.x;
  if(tid < FE*NHEAD) sv1[tid] = v1[tid];
  if(tid < FE)       sv2[tid] = v2[tid];
  __syncthreads();
  int e = blockIdx.x*256 + tid;
  int src, dst, row;
  if(e < EE){ src = ei[e];       dst = ei[EE+e]; row = e; }
  else      { int e0=e-EE; src = ei[EE+e0]; dst = ei[e0]; row = e0; }
  const float4* er4 = (const float4*)(ea + (long)row*FE);
  float a0=0,a1=0,a2=0,a3=0,ab=0;
  #pragma unroll
  for(int f4=0; f4<FE/4; f4++){
    float4 t = er4[f4];
    float tv[4] = {t.x, t.y, t.z, t.w};
    #pragma unroll
    for(int c=0;c<4;c++){
      int f = f4*4+c;
      float t1 = tv[c];
      a0 += t1*sv1[f*4+0]; a1 += t1*sv1[f*4+1]; a2 += t1*sv1[f*4+2]; a3 += t1*sv1[f*4+3];
      ab += t1*sv2[f];
    }
  }
  int pos = rowptr[dst] + atomicAdd(&fcnt[dst], 1);
  csrc[pos] = src;
  cae1[pos*4+0]=a0; cae1[pos*4+1]=a1; cae1[pos*4+2]=a2; cae1[pos*4+3]=a3;
  cae2[pos] = ab;
}

// ---------------- MFMA bf16 GEMM 128x128: C[M,N] = A[M,K] @ Bt[N,K]^T ----------------
__global__ __launch_bounds__(256) void mfma_gemm(const ushort_t* __restrict__ A, const ushort_t* __restrict__ Bt,
                                                 ushort_t* __restrict__ C, int M, int N, int K){
  __shared__ ushort_t As[128*32];
  __shared__ ushort_t Bs[128*32];
  int tid = threadIdx.x;
  int m0 = blockIdx.y*128, n0 = blockIdx.x*128;
  int w = tid>>6, lane = tid&63;
  int qr = (w>>1)*64, qc = (w&1)*64;
  int lrow = lane&15, koff = (lane>>4)*8;
  f32x4 acc[4][4] = {};
  for(int k0=0; k0<K; k0+=32){
    #pragma unroll
    for(int rep=0;rep<2;rep++){
      int segid = tid + rep*256;          // 512 segments of 8 bf16 (16B)
      int row = segid>>2, off = (segid&3)*8;
      int gr = m0 + row;
      int4 va = (gr<M) ? *(const int4*)(A + (long)gr*K + k0 + off) : int4{0,0,0,0};
      *(int4*)&As[row*32 + off] = va;
      int4 vb = *(const int4*)(Bt + (long)(n0+row)*K + k0 + off);
      *(int4*)&Bs[row*32 + off] = vb;
    }
    __syncthreads();
    frag8 af[4], bfr[4];
    #pragma unroll
    for(int i=0;i<4;i++) af[i]  = *(const frag8*)&As[(qr + i*16 + lrow)*32 + koff];
    #pragma unroll
    for(int j=0;j<4;j++) bfr[j] = *(const frag8*)&Bs[(qc + j*16 + lrow)*32 + koff];
    #pragma unroll
    for(int i=0;i<4;i++)
      #pragma unroll
      for(int j=0;j<4;j++)
        acc[i][j] = __builtin_amdgcn_mfma_f32_16x16x32_bf16(af[i], bfr[j], acc[i][j], 0,0,0);
    __syncthreads();
  }
  #pragma unroll
  for(int i=0;i<4;i++)
    #pragma unroll
    for(int j=0;j<4;j++)
      #pragma unroll
      for(int r=0;r<4;r++){
        int row = m0 + qr + i*16 + (lane>>4)*4 + r;
        int col = n0 + qc + j*16 + (lane&15);
        if(row<M) C[(long)row*N + col] = f2bf(acc[i][j][r]);
      }
}

// ---------------- MFMA bf16 GEMM 64x128 tile (better block count for N=128) ----------
__global__ __launch_bounds__(256) void mfma_gemm64(const ushort_t* __restrict__ A, const ushort_t* __restrict__ Bt,
                                                   ushort_t* __restrict__ C, int M, int N, int K){
  __shared__ ushort_t As[64*32];
  __shared__ ushort_t Bs[128*32];
  int tid = threadIdx.x;
  int m0 = blockIdx.y*64, n0 = blockIdx.x*128;
  int w = tid>>6, lane = tid&63;
  int qc = w*32;
  int lrow = lane&15, koff = (lane>>4)*8;
  f32x4 acc[4][2] = {};
  for(int k0=0; k0<K; k0+=32){
    {
      int row = tid>>2, off = (tid&3)*8;    // 256 segs = 64 rows x 4
      int gr = m0 + row;
      int4 va = (gr<M) ? *(const int4*)(A + (long)gr*K + k0 + off) : int4{0,0,0,0};
      *(int4*)&As[row*32 + off] = va;
    }
    #pragma unroll
    for(int rep=0;rep<2;rep++){
      int segid = tid + rep*256;            // 512 segs = 128 rows x 4
      int row = segid>>2, off = (segid&3)*8;
      int4 vb = *(const int4*)(Bt + (long)(n0+row)*K + k0 + off);
      *(int4*)&Bs[row*32 + off] = vb;
    }
    __syncthreads();
    frag8 af[4], bfr[2];
    #pragma unroll
    for(int i=0;i<4;i++) af[i]  = *(const frag8*)&As[(i*16 + lrow)*32 + koff];
    #pragma unroll
    for(int j=0;j<2;j++) bfr[j] = *(const frag8*)&Bs[(qc + j*16 + lrow)*32 + koff];
    #pragma unroll
    for(int i=0;i<4;i++)
      #pragma unroll
      for(int j=0;j<2;j++)
        acc[i][j] = __builtin_amdgcn_mfma_f32_16x16x32_bf16(af[i], bfr[j], acc[i][j], 0,0,0);
    __syncthreads();
  }
  #pragma unroll
  for(int i=0;i<4;i++)
    #pragma unroll
    for(int j=0;j<2;j++)
      #pragma unroll
      for(int r=0;r<4;r++){
        int row = m0 + i*16 + (lane>>4)*4 + r;
        int col = n0 + qc + j*16 + (lane&15);
        if(row<M) C[(long)row*N + col] = f2bf(acc[i][j][r]);
      }
}

// ---------------- per-node attention scalars (bf16 h) ----------------

__device__ inline float wsum4(float v){   // sum over lanes with same (lane&3)
  #pragma unroll
  for(int o=4;o<=32;o<<=1) v += __shfl_xor(v, o, 64);
  return v;
}

__global__ void node_attn1(const ushort_t* __restrict__ h1b, const float* __restrict__ as1,
                           const float* __restrict__ ad1, float* __restrict__ s1n, float* __restrict__ d1n){
  int n = blockIdx.x;
  int wv = threadIdx.x>>6, lane = threadIdx.x&63;
  unsigned v = *(const unsigned*)(h1b + (long)n*HH + wv*HIDD + 2*lane);
  float f0 = lo_of(v), f1 = hi_of(v);
  float s = f0*as1[wv*HIDD+2*lane] + f1*as1[wv*HIDD+2*lane+1];
  float d = f0*ad1[wv*HIDD+2*lane] + f1*ad1[wv*HIDD+2*lane+1];
  #pragma unroll
  for(int o=32;o>0;o>>=1){ s += __shfl_xor(s,o,64); d += __shfl_xor(d,o,64); }
  if(lane==0){ s1n[n*4+wv]=s; d1n[n*4+wv]=d; }
}

__global__ void node_attn2(const ushort_t* __restrict__ h2b, const float* __restrict__ as2,
                           const float* __restrict__ ad2, float* __restrict__ s2n, float* __restrict__ d2n){
  int n = blockIdx.x*4 + (threadIdx.x>>6);
  int lane = threadIdx.x&63;
  unsigned v = *(const unsigned*)(h2b + (long)n*HIDD + 2*lane);
  float f0 = lo_of(v), f1 = hi_of(v);
  float s = f0*as2[2*lane] + f1*as2[2*lane+1];
  float d = f0*ad2[2*lane] + f1*ad2[2*lane+1];
  #pragma unroll
  for(int o=32;o>0;o>>=1){ s += __shfl_xor(s,o,64); d += __shfl_xor(d,o,64); }
  if(lane==0){ s2n[n]=s; d2n[n]=d; }
}

// ---------------- agg1: online-softmax logits + x2-unrolled gather ----------------
// wave = node. pass1 (lane=(edge,head)): logit=lrelu(s1n[src]+d1n[n]+cae1), store to
// elog (restrict, no alias), online (m,s). gather (lane=8 channels): w=exp(logit-m)*inv.

__global__ void agg1(const ushort_t* __restrict__ h1b, const int* __restrict__ rowptr,
                     const int* __restrict__ csrc,
                     const float* __restrict__ s1n, const float* __restrict__ d1n,
                     const float* __restrict__ cae1, float* __restrict__ elog,
                     const float* __restrict__ b1, ushort_t* __restrict__ out1b){
  int n = blockIdx.x*4 + (threadIdx.x>>6);
  int lane = threadIdx.x&63;
  int beg = rowptr[n], end = rowptr[n+1];
  int h12 = lane&3;
  float dh = d1n[n*4 + h12];
  float m = -1e30f, ss = 0.f;
  for(int base=beg; base<end; base+=16){
    int e = base + (lane>>2);
    if(e<end){
      float t = s1n[csrc[e]*4 + h12] + dh + cae1[e*4 + h12];
      t = t>0.f? t : 0.2f*t;
      elog[e*4 + h12] = t;
      float nm = fmaxf(m, t);
      ss = ss*__expf(m-nm) + __expf(t-nm);
      m = nm;
    }
  }
  #pragma unroll
  for(int o=4;o<=32;o<<=1){
    float mo = __shfl_xor(m, o, 64), so = __shfl_xor(ss, o, 64);
    float nm = fmaxf(m, mo);
    ss = ss*__expf(m-nm) + so*__expf(mo-nm);
    m = nm;
  }
  float inv = ss>0.f ? 1.f/ss : 0.f;
  int hq = lane>>4;
  float mq   = __shfl(m,   hq, 64);
  float invq = __shfl(inv, hq, 64);
  float acc[8] = {};
  int i = beg;
  for(; i+1<end; i+=2){
    int s0 = csrc[i], s1 = csrc[i+1];
    float w0 = __expf(elog[i*4 + hq]     - mq)*invq;
    float w1 = __expf(elog[(i+1)*4 + hq] - mq)*invq;
    uint4 v0 = *(const uint4*)(h1b + (long)s0*HH + lane*8);
    uint4 v1 = *(const uint4*)(h1b + (long)s1*HH + lane*8);
    acc[0] += w0*lo_of(v0.x) + w1*lo_of(v1.x); acc[1] += w0*hi_of(v0.x) + w1*hi_of(v1.x);
    acc[2] += w0*lo_of(v0.y) + w1*lo_of(v1.y); acc[3] += w0*hi_of(v0.y) + w1*hi_of(v1.y);
    acc[4] += w0*lo_of(v0.z) + w1*lo_of(v1.z); acc[5] += w0*hi_of(v0.z) + w1*hi_of(v1.z);
    acc[6] += w0*lo_of(v0.w) + w1*lo_of(v1.w); acc[7] += w0*hi_of(v0.w) + w1*hi_of(v1.w);
  }
  if(i<end){
    int s0 = csrc[i];
    float w0 = __expf(elog[i*4 + hq] - mq)*invq;
    uint4 v0 = *(const uint4*)(h1b + (long)s0*HH + lane*8);
    acc[0] += w0*lo_of(v0.x); acc[1] += w0*hi_of(v0.x);
    acc[2] += w0*lo_of(v0.y); acc[3] += w0*hi_of(v0.y);
    acc[4] += w0*lo_of(v0.z); acc[5] += w0*hi_of(v0.z);
    acc[6] += w0*lo_of(v0.w); acc[7] += w0*hi_of(v0.w);
  }
  float4 bl = ((const float4*)b1)[lane*2];
  float4 bh = ((const float4*)b1)[lane*2+1];
  float bb[8] = {bl.x,bl.y,bl.z,bl.w,bh.x,bh.y,bh.z,bh.w};
  ushort_t o8[8];
  #pragma unroll
  for(int c=0;c<8;c++){
    float o = acc[c] + bb[c];
    o8[c] = f2bf(o>0.f? o : __expf(o)-1.f);   // ELU
  }
  uint4 pk;
  pk.x = (unsigned)o8[0] | ((unsigned)o8[1]<<16);
  pk.y = (unsigned)o8[2] | ((unsigned)o8[3]<<16);
  pk.z = (unsigned)o8[4] | ((unsigned)o8[5]<<16);
  pk.w = (unsigned)o8[6] | ((unsigned)o8[7]<<16);
  *(uint4*)(out1b + (long)n*HH + lane*8) = pk;
}

__global__ void agg2(const ushort_t* __restrict__ h2b, const int* __restrict__ rowptr,
                     const int* __restrict__ csrc,
                     const float* __restrict__ s2n, const float* __restrict__ d2n,
                     const float* __restrict__ cae2, float* __restrict__ elog,
                     const float* __restrict__ b2, float* __restrict__ out2){
  int n = blockIdx.x*4 + (threadIdx.x>>6);
  int lane = threadIdx.x&63;
  int beg = rowptr[n], end = rowptr[n+1];
  float dn = d2n[n];
  float m = -1e30f, ss = 0.f;
  for(int e=beg+lane; e<end; e+=64){
    float t = s2n[csrc[e]] + dn + cae2[e];
    t = t>0.f? t : 0.2f*t;
    elog[e] = t;
    float nm = fmaxf(m, t);
    ss = ss*__expf(m-nm) + __expf(t-nm);
    m = nm;
  }
  #pragma unroll
  for(int o=1;o<=32;o<<=1){
    float mo = __shfl_xor(m, o, 64), so = __shfl_xor(ss, o, 64);
    float nm = fmaxf(m, mo);
    ss = ss*__expf(m-nm) + so*__expf(mo-nm);
    m = nm;
  }
  float inv = ss>0.f ? 1.f/ss : 0.f;
  float a0=0.f, a1=0.f;
  int i = beg;
  for(; i+1<end; i+=2){
    int s0 = csrc[i], s1 = csrc[i+1];
    float w0 = __expf(elog[i]-m)*inv;
    float w1 = __expf(elog[i+1]-m)*inv;
    unsigned v0 = *(const unsigned*)(h2b + (long)s0*HIDD + 2*lane);
    unsigned v1 = *(const unsigned*)(h2b + (long)s1*HIDD + 2*lane);
    a0 += w0*lo_of(v0) + w1*lo_of(v1);
    a1 += w0*hi_of(v0) + w1*hi_of(v1);
  }
  if(i<end){
    float w0 = __expf(elog[i]-m)*inv;
    unsigned v0 = *(const unsigned*)(h2b + (long)csrc[i]*HIDD + 2*lane);
    a0 += w0*lo_of(v0); a1 += w0*hi_of(v0);
  }
  float o0 = a0 + b2[2*lane];
  float o1 = a1 + b2[2*lane+1];
  float2 pk;
  pk.x = o0>0.f? o0 : __expf(o0)-1.f;
  pk.y = o1>0.f? o1 : __expf(o1)-1.f;
  *(float2*)(out2 + (long)n*HIDD + 2*lane) = pk;
}

// ---------------- fp32 projection GEMM (output-facing, keep fp32) ----------------
__global__ __launch_bounds__(256) void gemm_tile(const float* __restrict__ A, const float* __restrict__ B,
                                                 float* __restrict__ C, int M, int N, int K,
                                                 const float* __restrict__ bias,
                                                 const float* __restrict__ prelu_a, int epi){
  __shared__ float As[16][66];
  __shared__ float Bs[16][64];
  int tid = threadIdx.x;
  int m0 = blockIdx.y*64, n0 = blockIdx.x*64;
  int tm = (tid>>4)<<2, tn = (tid&15)<<2;
  float acc[4][4] = {};
  for(int k0=0; k0<K; k0+=16){
    #pragma unroll
    for(int i=0;i<4;i++){
      int idx = tid + i*256;
      int r = idx>>4, c = idx&15;
      int gr = m0 + r;
      As[c][r] = (gr<M)? A[(long)gr*K + k0 + c] : 0.f;
    }
    #pragma unroll
    for(int i=0;i<4;i++){
      int idx = tid + i*256;
      int r = idx>>6, c = idx&63;
      Bs[r][c] = B[(long)(k0+r)*N + n0 + c];
    }
    __syncthreads();
    #pragma unroll
    for(int k=0;k<16;k++){
      float a0=As[k][tm+0],a1=As[k][tm+1],a2=As[k][tm+2],a3=As[k][tm+3];
      float b0=Bs[k][tn+0],b1=Bs[k][tn+1],b2=Bs[k][tn+2],b3=Bs[k][tn+3];
      acc[0][0]+=a0*b0; acc[0][1]+=a0*b1; acc[0][2]+=a0*b2; acc[0][3]+=a0*b3;
      acc[1][0]+=a1*b0; acc[1][1]+=a1*b1; acc[1][2]+=a1*b2; acc[1][3]+=a1*b3;
      acc[2][0]+=a2*b0; acc[2][1]+=a2*b1; acc[2][2]+=a2*b2; acc[2][3]+=a2*b3;
      acc[3][0]+=a3*b0; acc[3][1]+=a3*b1; acc[3][2]+=a3*b2; acc[3][3]+=a3*b3;
    }
    __syncthreads();
  }
  float ap = (epi==1)? prelu_a[0] : 0.f;
  #pragma unroll
  for(int i=0;i<4;i++){
    int gr = m0+tm+i;
    if(gr>=M) continue;
    #pragma unroll
    for(int j=0;j<4;j++){
      int gc = n0+tn+j;
      float v = acc[i][j];
      if(epi>=1) v += bias[gc];
      if(epi==1) v = v>0.f? v : ap*v;
      C[(long)gr*N+gc] = v;
    }
  }
}

// ---------------- readout ----------------

__global__ void colsum(const float* __restrict__ hp, float* __restrict__ gbuf){
  int c = threadIdx.x;
  float acc = 0.f;
  for(int r = blockIdx.x; r < NN; r += gridDim.x) acc += hp[(long)r*HIDD + c];
  atomicAdd(&gbuf[c], acc);
}

__global__ void sigmoid_g(const float* __restrict__ gbuf, float* __restrict__ gout){
  int c = threadIdx.x;
  float m = gbuf[c] * (1.0f/NN);
  gout[c] = 1.f/(1.f+__expf(-m));
}

// ---------------- launch ----------------

extern "C" void kernel_launch(void* const* d_in, const int* in_sizes, int n_in,
                              void* d_out, int out_size, void* d_ws, size_t ws_size,
                              hipStream_t stream){
  const float* x    = (const float*)d_in[0];
  const int*   ei   = (const int*)  d_in[1];
  const float* ea   = (const float*)d_in[2];
  const float* W1   = (const float*)d_in[3];
  const float* We1  = (const float*)d_in[4];
  const float* as1  = (const float*)d_in[5];
  const float* ad1  = (const float*)d_in[6];
  const float* ae1  = (const float*)d_in[7];
  const float* b1   = (const float*)d_in[8];
  const float* W2   = (const float*)d_in[9];
  const float* We2  = (const float*)d_in[10];
  const float* as2  = (const float*)d_in[11];
  const float* ad2  = (const float*)d_in[12];
  const float* ae2  = (const float*)d_in[13];
  const float* b2   = (const float*)d_in[14];
  const float* P1   = (const float*)d_in[15];
  const float* pb1  = (const float*)d_in[16];
  const float* pra  = (const float*)d_in[17];
  const float* P2   = (const float*)d_in[18];
  const float* pb2  = (const float*)d_in[19];
  float* out = (float*)d_out;

  char* wsp = (char*)d_ws;
  size_t off = 0;
  auto alloc = [&](size_t bytes)->char*{
    char* p = wsp + off;
    off += (bytes + 255) & ~(size_t)255;
    return p;
  };
  ushort_t* h1b  = (ushort_t*)alloc(sizeof(ushort_t)*(size_t)NN*HH);
  ushort_t* out1b= (ushort_t*)alloc(sizeof(ushort_t)*(size_t)NN*HH);
  ushort_t* h2b  = (ushort_t*)alloc(sizeof(ushort_t)*(size_t)NN*HIDD);
  float*    out2 = (float*)  alloc(sizeof(float)*(size_t)NN*HIDD);
  float*    zb   = (float*)  alloc(sizeof(float)*(size_t)NN*HIDD);
  ushort_t* xb   = (ushort_t*)alloc(sizeof(ushort_t)*(size_t)NN*FIN);
  ushort_t* W1t  = (ushort_t*)alloc(sizeof(ushort_t)*(size_t)HH*FIN);
  ushort_t* W2t  = (ushort_t*)alloc(sizeof(ushort_t)*(size_t)HIDD*HH);
  float* s1n   = (float*)alloc(sizeof(float)*NN*NHEAD);
  float* d1n   = (float*)alloc(sizeof(float)*NN*NHEAD);
  float* s2n   = (float*)alloc(sizeof(float)*NN);
  float* d2n   = (float*)alloc(sizeof(float)*NN);
  float* v1    = (float*)alloc(sizeof(float)*FE*NHEAD);
  float* v2    = (float*)alloc(sizeof(float)*FE);
  float* cae1  = (float*)alloc(sizeof(float)*(size_t)E2*NHEAD);
  float* elog1 = (float*)alloc(sizeof(float)*(size_t)E2*NHEAD);
  float* cae2  = (float*)alloc(sizeof(float)*(size_t)E2);
  float* elog2 = (float*)alloc(sizeof(float)*(size_t)E2);
  int*   rowptr= (int*)  alloc(sizeof(int)*(NN+1));
  int*   csrc  = (int*)  alloc(sizeof(int)*(size_t)E2);
  // zero-init trio: keep adjacent for one memset
  int*   cnt   = (int*)  alloc(sizeof(int)*NN);     // 80128 B span
  int*   fcnt  = (int*)  alloc(sizeof(int)*NN);     // 80128 B span
  float* gbuf  = (float*)alloc(sizeof(float)*HIDD); // 512 B span

  hipMemsetAsync(cnt, 0, 80128 + 80128 + 512, stream);

  prep    <<<8269, 256, 0, stream>>>(ei, cnt, x, xb, W1, W1t, W2, W2t, We1, ae1, We2, ae2, v1, v2);
  scan_k  <<<1, 1024, 0, stream>>>(cnt, rowptr);
  csr_fill<<<E2/256, 256, 0, stream>>>(ei, ea, v1, v2, rowptr, fcnt, csrc, cae1, cae2);

  // layer 1
  mfma_gemm <<<dim3(HH/128, (NN+127)/128), 256, 0, stream>>>(xb, W1t, h1b, NN, HH, FIN);
  node_attn1<<<NN, 256, 0, stream>>>(h1b, as1, ad1, s1n, d1n);
  agg1      <<<NN/4, 256, 0, stream>>>(h1b, rowptr, csrc, s1n, d1n, cae1, elog1, b1, out1b);

  // layer 2
  mfma_gemm64<<<dim3(1, (NN+63)/64), 256, 0, stream>>>(out1b, W2t, h2b, NN, HIDD, HH);
  node_attn2 <<<NN/4, 256, 0, stream>>>(h2b, as2, ad2, s2n, d2n);
  agg2       <<<NN/4, 256, 0, stream>>>(h2b, rowptr, csrc, s2n, d2n, cae2, elog2, b2, out2);

  // projection head (fp32)
  gemm_tile<<<dim3(HIDD/64, (NN+63)/64), 256, 0, stream>>>(out2, P1, zb, NN, HIDD, HIDD, pb1, pra, 1);
  gemm_tile<<<dim3(HIDD/64, (NN+63)/64), 256, 0, stream>>>(zb, P2, out, NN, HIDD, HIDD, pb2, nullptr, 2);

  // g = sigmoid(mean(h_proj, axis=0))
  colsum   <<<256, 128, 0, stream>>>(out, gbuf);
  sigmoid_g<<<1, 128, 0, stream>>>(gbuf, out + (size_t)NN*HIDD);
}

// Round 6
// 448.668 us; speedup vs baseline: 1.7679x; 1.0884x over previous
//
#include <hip/hip_runtime.h>
#include <hip/hip_bf16.h>

// GRN_GAT_Encoder round 6:
// r5 post-mortem: agg1 near its fabric floor (43% L2-miss on random gather of 20.5MB h1b).
// Real target = the ~200us hiding in the two fp32 vector proj GEMMs (~3 TF each, just
// under agg1 in the top-5). This round:
//  - proj head via SPLIT-bf16 MFMA (A=Ah+Al, B=Bh+Bl; AhBh+AhBl+AlBh, fp32 accum)
//    -> fp32-equivalent accuracy, no new absmax risk, ~10x faster.
//  - csr_fill computes shared edge term once, writes fwd+rev CSR slots (halves ea reads).
//  - agg1/agg2 gather unrolled x4 (more outstanding 16B gathers).

#define NN    20000
#define EE    320000
#define E2    640000
#define FIN   256
#define FE    32
#define HIDD  128
#define NHEAD 4
#define HH    512   // NHEAD*HIDD

typedef unsigned short ushort_t;
typedef short frag8 __attribute__((ext_vector_type(8)));   // 8 bf16 (4 VGPRs)
typedef float f32x4 __attribute__((ext_vector_type(4)));   // 4 fp32 acc

__device__ inline ushort_t f2bf(float f){               // RNE fp32->bf16
  unsigned x = __float_as_uint(f);
  unsigned r = (x + 0x7fffu + ((x>>16)&1u)) >> 16;
  return (ushort_t)r;
}
__device__ inline float bf2f(ushort_t u){ return __uint_as_float(((unsigned)u)<<16); }
__device__ inline float lo_of(unsigned v){ return __uint_as_float(v<<16); }
__device__ inline float hi_of(unsigned v){ return __uint_as_float(v & 0xffff0000u); }

// ---------------- fused prep ----------------
// blocks: [0,2500) count | [2500,7500) cast_x | [7500,8012) W1t | [8012,8268) W2t
//         [8268,8332) P1 split-T | [8332,8396) P2 split-T | 8396 v1/v2
__global__ void prep(const int* __restrict__ ei, int* __restrict__ cnt,
                     const float* __restrict__ x, ushort_t* __restrict__ xb,
                     const float* __restrict__ W1, ushort_t* __restrict__ W1t,
                     const float* __restrict__ W2, ushort_t* __restrict__ W2t,
                     const float* __restrict__ P1, ushort_t* __restrict__ P1th, ushort_t* __restrict__ P1tl,
                     const float* __restrict__ P2, ushort_t* __restrict__ P2th, ushort_t* __restrict__ P2tl,
                     const float* __restrict__ We1, const float* __restrict__ ae1,
                     const float* __restrict__ We2, const float* __restrict__ ae2,
                     float* __restrict__ v1, float* __restrict__ v2){
  int b = blockIdx.x, tid = threadIdx.x;
  if(b < 2500){
    int e = b*256 + tid;
    int dst = (e < EE) ? ei[EE + e] : ei[e - EE];
    atomicAdd(&cnt[dst], 1);
  } else if(b < 7500){
    int i = (b-2500)*256 + tid;                 // NN*FIN/4 = 1,280,000 exactly
    float4 v = ((const float4*)x)[i];
    ushort4 o; o.x=f2bf(v.x); o.y=f2bf(v.y); o.z=f2bf(v.z); o.w=f2bf(v.w);
    ((ushort4*)xb)[i] = o;
  } else if(b < 8012){
    int idx = (b-7500)*256 + tid;               // FIN*HH = 131072
    int k = idx>>9, n = idx&511;
    W1t[n*FIN + k] = f2bf(W1[idx]);
  } else if(b < 8268){
    int idx = (b-8012)*256 + tid;               // HH*HIDD = 65536
    int k = idx>>7, n = idx&127;
    W2t[n*HH + k] = f2bf(W2[idx]);
  } else if(b < 8332){
    int idx = (b-8268)*256 + tid;               // HIDD*HIDD = 16384
    int k = idx>>7, n = idx&127;
    float v = P1[idx];
    ushort_t h = f2bf(v);
    P1th[n*HIDD + k] = h;
    P1tl[n*HIDD + k] = f2bf(v - bf2f(h));
  } else if(b < 8396){
    int idx = (b-8332)*256 + tid;
    int k = idx>>7, n = idx&127;
    float v = P2[idx];
    ushort_t h = f2bf(v);
    P2th[n*HIDD + k] = h;
    P2tl[n*HIDD + k] = f2bf(v - bf2f(h));
  } else {
    if(tid < FE*NHEAD){
      int f = tid>>2, h = tid&3;
      float s = 0.f;
      for(int c=0;c<HIDD;c++) s += We1[f*HH + h*HIDD + c] * ae1[h*HIDD + c];
      v1[f*4+h] = s;
    } else if(tid < FE*NHEAD + FE){
      int f = tid - FE*NHEAD;
      float s = 0.f;
      for(int c=0;c<HIDD;c++) s += We2[f*HIDD + c] * ae2[c];
      v2[f] = s;
    }
  }
}

__global__ void scan_k(const int* __restrict__ cnt, int* __restrict__ rowptr){
  __shared__ int sums[1024];
  int tid = threadIdx.x;
  const int per = (NN + 1023)/1024;  // 20
  int base = tid*per;
  int s = 0;
  for(int i=0;i<per;i++){ int idx=base+i; if(idx<NN) s += cnt[idx]; }
  sums[tid] = s; __syncthreads();
  for(int off=1; off<1024; off<<=1){
    int v = (tid>=off)? sums[tid-off] : 0;
    __syncthreads();
    sums[tid] += v;
    __syncthreads();
  }
  int run = (tid==0)? 0 : sums[tid-1];
  for(int i=0;i<per;i++){
    int idx = base+i;
    if(idx<=NN) rowptr[idx] = run;
    if(idx<NN)  run += cnt[idx];
  }
}

// fwd edge (a->b) and rev edge (b->a) share the same ea row => same edge-logit terms.
__global__ void csr_fill(const int* __restrict__ ei, const float* __restrict__ ea,
                         const float* __restrict__ v1, const float* __restrict__ v2,
                         const int* __restrict__ rowptr, int* __restrict__ fcnt,
                         int* __restrict__ csrc, float* __restrict__ cae1, float* __restrict__ cae2){
  __shared__ float sv1[FE*NHEAD];
  __shared__ float sv2[FE];
  int tid = threadIdx.x;
  if(tid < FE*NHEAD) sv1[tid] = v1[tid];
  if(tid < FE)       sv2[tid] = v2[tid];
  __syncthreads();
  int e = blockIdx.x*256 + tid;                // grid EE/256 = 1250
  int a = ei[e], b = ei[EE+e];
  const float4* er4 = (const float4*)(ea + (long)e*FE);
  float a0=0,a1=0,a2=0,a3=0,ab=0;
  #pragma unroll
  for(int f4=0; f4<FE/4; f4++){
    float4 t = er4[f4];
    float tv[4] = {t.x, t.y, t.z, t.w};
    #pragma unroll
    for(int c=0;c<4;c++){
      int f = f4*4+c;
      float t1 = tv[c];
      a0 += t1*sv1[f*4+0]; a1 += t1*sv1[f*4+1]; a2 += t1*sv1[f*4+2]; a3 += t1*sv1[f*4+3];
      ab += t1*sv2[f];
    }
  }
  int pos = rowptr[b] + atomicAdd(&fcnt[b], 1);    // fwd: src=a, dst=b
  csrc[pos] = a;
  cae1[pos*4+0]=a0; cae1[pos*4+1]=a1; cae1[pos*4+2]=a2; cae1[pos*4+3]=a3;
  cae2[pos] = ab;
  pos = rowptr[a] + atomicAdd(&fcnt[a], 1);        // rev: src=b, dst=a
  csrc[pos] = b;
  cae1[pos*4+0]=a0; cae1[pos*4+1]=a1; cae1[pos*4+2]=a2; cae1[pos*4+3]=a3;
  cae2[pos] = ab;
}

// ---------------- MFMA bf16 GEMM 128x128: C[M,N] = A[M,K] @ Bt[N,K]^T ----------------
__global__ __launch_bounds__(256) void mfma_gemm(const ushort_t* __restrict__ A, const ushort_t* __restrict__ Bt,
                                                 ushort_t* __restrict__ C, int M, int N, int K){
  __shared__ ushort_t As[128*32];
  __shared__ ushort_t Bs[128*32];
  int tid = threadIdx.x;
  int m0 = blockIdx.y*128, n0 = blockIdx.x*128;
  int w = tid>>6, lane = tid&63;
  int qr = (w>>1)*64, qc = (w&1)*64;
  int lrow = lane&15, koff = (lane>>4)*8;
  f32x4 acc[4][4] = {};
  for(int k0=0; k0<K; k0+=32){
    #pragma unroll
    for(int rep=0;rep<2;rep++){
      int segid = tid + rep*256;
      int row = segid>>2, off = (segid&3)*8;
      int gr = m0 + row;
      int4 va = (gr<M) ? *(const int4*)(A + (long)gr*K + k0 + off) : int4{0,0,0,0};
      *(int4*)&As[row*32 + off] = va;
      int4 vb = *(const int4*)(Bt + (long)(n0+row)*K + k0 + off);
      *(int4*)&Bs[row*32 + off] = vb;
    }
    __syncthreads();
    frag8 af[4], bfr[4];
    #pragma unroll
    for(int i=0;i<4;i++) af[i]  = *(const frag8*)&As[(qr + i*16 + lrow)*32 + koff];
    #pragma unroll
    for(int j=0;j<4;j++) bfr[j] = *(const frag8*)&Bs[(qc + j*16 + lrow)*32 + koff];
    #pragma unroll
    for(int i=0;i<4;i++)
      #pragma unroll
      for(int j=0;j<4;j++)
        acc[i][j] = __builtin_amdgcn_mfma_f32_16x16x32_bf16(af[i], bfr[j], acc[i][j], 0,0,0);
    __syncthreads();
  }
  #pragma unroll
  for(int i=0;i<4;i++)
    #pragma unroll
    for(int j=0;j<4;j++)
      #pragma unroll
      for(int r=0;r<4;r++){
        int row = m0 + qr + i*16 + (lane>>4)*4 + r;
        int col = n0 + qc + j*16 + (lane&15);
        if(row<M) C[(long)row*N + col] = f2bf(acc[i][j][r]);
      }
}

// ---------------- MFMA bf16 GEMM 64x128 tile (layer 2, N=128) ----------
__global__ __launch_bounds__(256) void mfma_gemm64(const ushort_t* __restrict__ A, const ushort_t* __restrict__ Bt,
                                                   ushort_t* __restrict__ C, int M, int N, int K){
  __shared__ ushort_t As[64*32];
  __shared__ ushort_t Bs[128*32];
  int tid = threadIdx.x;
  int m0 = blockIdx.y*64, n0 = blockIdx.x*128;
  int w = tid>>6, lane = tid&63;
  int qc = w*32;
  int lrow = lane&15, koff = (lane>>4)*8;
  f32x4 acc[4][2] = {};
  for(int k0=0; k0<K; k0+=32){
    {
      int row = tid>>2, off = (tid&3)*8;
      int gr = m0 + row;
      int4 va = (gr<M) ? *(const int4*)(A + (long)gr*K + k0 + off) : int4{0,0,0,0};
      *(int4*)&As[row*32 + off] = va;
    }
    #pragma unroll
    for(int rep=0;rep<2;rep++){
      int segid = tid + rep*256;
      int row = segid>>2, off = (segid&3)*8;
      int4 vb = *(const int4*)(Bt + (long)(n0+row)*K + k0 + off);
      *(int4*)&Bs[row*32 + off] = vb;
    }
    __syncthreads();
    frag8 af[4], bfr[2];
    #pragma unroll
    for(int i=0;i<4;i++) af[i]  = *(const frag8*)&As[(i*16 + lrow)*32 + koff];
    #pragma unroll
    for(int j=0;j<2;j++) bfr[j] = *(const frag8*)&Bs[(qc + j*16 + lrow)*32 + koff];
    #pragma unroll
    for(int i=0;i<4;i++)
      #pragma unroll
      for(int j=0;j<2;j++)
        acc[i][j] = __builtin_amdgcn_mfma_f32_16x16x32_bf16(af[i], bfr[j], acc[i][j], 0,0,0);
    __syncthreads();
  }
  #pragma unroll
  for(int i=0;i<4;i++)
    #pragma unroll
    for(int j=0;j<2;j++)
      #pragma unroll
      for(int r=0;r<4;r++){
        int row = m0 + i*16 + (lane>>4)*4 + r;
        int col = n0 + qc + j*16 + (lane&15);
        if(row<M) C[(long)row*N + col] = f2bf(acc[i][j][r]);
      }
}

// ---------------- split-bf16 MFMA projection: C[M,128] = A[M,128]@Bt^T (+bias, opt PReLU) ----
// A fp32; decomposed on the fly A=Ah+Al; Bt pre-split (prep). AhBh+AhBl+AlBh, fp32 accum.
__global__ __launch_bounds__(256) void mfma_proj(const float* __restrict__ A,
                                                 const ushort_t* __restrict__ Bth, const ushort_t* __restrict__ Btl,
                                                 float* __restrict__ C, int M,
                                                 const float* __restrict__ bias,
                                                 const float* __restrict__ prelu_a, int epi){
  __shared__ ushort_t Ash[64*32], Asl[64*32];
  __shared__ ushort_t Bsh[128*32], Bsl[128*32];
  int tid = threadIdx.x;
  int m0 = blockIdx.x*64;
  int w = tid>>6, lane = tid&63;
  int qc = w*32;
  int lrow = lane&15, koff2 = (lane>>4)*8;
  f32x4 acc[4][2] = {};
  for(int k0=0; k0<128; k0+=32){
    {
      int row = tid>>2, koff = (tid&3)*8;
      int gr = m0 + row;
      float4 u0{0,0,0,0}, u1{0,0,0,0};
      if(gr<M){
        u0 = *(const float4*)(A + (long)gr*HIDD + k0 + koff);
        u1 = *(const float4*)(A + (long)gr*HIDD + k0 + koff + 4);
      }
      float vv[8] = {u0.x,u0.y,u0.z,u0.w,u1.x,u1.y,u1.z,u1.w};
      unsigned ph[4], pl[4];
      #pragma unroll
      for(int c=0;c<4;c++){
        ushort_t h0 = f2bf(vv[2*c]),   l0 = f2bf(vv[2*c]   - bf2f(h0));
        ushort_t h1 = f2bf(vv[2*c+1]), l1 = f2bf(vv[2*c+1] - bf2f(h1));
        ph[c] = (unsigned)h0 | ((unsigned)h1<<16);
        pl[c] = (unsigned)l0 | ((unsigned)l1<<16);
      }
      *(uint4*)&Ash[row*32 + koff] = *(uint4*)ph;
      *(uint4*)&Asl[row*32 + koff] = *(uint4*)pl;
    }
    #pragma unroll
    for(int rep=0;rep<2;rep++){
      int segid = tid + rep*256;
      int row = segid>>2, off = (segid&3)*8;
      *(int4*)&Bsh[row*32 + off] = *(const int4*)(Bth + (long)row*HIDD + k0 + off);
      *(int4*)&Bsl[row*32 + off] = *(const int4*)(Btl + (long)row*HIDD + k0 + off);
    }
    __syncthreads();
    frag8 afh[4], afl[4], bfh[2], bfl[2];
    #pragma unroll
    for(int i=0;i<4;i++){
      afh[i] = *(const frag8*)&Ash[(i*16 + lrow)*32 + koff2];
      afl[i] = *(const frag8*)&Asl[(i*16 + lrow)*32 + koff2];
    }
    #pragma unroll
    for(int j=0;j<2;j++){
      bfh[j] = *(const frag8*)&Bsh[(qc + j*16 + lrow)*32 + koff2];
      bfl[j] = *(const frag8*)&Bsl[(qc + j*16 + lrow)*32 + koff2];
    }
    #pragma unroll
    for(int i=0;i<4;i++)
      #pragma unroll
      for(int j=0;j<2;j++){
        acc[i][j] = __builtin_amdgcn_mfma_f32_16x16x32_bf16(afh[i], bfh[j], acc[i][j], 0,0,0);
        acc[i][j] = __builtin_amdgcn_mfma_f32_16x16x32_bf16(afh[i], bfl[j], acc[i][j], 0,0,0);
        acc[i][j] = __builtin_amdgcn_mfma_f32_16x16x32_bf16(afl[i], bfh[j], acc[i][j], 0,0,0);
      }
    __syncthreads();
  }
  float ap = (epi==1)? prelu_a[0] : 0.f;
  #pragma unroll
  for(int i=0;i<4;i++)
    #pragma unroll
    for(int j=0;j<2;j++)
      #pragma unroll
      for(int r=0;r<4;r++){
        int row = m0 + i*16 + (lane>>4)*4 + r;
        int col = qc + j*16 + (lane&15);
        if(row<M){
          float v = acc[i][j][r] + bias[col];
          if(epi==1) v = v>0.f? v : ap*v;
          C[(long)row*HIDD + col] = v;
        }
      }
}

// ---------------- per-node attention scalars (bf16 h) ----------------

__global__ void node_attn1(const ushort_t* __restrict__ h1b, const float* __restrict__ as1,
                           const float* __restrict__ ad1, float* __restrict__ s1n, float* __restrict__ d1n){
  int n = blockIdx.x;
  int wv = threadIdx.x>>6, lane = threadIdx.x&63;
  unsigned v = *(const unsigned*)(h1b + (long)n*HH + wv*HIDD + 2*lane);
  float f0 = lo_of(v), f1 = hi_of(v);
  float s = f0*as1[wv*HIDD+2*lane] + f1*as1[wv*HIDD+2*lane+1];
  float d = f0*ad1[wv*HIDD+2*lane] + f1*ad1[wv*HIDD+2*lane+1];
  #pragma unroll
  for(int o=32;o>0;o>>=1){ s += __shfl_xor(s,o,64); d += __shfl_xor(d,o,64); }
  if(lane==0){ s1n[n*4+wv]=s; d1n[n*4+wv]=d; }
}

__global__ void node_attn2(const ushort_t* __restrict__ h2b, const float* __restrict__ as2,
                           const float* __restrict__ ad2, float* __restrict__ s2n, float* __restrict__ d2n){
  int n = blockIdx.x*4 + (threadIdx.x>>6);
  int lane = threadIdx.x&63;
  unsigned v = *(const unsigned*)(h2b + (long)n*HIDD + 2*lane);
  float f0 = lo_of(v), f1 = hi_of(v);
  float s = f0*as2[2*lane] + f1*as2[2*lane+1];
  float d = f0*ad2[2*lane] + f1*ad2[2*lane+1];
  #pragma unroll
  for(int o=32;o>0;o>>=1){ s += __shfl_xor(s,o,64); d += __shfl_xor(d,o,64); }
  if(lane==0){ s2n[n]=s; d2n[n]=d; }
}

// ---------------- agg1: online-softmax + x4-unrolled gather ----------------

__global__ void agg1(const ushort_t* __restrict__ h1b, const int* __restrict__ rowptr,
                     const int* __restrict__ csrc,
                     const float* __restrict__ s1n, const float* __restrict__ d1n,
                     const float* __restrict__ cae1, float* __restrict__ elog,
                     const float* __restrict__ b1, ushort_t* __restrict__ out1b){
  int n = blockIdx.x*4 + (threadIdx.x>>6);
  int lane = threadIdx.x&63;
  int beg = rowptr[n], end = rowptr[n+1];
  int h12 = lane&3;
  float dh = d1n[n*4 + h12];
  float m = -1e30f, ss = 0.f;
  for(int base=beg; base<end; base+=16){
    int e = base + (lane>>2);
    if(e<end){
      float t = s1n[csrc[e]*4 + h12] + dh + cae1[e*4 + h12];
      t = t>0.f? t : 0.2f*t;
      elog[e*4 + h12] = t;
      float nm = fmaxf(m, t);
      ss = ss*__expf(m-nm) + __expf(t-nm);
      m = nm;
    }
  }
  #pragma unroll
  for(int o=4;o<=32;o<<=1){
    float mo = __shfl_xor(m, o, 64), so = __shfl_xor(ss, o, 64);
    float nm = fmaxf(m, mo);
    ss = ss*__expf(m-nm) + so*__expf(mo-nm);
    m = nm;
  }
  float inv = ss>0.f ? 1.f/ss : 0.f;
  int hq = lane>>4;
  float mq   = __shfl(m,   hq, 64);
  float invq = __shfl(inv, hq, 64);
  float acc[8] = {};
  int i = beg;
  for(; i+3<end; i+=4){
    int s0 = csrc[i], s1 = csrc[i+1], s2 = csrc[i+2], s3 = csrc[i+3];
    float w0 = __expf(elog[i*4 + hq]     - mq)*invq;
    float w1 = __expf(elog[(i+1)*4 + hq] - mq)*invq;
    float w2 = __expf(elog[(i+2)*4 + hq] - mq)*invq;
    float w3 = __expf(elog[(i+3)*4 + hq] - mq)*invq;
    uint4 v0 = *(const uint4*)(h1b + (long)s0*HH + lane*8);
    uint4 v1 = *(const uint4*)(h1b + (long)s1*HH + lane*8);
    uint4 v2 = *(const uint4*)(h1b + (long)s2*HH + lane*8);
    uint4 v3 = *(const uint4*)(h1b + (long)s3*HH + lane*8);
    acc[0] += w0*lo_of(v0.x) + w1*lo_of(v1.x) + w2*lo_of(v2.x) + w3*lo_of(v3.x);
    acc[1] += w0*hi_of(v0.x) + w1*hi_of(v1.x) + w2*hi_of(v2.x) + w3*hi_of(v3.x);
    acc[2] += w0*lo_of(v0.y) + w1*lo_of(v1.y) + w2*lo_of(v2.y) + w3*lo_of(v3.y);
    acc[3] += w0*hi_of(v0.y) + w1*hi_of(v1.y) + w2*hi_of(v2.y) + w3*hi_of(v3.y);
    acc[4] += w0*lo_of(v0.z) + w1*lo_of(v1.z) + w2*lo_of(v2.z) + w3*lo_of(v3.z);
    acc[5] += w0*hi_of(v0.z) + w1*hi_of(v1.z) + w2*hi_of(v2.z) + w3*hi_of(v3.z);
    acc[6] += w0*lo_of(v0.w) + w1*lo_of(v1.w) + w2*lo_of(v2.w) + w3*lo_of(v3.w);
    acc[7] += w0*hi_of(v0.w) + w1*hi_of(v1.w) + w2*hi_of(v2.w) + w3*hi_of(v3.w);
  }
  for(; i<end; i++){
    int s0 = csrc[i];
    float w0 = __expf(elog[i*4 + hq] - mq)*invq;
    uint4 v0 = *(const uint4*)(h1b + (long)s0*HH + lane*8);
    acc[0] += w0*lo_of(v0.x); acc[1] += w0*hi_of(v0.x);
    acc[2] += w0*lo_of(v0.y); acc[3] += w0*hi_of(v0.y);
    acc[4] += w0*lo_of(v0.z); acc[5] += w0*hi_of(v0.z);
    acc[6] += w0*lo_of(v0.w); acc[7] += w0*hi_of(v0.w);
  }
  float4 bl = ((const float4*)b1)[lane*2];
  float4 bh = ((const float4*)b1)[lane*2+1];
  float bb[8] = {bl.x,bl.y,bl.z,bl.w,bh.x,bh.y,bh.z,bh.w};
  ushort_t o8[8];
  #pragma unroll
  for(int c=0;c<8;c++){
    float o = acc[c] + bb[c];
    o8[c] = f2bf(o>0.f? o : __expf(o)-1.f);   // ELU
  }
  uint4 pk;
  pk.x = (unsigned)o8[0] | ((unsigned)o8[1]<<16);
  pk.y = (unsigned)o8[2] | ((unsigned)o8[3]<<16);
  pk.z = (unsigned)o8[4] | ((unsigned)o8[5]<<16);
  pk.w = (unsigned)o8[6] | ((unsigned)o8[7]<<16);
  *(uint4*)(out1b + (long)n*HH + lane*8) = pk;
}

__global__ void agg2(const ushort_t* __restrict__ h2b, const int* __restrict__ rowptr,
                     const int* __restrict__ csrc,
                     const float* __restrict__ s2n, const float* __restrict__ d2n,
                     const float* __restrict__ cae2, float* __restrict__ elog,
                     const float* __restrict__ b2, float* __restrict__ out2){
  int n = blockIdx.x*4 + (threadIdx.x>>6);
  int lane = threadIdx.x&63;
  int beg = rowptr[n], end = rowptr[n+1];
  float dn = d2n[n];
  float m = -1e30f, ss = 0.f;
  for(int e=beg+lane; e<end; e+=64){
    float t = s2n[csrc[e]] + dn + cae2[e];
    t = t>0.f? t : 0.2f*t;
    elog[e] = t;
    float nm = fmaxf(m, t);
    ss = ss*__expf(m-nm) + __expf(t-nm);
    m = nm;
  }
  #pragma unroll
  for(int o=1;o<=32;o<<=1){
    float mo = __shfl_xor(m, o, 64), so = __shfl_xor(ss, o, 64);
    float nm = fmaxf(m, mo);
    ss = ss*__expf(m-nm) + so*__expf(mo-nm);
    m = nm;
  }
  float inv = ss>0.f ? 1.f/ss : 0.f;
  float a0=0.f, a1=0.f;
  int i = beg;
  for(; i+3<end; i+=4){
    int s0 = csrc[i], s1 = csrc[i+1], s2 = csrc[i+2], s3 = csrc[i+3];
    float w0 = __expf(elog[i]-m)*inv;
    float w1 = __expf(elog[i+1]-m)*inv;
    float w2 = __expf(elog[i+2]-m)*inv;
    float w3 = __expf(elog[i+3]-m)*inv;
    unsigned v0 = *(const unsigned*)(h2b + (long)s0*HIDD + 2*lane);
    unsigned v1 = *(const unsigned*)(h2b + (long)s1*HIDD + 2*lane);
    unsigned v2 = *(const unsigned*)(h2b + (long)s2*HIDD + 2*lane);
    unsigned v3 = *(const unsigned*)(h2b + (long)s3*HIDD + 2*lane);
    a0 += w0*lo_of(v0) + w1*lo_of(v1) + w2*lo_of(v2) + w3*lo_of(v3);
    a1 += w0*hi_of(v0) + w1*hi_of(v1) + w2*hi_of(v2) + w3*hi_of(v3);
  }
  for(; i<end; i++){
    float w0 = __expf(elog[i]-m)*inv;
    unsigned v0 = *(const unsigned*)(h2b + (long)csrc[i]*HIDD + 2*lane);
    a0 += w0*lo_of(v0); a1 += w0*hi_of(v0);
  }
  float o0 = a0 + b2[2*lane];
  float o1 = a1 + b2[2*lane+1];
  float2 pk;
  pk.x = o0>0.f? o0 : __expf(o0)-1.f;
  pk.y = o1>0.f? o1 : __expf(o1)-1.f;
  *(float2*)(out2 + (long)n*HIDD + 2*lane) = pk;
}

// ---------------- readout ----------------

__global__ void colsum(const float* __restrict__ hp, float* __restrict__ gbuf){
  int c = threadIdx.x;
  float acc = 0.f;
  for(int r = blockIdx.x; r < NN; r += gridDim.x) acc += hp[(long)r*HIDD + c];
  atomicAdd(&gbuf[c], acc);
}

__global__ void sigmoid_g(const float* __restrict__ gbuf, float* __restrict__ gout){
  int c = threadIdx.x;
  float m = gbuf[c] * (1.0f/NN);
  gout[c] = 1.f/(1.f+__expf(-m));
}

// ---------------- launch ----------------

extern "C" void kernel_launch(void* const* d_in, const int* in_sizes, int n_in,
                              void* d_out, int out_size, void* d_ws, size_t ws_size,
                              hipStream_t stream){
  const float* x    = (const float*)d_in[0];
  const int*   ei   = (const int*)  d_in[1];
  const float* ea   = (const float*)d_in[2];
  const float* W1   = (const float*)d_in[3];
  const float* We1  = (const float*)d_in[4];
  const float* as1  = (const float*)d_in[5];
  const float* ad1  = (const float*)d_in[6];
  const float* ae1  = (const float*)d_in[7];
  const float* b1   = (const float*)d_in[8];
  const float* W2   = (const float*)d_in[9];
  const float* We2  = (const float*)d_in[10];
  const float* as2  = (const float*)d_in[11];
  const float* ad2  = (const float*)d_in[12];
  const float* ae2  = (const float*)d_in[13];
  const float* b2   = (const float*)d_in[14];
  const float* P1   = (const float*)d_in[15];
  const float* pb1  = (const float*)d_in[16];
  const float* pra  = (const float*)d_in[17];
  const float* P2   = (const float*)d_in[18];
  const float* pb2  = (const float*)d_in[19];
  float* out = (float*)d_out;

  char* wsp = (char*)d_ws;
  size_t off = 0;
  auto alloc = [&](size_t bytes)->char*{
    char* p = wsp + off;
    off += (bytes + 255) & ~(size_t)255;
    return p;
  };
  ushort_t* h1b  = (ushort_t*)alloc(sizeof(ushort_t)*(size_t)NN*HH);
  ushort_t* out1b= (ushort_t*)alloc(sizeof(ushort_t)*(size_t)NN*HH);
  ushort_t* h2b  = (ushort_t*)alloc(sizeof(ushort_t)*(size_t)NN*HIDD);
  float*    out2 = (float*)  alloc(sizeof(float)*(size_t)NN*HIDD);
  float*    zb   = (float*)  alloc(sizeof(float)*(size_t)NN*HIDD);
  ushort_t* xb   = (ushort_t*)alloc(sizeof(ushort_t)*(size_t)NN*FIN);
  ushort_t* W1t  = (ushort_t*)alloc(sizeof(ushort_t)*(size_t)HH*FIN);
  ushort_t* W2t  = (ushort_t*)alloc(sizeof(ushort_t)*(size_t)HIDD*HH);
  ushort_t* P1th = (ushort_t*)alloc(sizeof(ushort_t)*(size_t)HIDD*HIDD);
  ushort_t* P1tl = (ushort_t*)alloc(sizeof(ushort_t)*(size_t)HIDD*HIDD);
  ushort_t* P2th = (ushort_t*)alloc(sizeof(ushort_t)*(size_t)HIDD*HIDD);
  ushort_t* P2tl = (ushort_t*)alloc(sizeof(ushort_t)*(size_t)HIDD*HIDD);
  float* s1n   = (float*)alloc(sizeof(float)*NN*NHEAD);
  float* d1n   = (float*)alloc(sizeof(float)*NN*NHEAD);
  float* s2n   = (float*)alloc(sizeof(float)*NN);
  float* d2n   = (float*)alloc(sizeof(float)*NN);
  float* v1    = (float*)alloc(sizeof(float)*FE*NHEAD);
  float* v2    = (float*)alloc(sizeof(float)*FE);
  float* cae1  = (float*)alloc(sizeof(float)*(size_t)E2*NHEAD);
  float* elog1 = (float*)alloc(sizeof(float)*(size_t)E2*NHEAD);
  float* cae2  = (float*)alloc(sizeof(float)*(size_t)E2);
  float* elog2 = (float*)alloc(sizeof(float)*(size_t)E2);
  int*   rowptr= (int*)  alloc(sizeof(int)*(NN+1));
  int*   csrc  = (int*)  alloc(sizeof(int)*(size_t)E2);
  // zero-init trio: adjacent for one memset
  int*   cnt   = (int*)  alloc(sizeof(int)*NN);     // 80128 B span
  int*   fcnt  = (int*)  alloc(sizeof(int)*NN);     // 80128 B span
  float* gbuf  = (float*)alloc(sizeof(float)*HIDD); // 512 B span

  hipMemsetAsync(cnt, 0, 80128 + 80128 + 512, stream);

  prep    <<<8397, 256, 0, stream>>>(ei, cnt, x, xb, W1, W1t, W2, W2t,
                                     P1, P1th, P1tl, P2, P2th, P2tl,
                                     We1, ae1, We2, ae2, v1, v2);
  scan_k  <<<1, 1024, 0, stream>>>(cnt, rowptr);
  csr_fill<<<EE/256, 256, 0, stream>>>(ei, ea, v1, v2, rowptr, fcnt, csrc, cae1, cae2);

  // layer 1
  mfma_gemm <<<dim3(HH/128, (NN+127)/128), 256, 0, stream>>>(xb, W1t, h1b, NN, HH, FIN);
  node_attn1<<<NN, 256, 0, stream>>>(h1b, as1, ad1, s1n, d1n);
  agg1      <<<NN/4, 256, 0, stream>>>(h1b, rowptr, csrc, s1n, d1n, cae1, elog1, b1, out1b);

  // layer 2
  mfma_gemm64<<<dim3(1, (NN+63)/64), 256, 0, stream>>>(out1b, W2t, h2b, NN, HIDD, HH);
  node_attn2 <<<NN/4, 256, 0, stream>>>(h2b, as2, ad2, s2n, d2n);
  agg2       <<<NN/4, 256, 0, stream>>>(h2b, rowptr, csrc, s2n, d2n, cae2, elog2, b2, out2);

  // projection head: split-bf16 MFMA (fp32-accurate)
  mfma_proj<<<(NN+63)/64, 256, 0, stream>>>(out2, P1th, P1tl, zb, NN, pb1, pra, 1);
  mfma_proj<<<(NN+63)/64, 256, 0, stream>>>(zb,  P2th, P2tl, out, NN, pb2, nullptr, 0);

  // g = sigmoid(mean(h_proj, axis=0))
  colsum   <<<256, 128, 0, stream>>>(out, gbuf);
  sigmoid_g<<<1, 128, 0, stream>>>(gbuf, out + (size_t)NN*HIDD);
}

// Round 7
// 432.688 us; speedup vs baseline: 1.8332x; 1.0369x over previous
//
#include <hip/hip_runtime.h>
#include <hip/hip_bf16.h>

// GRN_GAT_Encoder round 7:
// r6: ~170us hidden in 2nd-tier dispatches (top-5 all agg1). This round:
//  - node_attn1 fused into gemm1 epilogue (col tile == head; shuffle+LDS reduce)
//  - node_attn2 fused into gemm64 epilogue
//  - colsum fused into proj2 epilogue (block reduce + atomics)
//  - agg1: 2 waves/node (contiguous edge halves, LDS combine) + x4 unroll
//  - csr_fill float4 stores.  14 -> 11 dispatches.

#define NN    20000
#define EE    320000
#define E2    640000
#define FIN   256
#define FE    32
#define HIDD  128
#define NHEAD 4
#define HH    512   // NHEAD*HIDD

typedef unsigned short ushort_t;
typedef short frag8 __attribute__((ext_vector_type(8)));
typedef float f32x4 __attribute__((ext_vector_type(4)));

__device__ inline ushort_t f2bf(float f){
  unsigned x = __float_as_uint(f);
  unsigned r = (x + 0x7fffu + ((x>>16)&1u)) >> 16;
  return (ushort_t)r;
}
__device__ inline float bf2f(ushort_t u){ return __uint_as_float(((unsigned)u)<<16); }
__device__ inline float lo_of(unsigned v){ return __uint_as_float(v<<16); }
__device__ inline float hi_of(unsigned v){ return __uint_as_float(v & 0xffff0000u); }

// ---------------- fused prep ----------------
__global__ void prep(const int* __restrict__ ei, int* __restrict__ cnt,
                     const float* __restrict__ x, ushort_t* __restrict__ xb,
                     const float* __restrict__ W1, ushort_t* __restrict__ W1t,
                     const float* __restrict__ W2, ushort_t* __restrict__ W2t,
                     const float* __restrict__ P1, ushort_t* __restrict__ P1th, ushort_t* __restrict__ P1tl,
                     const float* __restrict__ P2, ushort_t* __restrict__ P2th, ushort_t* __restrict__ P2tl,
                     const float* __restrict__ We1, const float* __restrict__ ae1,
                     const float* __restrict__ We2, const float* __restrict__ ae2,
                     float* __restrict__ v1, float* __restrict__ v2){
  int b = blockIdx.x, tid = threadIdx.x;
  if(b < 2500){
    int e = b*256 + tid;
    int dst = (e < EE) ? ei[EE + e] : ei[e - EE];
    atomicAdd(&cnt[dst], 1);
  } else if(b < 7500){
    int i = (b-2500)*256 + tid;
    float4 v = ((const float4*)x)[i];
    ushort4 o; o.x=f2bf(v.x); o.y=f2bf(v.y); o.z=f2bf(v.z); o.w=f2bf(v.w);
    ((ushort4*)xb)[i] = o;
  } else if(b < 8012){
    int idx = (b-7500)*256 + tid;               // FIN*HH
    int k = idx>>9, n = idx&511;
    W1t[n*FIN + k] = f2bf(W1[idx]);
  } else if(b < 8268){
    int idx = (b-8012)*256 + tid;               // HH*HIDD
    int k = idx>>7, n = idx&127;
    W2t[n*HH + k] = f2bf(W2[idx]);
  } else if(b < 8332){
    int idx = (b-8268)*256 + tid;               // HIDD*HIDD
    int k = idx>>7, n = idx&127;
    float v = P1[idx];
    ushort_t h = f2bf(v);
    P1th[n*HIDD + k] = h;
    P1tl[n*HIDD + k] = f2bf(v - bf2f(h));
  } else if(b < 8396){
    int idx = (b-8332)*256 + tid;
    int k = idx>>7, n = idx&127;
    float v = P2[idx];
    ushort_t h = f2bf(v);
    P2th[n*HIDD + k] = h;
    P2tl[n*HIDD + k] = f2bf(v - bf2f(h));
  } else {
    if(tid < FE*NHEAD){
      int f = tid>>2, h = tid&3;
      float s = 0.f;
      for(int c=0;c<HIDD;c++) s += We1[f*HH + h*HIDD + c] * ae1[h*HIDD + c];
      v1[f*4+h] = s;
    } else if(tid < FE*NHEAD + FE){
      int f = tid - FE*NHEAD;
      float s = 0.f;
      for(int c=0;c<HIDD;c++) s += We2[f*HIDD + c] * ae2[c];
      v2[f] = s;
    }
  }
}

__global__ void scan_k(const int* __restrict__ cnt, int* __restrict__ rowptr){
  __shared__ int sums[1024];
  int tid = threadIdx.x;
  const int per = (NN + 1023)/1024;
  int base = tid*per;
  int s = 0;
  for(int i=0;i<per;i++){ int idx=base+i; if(idx<NN) s += cnt[idx]; }
  sums[tid] = s; __syncthreads();
  for(int off=1; off<1024; off<<=1){
    int v = (tid>=off)? sums[tid-off] : 0;
    __syncthreads();
    sums[tid] += v;
    __syncthreads();
  }
  int run = (tid==0)? 0 : sums[tid-1];
  for(int i=0;i<per;i++){
    int idx = base+i;
    if(idx<=NN) rowptr[idx] = run;
    if(idx<NN)  run += cnt[idx];
  }
}

__global__ void csr_fill(const int* __restrict__ ei, const float* __restrict__ ea,
                         const float* __restrict__ v1, const float* __restrict__ v2,
                         const int* __restrict__ rowptr, int* __restrict__ fcnt,
                         int* __restrict__ csrc, float* __restrict__ cae1, float* __restrict__ cae2){
  __shared__ float sv1[FE*NHEAD];
  __shared__ float sv2[FE];
  int tid = threadIdx.x;
  if(tid < FE*NHEAD) sv1[tid] = v1[tid];
  if(tid < FE)       sv2[tid] = v2[tid];
  __syncthreads();
  int e = blockIdx.x*256 + tid;                // grid EE/256
  int a = ei[e], b = ei[EE+e];
  const float4* er4 = (const float4*)(ea + (long)e*FE);
  float a0=0,a1=0,a2=0,a3=0,ab=0;
  #pragma unroll
  for(int f4=0; f4<FE/4; f4++){
    float4 t = er4[f4];
    float tv[4] = {t.x, t.y, t.z, t.w};
    #pragma unroll
    for(int c=0;c<4;c++){
      int f = f4*4+c;
      float t1 = tv[c];
      a0 += t1*sv1[f*4+0]; a1 += t1*sv1[f*4+1]; a2 += t1*sv1[f*4+2]; a3 += t1*sv1[f*4+3];
      ab += t1*sv2[f];
    }
  }
  float4 c4; c4.x=a0; c4.y=a1; c4.z=a2; c4.w=a3;
  int pos = rowptr[b] + atomicAdd(&fcnt[b], 1);    // fwd
  csrc[pos] = a;
  *(float4*)(cae1 + (size_t)pos*4) = c4;
  cae2[pos] = ab;
  pos = rowptr[a] + atomicAdd(&fcnt[a], 1);        // rev
  csrc[pos] = b;
  *(float4*)(cae1 + (size_t)pos*4) = c4;
  cae2[pos] = ab;
}

// ---------------- gemm1 (+fused node_attn1): h1 = xb@W1t^T, s1n/d1n ----------------
// grid (4 heads, ceil(M/128)); n0 = head*128.
__global__ __launch_bounds__(256) void gemm1_attn(const ushort_t* __restrict__ A, const ushort_t* __restrict__ Bt,
                                                  ushort_t* __restrict__ C, int M,
                                                  const float* __restrict__ as1, const float* __restrict__ ad1,
                                                  float* __restrict__ s1n, float* __restrict__ d1n){
  __shared__ ushort_t As[128*32];
  __shared__ ushort_t Bs[128*32];
  __shared__ float sred[2][128], dred[2][128];
  int tid = threadIdx.x;
  int head = blockIdx.x;
  int m0 = blockIdx.y*128, n0 = head*128;
  int w = tid>>6, lane = tid&63;
  int qr = (w>>1)*64, qc = (w&1)*64;
  int lrow = lane&15, koff = (lane>>4)*8;
  f32x4 acc[4][4] = {};
  for(int k0=0; k0<FIN; k0+=32){
    #pragma unroll
    for(int rep=0;rep<2;rep++){
      int segid = tid + rep*256;
      int row = segid>>2, off = (segid&3)*8;
      int gr = m0 + row;
      int4 va = (gr<M) ? *(const int4*)(A + (long)gr*FIN + k0 + off) : int4{0,0,0,0};
      *(int4*)&As[row*32 + off] = va;
      int4 vb = *(const int4*)(Bt + (long)(n0+row)*FIN + k0 + off);
      *(int4*)&Bs[row*32 + off] = vb;
    }
    __syncthreads();
    frag8 af[4], bfr[4];
    #pragma unroll
    for(int i=0;i<4;i++) af[i]  = *(const frag8*)&As[(qr + i*16 + lrow)*32 + koff];
    #pragma unroll
    for(int j=0;j<4;j++) bfr[j] = *(const frag8*)&Bs[(qc + j*16 + lrow)*32 + koff];
    #pragma unroll
    for(int i=0;i<4;i++)
      #pragma unroll
      for(int j=0;j<4;j++)
        acc[i][j] = __builtin_amdgcn_mfma_f32_16x16x32_bf16(af[i], bfr[j], acc[i][j], 0,0,0);
    __syncthreads();
  }
  // store C
  #pragma unroll
  for(int i=0;i<4;i++)
    #pragma unroll
    for(int j=0;j<4;j++)
      #pragma unroll
      for(int r=0;r<4;r++){
        int row = m0 + qr + i*16 + (lane>>4)*4 + r;
        int col = n0 + qc + j*16 + (lane&15);
        if(row<M) C[(long)row*HH + col] = f2bf(acc[i][j][r]);
      }
  // fused attn dot-products: ch = qc + j*16 + (lane&15)
  float a_s[4], a_d[4];
  #pragma unroll
  for(int j=0;j<4;j++){
    a_s[j] = as1[head*HIDD + qc + j*16 + (lane&15)];
    a_d[j] = ad1[head*HIDD + qc + j*16 + (lane&15)];
  }
  #pragma unroll
  for(int i=0;i<4;i++)
    #pragma unroll
    for(int r=0;r<4;r++){
      float sp = acc[i][0][r]*a_s[0] + acc[i][1][r]*a_s[1] + acc[i][2][r]*a_s[2] + acc[i][3][r]*a_s[3];
      float dp = acc[i][0][r]*a_d[0] + acc[i][1][r]*a_d[1] + acc[i][2][r]*a_d[2] + acc[i][3][r]*a_d[3];
      #pragma unroll
      for(int o=1;o<=8;o<<=1){ sp += __shfl_xor(sp,o,64); dp += __shfl_xor(dp,o,64); }
      if((lane&15)==0){
        int rl = qr + i*16 + (lane>>4)*4 + r;
        sred[w&1][rl] = sp;
        dred[w&1][rl] = dp;
      }
    }
  __syncthreads();
  if(tid < 128){
    int gr = m0 + tid;
    if(gr < M){
      s1n[gr*4 + head] = sred[0][tid] + sred[1][tid];
      d1n[gr*4 + head] = dred[0][tid] + dred[1][tid];
    }
  }
}

// ---------------- gemm64 (+fused node_attn2): h2 = out1b@W2t^T, s2n/d2n ----------------
__global__ __launch_bounds__(256) void gemm64_attn(const ushort_t* __restrict__ A, const ushort_t* __restrict__ Bt,
                                                   ushort_t* __restrict__ C, int M,
                                                   const float* __restrict__ as2, const float* __restrict__ ad2,
                                                   float* __restrict__ s2n, float* __restrict__ d2n){
  __shared__ ushort_t As[64*32];
  __shared__ ushort_t Bs[128*32];
  __shared__ float sred[4][64], dred[4][64];
  int tid = threadIdx.x;
  int m0 = blockIdx.y*64;
  int w = tid>>6, lane = tid&63;
  int qc = w*32;
  int lrow = lane&15, koff = (lane>>4)*8;
  f32x4 acc[4][2] = {};
  for(int k0=0; k0<HH; k0+=32){
    {
      int row = tid>>2, off = (tid&3)*8;
      int gr = m0 + row;
      int4 va = (gr<M) ? *(const int4*)(A + (long)gr*HH + k0 + off) : int4{0,0,0,0};
      *(int4*)&As[row*32 + off] = va;
    }
    #pragma unroll
    for(int rep=0;rep<2;rep++){
      int segid = tid + rep*256;
      int row = segid>>2, off = (segid&3)*8;
      int4 vb = *(const int4*)(Bt + (long)row*HH + k0 + off);
      *(int4*)&Bs[row*32 + off] = vb;
    }
    __syncthreads();
    frag8 af[4], bfr[2];
    #pragma unroll
    for(int i=0;i<4;i++) af[i]  = *(const frag8*)&As[(i*16 + lrow)*32 + koff];
    #pragma unroll
    for(int j=0;j<2;j++) bfr[j] = *(const frag8*)&Bs[(qc + j*16 + lrow)*32 + koff];
    #pragma unroll
    for(int i=0;i<4;i++)
      #pragma unroll
      for(int j=0;j<2;j++)
        acc[i][j] = __builtin_amdgcn_mfma_f32_16x16x32_bf16(af[i], bfr[j], acc[i][j], 0,0,0);
    __syncthreads();
  }
  #pragma unroll
  for(int i=0;i<4;i++)
    #pragma unroll
    for(int j=0;j<2;j++)
      #pragma unroll
      for(int r=0;r<4;r++){
        int row = m0 + i*16 + (lane>>4)*4 + r;
        int col = qc + j*16 + (lane&15);
        if(row<M) C[(long)row*HIDD + col] = f2bf(acc[i][j][r]);
      }
  float a_s[2], a_d[2];
  #pragma unroll
  for(int j=0;j<2;j++){
    a_s[j] = as2[qc + j*16 + (lane&15)];
    a_d[j] = ad2[qc + j*16 + (lane&15)];
  }
  #pragma unroll
  for(int i=0;i<4;i++)
    #pragma unroll
    for(int r=0;r<4;r++){
      float sp = acc[i][0][r]*a_s[0] + acc[i][1][r]*a_s[1];
      float dp = acc[i][0][r]*a_d[0] + acc[i][1][r]*a_d[1];
      #pragma unroll
      for(int o=1;o<=8;o<<=1){ sp += __shfl_xor(sp,o,64); dp += __shfl_xor(dp,o,64); }
      if((lane&15)==0){
        int rl = i*16 + (lane>>4)*4 + r;
        sred[w][rl] = sp;
        dred[w][rl] = dp;
      }
    }
  __syncthreads();
  if(tid < 64){
    int gr = m0 + tid;
    if(gr < M){
      s2n[gr] = sred[0][tid]+sred[1][tid]+sred[2][tid]+sred[3][tid];
      d2n[gr] = dred[0][tid]+dred[1][tid]+dred[2][tid]+dred[3][tid];
    }
  }
}

// ---------------- split-bf16 MFMA projection (+optional fused colsum) ----------------
__global__ __launch_bounds__(256) void mfma_proj(const float* __restrict__ A,
                                                 const ushort_t* __restrict__ Bth, const ushort_t* __restrict__ Btl,
                                                 float* __restrict__ C, int M,
                                                 const float* __restrict__ bias,
                                                 const float* __restrict__ prelu_a, int epi,
                                                 float* __restrict__ gbuf){
  __shared__ ushort_t Ash[64*32], Asl[64*32];
  __shared__ ushort_t Bsh[128*32], Bsl[128*32];
  int tid = threadIdx.x;
  int m0 = blockIdx.x*64;
  int w = tid>>6, lane = tid&63;
  int qc = w*32;
  int lrow = lane&15, koff2 = (lane>>4)*8;
  f32x4 acc[4][2] = {};
  for(int k0=0; k0<128; k0+=32){
    {
      int row = tid>>2, koff = (tid&3)*8;
      int gr = m0 + row;
      float4 u0{0,0,0,0}, u1{0,0,0,0};
      if(gr<M){
        u0 = *(const float4*)(A + (long)gr*HIDD + k0 + koff);
        u1 = *(const float4*)(A + (long)gr*HIDD + k0 + koff + 4);
      }
      float vv[8] = {u0.x,u0.y,u0.z,u0.w,u1.x,u1.y,u1.z,u1.w};
      unsigned ph[4], pl[4];
      #pragma unroll
      for(int c=0;c<4;c++){
        ushort_t h0 = f2bf(vv[2*c]),   l0 = f2bf(vv[2*c]   - bf2f(h0));
        ushort_t h1 = f2bf(vv[2*c+1]), l1 = f2bf(vv[2*c+1] - bf2f(h1));
        ph[c] = (unsigned)h0 | ((unsigned)h1<<16);
        pl[c] = (unsigned)l0 | ((unsigned)l1<<16);
      }
      *(uint4*)&Ash[row*32 + koff] = *(uint4*)ph;
      *(uint4*)&Asl[row*32 + koff] = *(uint4*)pl;
    }
    #pragma unroll
    for(int rep=0;rep<2;rep++){
      int segid = tid + rep*256;
      int row = segid>>2, off = (segid&3)*8;
      *(int4*)&Bsh[row*32 + off] = *(const int4*)(Bth + (long)row*HIDD + k0 + off);
      *(int4*)&Bsl[row*32 + off] = *(const int4*)(Btl + (long)row*HIDD + k0 + off);
    }
    __syncthreads();
    frag8 afh[4], afl[4], bfh[2], bfl[2];
    #pragma unroll
    for(int i=0;i<4;i++){
      afh[i] = *(const frag8*)&Ash[(i*16 + lrow)*32 + koff2];
      afl[i] = *(const frag8*)&Asl[(i*16 + lrow)*32 + koff2];
    }
    #pragma unroll
    for(int j=0;j<2;j++){
      bfh[j] = *(const frag8*)&Bsh[(qc + j*16 + lrow)*32 + koff2];
      bfl[j] = *(const frag8*)&Bsl[(qc + j*16 + lrow)*32 + koff2];
    }
    #pragma unroll
    for(int i=0;i<4;i++)
      #pragma unroll
      for(int j=0;j<2;j++){
        acc[i][j] = __builtin_amdgcn_mfma_f32_16x16x32_bf16(afh[i], bfh[j], acc[i][j], 0,0,0);
        acc[i][j] = __builtin_amdgcn_mfma_f32_16x16x32_bf16(afh[i], bfl[j], acc[i][j], 0,0,0);
        acc[i][j] = __builtin_amdgcn_mfma_f32_16x16x32_bf16(afl[i], bfh[j], acc[i][j], 0,0,0);
      }
    __syncthreads();
  }
  float ap = (epi==1)? prelu_a[0] : 0.f;
  #pragma unroll
  for(int i=0;i<4;i++)
    #pragma unroll
    for(int j=0;j<2;j++)
      #pragma unroll
      for(int r=0;r<4;r++){
        int row = m0 + i*16 + (lane>>4)*4 + r;
        int col = qc + j*16 + (lane&15);
        if(row<M){
          float v = acc[i][j][r] + bias[col];
          if(epi==1) v = v>0.f? v : ap*v;
          acc[i][j][r] = v;              // keep post-epilogue value for colsum
          C[(long)row*HIDD + col] = v;
        } else acc[i][j][r] = 0.f;
      }
  if(epi==0){   // fused colsum for readout
    #pragma unroll
    for(int j=0;j<2;j++){
      float cp = 0.f;
      #pragma unroll
      for(int i=0;i<4;i++)
        #pragma unroll
        for(int r=0;r<4;r++) cp += acc[i][j][r];
      cp += __shfl_xor(cp,16,64);
      cp += __shfl_xor(cp,32,64);
      if((lane>>4)==0) atomicAdd(&gbuf[qc + j*16 + (lane&15)], cp);
    }
  }
}

// ---------------- agg1: 2 waves/node, online softmax, x4 unrolled gather ----------------

__global__ __launch_bounds__(512) void agg1(const ushort_t* __restrict__ h1b, const int* __restrict__ rowptr,
                     const int* __restrict__ csrc,
                     const float* __restrict__ s1n, const float* __restrict__ d1n,
                     const float* __restrict__ cae1, float* __restrict__ elog,
                     const float* __restrict__ b1, ushort_t* __restrict__ out1b){
  __shared__ float part[4][512];
  int tid = threadIdx.x;
  int nodeLoc = tid>>7;            // 0..3
  int wv = (tid>>6)&1;             // 0/1
  int lane = tid&63;
  int n = blockIdx.x*4 + nodeLoc;
  int beg = rowptr[n], end = rowptr[n+1];
  int h12 = lane&3;
  float dh = d1n[n*4 + h12];
  float m = -1e30f, ss = 0.f;
  for(int base=beg; base<end; base+=16){
    int e = base + (lane>>2);
    if(e<end){
      float t = s1n[csrc[e]*4 + h12] + dh + cae1[e*4 + h12];
      t = t>0.f? t : 0.2f*t;
      if(wv==0) elog[e*4 + h12] = t;
      float nm = fmaxf(m, t);
      ss = ss*__expf(m-nm) + __expf(t-nm);
      m = nm;
    }
  }
  #pragma unroll
  for(int o=4;o<=32;o<<=1){
    float mo = __shfl_xor(m, o, 64), so = __shfl_xor(ss, o, 64);
    float nm = fmaxf(m, mo);
    ss = ss*__expf(m-nm) + so*__expf(mo-nm);
    m = nm;
  }
  float inv = ss>0.f ? 1.f/ss : 0.f;
  int hq = lane>>4;
  float mq   = __shfl(m,   hq, 64);
  float invq = __shfl(inv, hq, 64);
  __syncthreads();                 // elog visible to both waves
  // contiguous edge halves per wave
  int deg = end-beg;
  int half = (deg+1)>>1;
  int gb = beg + wv*half;
  int ge = wv ? end : beg+half;
  float acc[8] = {};
  int i = gb;
  for(; i+3<ge; i+=4){
    int s0 = csrc[i], s1 = csrc[i+1], s2 = csrc[i+2], s3 = csrc[i+3];
    float w0 = __expf(elog[i*4 + hq]     - mq)*invq;
    float w1 = __expf(elog[(i+1)*4 + hq] - mq)*invq;
    float w2 = __expf(elog[(i+2)*4 + hq] - mq)*invq;
    float w3 = __expf(elog[(i+3)*4 + hq] - mq)*invq;
    uint4 v0 = *(const uint4*)(h1b + (long)s0*HH + lane*8);
    uint4 v1 = *(const uint4*)(h1b + (long)s1*HH + lane*8);
    uint4 v2 = *(const uint4*)(h1b + (long)s2*HH + lane*8);
    uint4 v3 = *(const uint4*)(h1b + (long)s3*HH + lane*8);
    acc[0] += w0*lo_of(v0.x) + w1*lo_of(v1.x) + w2*lo_of(v2.x) + w3*lo_of(v3.x);
    acc[1] += w0*hi_of(v0.x) + w1*hi_of(v1.x) + w2*hi_of(v2.x) + w3*hi_of(v3.x);
    acc[2] += w0*lo_of(v0.y) + w1*lo_of(v1.y) + w2*lo_of(v2.y) + w3*lo_of(v3.y);
    acc[3] += w0*hi_of(v0.y) + w1*hi_of(v1.y) + w2*hi_of(v2.y) + w3*hi_of(v3.y);
    acc[4] += w0*lo_of(v0.z) + w1*lo_of(v1.z) + w2*lo_of(v2.z) + w3*lo_of(v3.z);
    acc[5] += w0*hi_of(v0.z) + w1*hi_of(v1.z) + w2*hi_of(v2.z) + w3*hi_of(v3.z);
    acc[6] += w0*lo_of(v0.w) + w1*lo_of(v1.w) + w2*lo_of(v2.w) + w3*lo_of(v3.w);
    acc[7] += w0*hi_of(v0.w) + w1*hi_of(v1.w) + w2*hi_of(v2.w) + w3*hi_of(v3.w);
  }
  for(; i<ge; i++){
    int s0 = csrc[i];
    float w0 = __expf(elog[i*4 + hq] - mq)*invq;
    uint4 v0 = *(const uint4*)(h1b + (long)s0*HH + lane*8);
    acc[0] += w0*lo_of(v0.x); acc[1] += w0*hi_of(v0.x);
    acc[2] += w0*lo_of(v0.y); acc[3] += w0*hi_of(v0.y);
    acc[4] += w0*lo_of(v0.z); acc[5] += w0*hi_of(v0.z);
    acc[6] += w0*lo_of(v0.w); acc[7] += w0*hi_of(v0.w);
  }
  if(wv==1){
    #pragma unroll
    for(int c=0;c<8;c++) part[nodeLoc][c*64 + lane] = acc[c];
  }
  __syncthreads();
  if(wv==0){
    #pragma unroll
    for(int c=0;c<8;c++) acc[c] += part[nodeLoc][c*64 + lane];
    float4 bl = ((const float4*)b1)[lane*2];
    float4 bh = ((const float4*)b1)[lane*2+1];
    float bb[8] = {bl.x,bl.y,bl.z,bl.w,bh.x,bh.y,bh.z,bh.w};
    ushort_t o8[8];
    #pragma unroll
    for(int c=0;c<8;c++){
      float o = acc[c] + bb[c];
      o8[c] = f2bf(o>0.f? o : __expf(o)-1.f);   // ELU
    }
    uint4 pk;
    pk.x = (unsigned)o8[0] | ((unsigned)o8[1]<<16);
    pk.y = (unsigned)o8[2] | ((unsigned)o8[3]<<16);
    pk.z = (unsigned)o8[4] | ((unsigned)o8[5]<<16);
    pk.w = (unsigned)o8[6] | ((unsigned)o8[7]<<16);
    *(uint4*)(out1b + (long)n*HH + lane*8) = pk;
  }
}

__global__ void agg2(const ushort_t* __restrict__ h2b, const int* __restrict__ rowptr,
                     const int* __restrict__ csrc,
                     const float* __restrict__ s2n, const float* __restrict__ d2n,
                     const float* __restrict__ cae2, float* __restrict__ elog,
                     const float* __restrict__ b2, float* __restrict__ out2){
  int n = blockIdx.x*4 + (threadIdx.x>>6);
  int lane = threadIdx.x&63;
  int beg = rowptr[n], end = rowptr[n+1];
  float dn = d2n[n];
  float m = -1e30f, ss = 0.f;
  for(int e=beg+lane; e<end; e+=64){
    float t = s2n[csrc[e]] + dn + cae2[e];
    t = t>0.f? t : 0.2f*t;
    elog[e] = t;
    float nm = fmaxf(m, t);
    ss = ss*__expf(m-nm) + __expf(t-nm);
    m = nm;
  }
  #pragma unroll
  for(int o=1;o<=32;o<<=1){
    float mo = __shfl_xor(m, o, 64), so = __shfl_xor(ss, o, 64);
    float nm = fmaxf(m, mo);
    ss = ss*__expf(m-nm) + so*__expf(mo-nm);
    m = nm;
  }
  float inv = ss>0.f ? 1.f/ss : 0.f;
  float a0=0.f, a1=0.f;
  int i = beg;
  for(; i+3<end; i+=4){
    int s0 = csrc[i], s1 = csrc[i+1], s2 = csrc[i+2], s3 = csrc[i+3];
    float w0 = __expf(elog[i]-m)*inv;
    float w1 = __expf(elog[i+1]-m)*inv;
    float w2 = __expf(elog[i+2]-m)*inv;
    float w3 = __expf(elog[i+3]-m)*inv;
    unsigned v0 = *(const unsigned*)(h2b + (long)s0*HIDD + 2*lane);
    unsigned v1 = *(const unsigned*)(h2b + (long)s1*HIDD + 2*lane);
    unsigned v2 = *(const unsigned*)(h2b + (long)s2*HIDD + 2*lane);
    unsigned v3 = *(const unsigned*)(h2b + (long)s3*HIDD + 2*lane);
    a0 += w0*lo_of(v0) + w1*lo_of(v1) + w2*lo_of(v2) + w3*lo_of(v3);
    a1 += w0*hi_of(v0) + w1*hi_of(v1) + w2*hi_of(v2) + w3*hi_of(v3);
  }
  for(; i<end; i++){
    float w0 = __expf(elog[i]-m)*inv;
    unsigned v0 = *(const unsigned*)(h2b + (long)csrc[i]*HIDD + 2*lane);
    a0 += w0*lo_of(v0); a1 += w0*hi_of(v0);
  }
  float o0 = a0 + b2[2*lane];
  float o1 = a1 + b2[2*lane+1];
  float2 pk;
  pk.x = o0>0.f? o0 : __expf(o0)-1.f;
  pk.y = o1>0.f? o1 : __expf(o1)-1.f;
  *(float2*)(out2 + (long)n*HIDD + 2*lane) = pk;
}

__global__ void sigmoid_g(const float* __restrict__ gbuf, float* __restrict__ gout){
  int c = threadIdx.x;
  float m = gbuf[c] * (1.0f/NN);
  gout[c] = 1.f/(1.f+__expf(-m));
}

// ---------------- launch ----------------

extern "C" void kernel_launch(void* const* d_in, const int* in_sizes, int n_in,
                              void* d_out, int out_size, void* d_ws, size_t ws_size,
                              hipStream_t stream){
  const float* x    = (const float*)d_in[0];
  const int*   ei   = (const int*)  d_in[1];
  const float* ea   = (const float*)d_in[2];
  const float* W1   = (const float*)d_in[3];
  const float* We1  = (const float*)d_in[4];
  const float* as1  = (const float*)d_in[5];
  const float* ad1  = (const float*)d_in[6];
  const float* ae1  = (const float*)d_in[7];
  const float* b1   = (const float*)d_in[8];
  const float* W2   = (const float*)d_in[9];
  const float* We2  = (const float*)d_in[10];
  const float* as2  = (const float*)d_in[11];
  const float* ad2  = (const float*)d_in[12];
  const float* ae2  = (const float*)d_in[13];
  const float* b2   = (const float*)d_in[14];
  const float* P1   = (const float*)d_in[15];
  const float* pb1  = (const float*)d_in[16];
  const float* pra  = (const float*)d_in[17];
  const float* P2   = (const float*)d_in[18];
  const float* pb2  = (const float*)d_in[19];
  float* out = (float*)d_out;

  char* wsp = (char*)d_ws;
  size_t off = 0;
  auto alloc = [&](size_t bytes)->char*{
    char* p = wsp + off;
    off += (bytes + 255) & ~(size_t)255;
    return p;
  };
  ushort_t* h1b  = (ushort_t*)alloc(sizeof(ushort_t)*(size_t)NN*HH);
  ushort_t* out1b= (ushort_t*)alloc(sizeof(ushort_t)*(size_t)NN*HH);
  ushort_t* h2b  = (ushort_t*)alloc(sizeof(ushort_t)*(size_t)NN*HIDD);
  float*    out2 = (float*)  alloc(sizeof(float)*(size_t)NN*HIDD);
  float*    zb   = (float*)  alloc(sizeof(float)*(size_t)NN*HIDD);
  ushort_t* xb   = (ushort_t*)alloc(sizeof(ushort_t)*(size_t)NN*FIN);
  ushort_t* W1t  = (ushort_t*)alloc(sizeof(ushort_t)*(size_t)HH*FIN);
  ushort_t* W2t  = (ushort_t*)alloc(sizeof(ushort_t)*(size_t)HIDD*HH);
  ushort_t* P1th = (ushort_t*)alloc(sizeof(ushort_t)*(size_t)HIDD*HIDD);
  ushort_t* P1tl = (ushort_t*)alloc(sizeof(ushort_t)*(size_t)HIDD*HIDD);
  ushort_t* P2th = (ushort_t*)alloc(sizeof(ushort_t)*(size_t)HIDD*HIDD);
  ushort_t* P2tl = (ushort_t*)alloc(sizeof(ushort_t)*(size_t)HIDD*HIDD);
  float* s1n   = (float*)alloc(sizeof(float)*NN*NHEAD);
  float* d1n   = (float*)alloc(sizeof(float)*NN*NHEAD);
  float* s2n   = (float*)alloc(sizeof(float)*NN);
  float* d2n   = (float*)alloc(sizeof(float)*NN);
  float* v1    = (float*)alloc(sizeof(float)*FE*NHEAD);
  float* v2    = (float*)alloc(sizeof(float)*FE);
  float* cae1  = (float*)alloc(sizeof(float)*(size_t)E2*NHEAD);
  float* elog1 = (float*)alloc(sizeof(float)*(size_t)E2*NHEAD);
  float* cae2  = (float*)alloc(sizeof(float)*(size_t)E2);
  float* elog2 = (float*)alloc(sizeof(float)*(size_t)E2);
  int*   rowptr= (int*)  alloc(sizeof(int)*(NN+1));
  int*   csrc  = (int*)  alloc(sizeof(int)*(size_t)E2);
  // zero-init trio: adjacent for one memset
  int*   cnt   = (int*)  alloc(sizeof(int)*NN);
  int*   fcnt  = (int*)  alloc(sizeof(int)*NN);
  float* gbuf  = (float*)alloc(sizeof(float)*HIDD);

  hipMemsetAsync(cnt, 0, 80128 + 80128 + 512, stream);

  prep    <<<8397, 256, 0, stream>>>(ei, cnt, x, xb, W1, W1t, W2, W2t,
                                     P1, P1th, P1tl, P2, P2th, P2tl,
                                     We1, ae1, We2, ae2, v1, v2);
  scan_k  <<<1, 1024, 0, stream>>>(cnt, rowptr);
  csr_fill<<<EE/256, 256, 0, stream>>>(ei, ea, v1, v2, rowptr, fcnt, csrc, cae1, cae2);

  // layer 1 (GEMM + fused attn scalars)
  gemm1_attn<<<dim3(NHEAD, (NN+127)/128), 256, 0, stream>>>(xb, W1t, h1b, NN, as1, ad1, s1n, d1n);
  agg1      <<<NN/4, 512, 0, stream>>>(h1b, rowptr, csrc, s1n, d1n, cae1, elog1, b1, out1b);

  // layer 2 (GEMM + fused attn scalars)
  gemm64_attn<<<dim3(1, (NN+63)/64), 256, 0, stream>>>(out1b, W2t, h2b, NN, as2, ad2, s2n, d2n);
  agg2       <<<NN/4, 256, 0, stream>>>(h2b, rowptr, csrc, s2n, d2n, cae2, elog2, b2, out2);

  // projection head (split-bf16 MFMA, fp32-accurate); proj2 fuses colsum
  mfma_proj<<<(NN+63)/64, 256, 0, stream>>>(out2, P1th, P1tl, zb, NN, pb1, pra, 1, nullptr);
  mfma_proj<<<(NN+63)/64, 256, 0, stream>>>(zb,  P2th, P2tl, out, NN, pb2, nullptr, 0, gbuf);

  sigmoid_g<<<1, 128, 0, stream>>>(gbuf, out + (size_t)NN*HIDD);
}

// Round 8
// 394.807 us; speedup vs baseline: 2.0091x; 1.0959x over previous
//
#include <hip/hip_runtime.h>
#include <hip/hip_bf16.h>

// GRN_GAT_Encoder round 8:
// r7: 2-wave agg1 regressed (duplicated logit pass); ~170us in 2nd-tier + gaps.
// r8: agg1/agg2 stage logits+indices in LDS (1 wave/node, CAP=160, overflow fallback)
//     -> elog globals die, gather loop has zero small global loads.
//     proj1+proj2+colsum fused in-block (z via LDS, stride-132 pad); csr_fill+gemm1
//     merged block-partitioned. 8 dispatches + memset.

#define NN    20000
#define EE    320000
#define E2    640000
#define FIN   256
#define FE    32
#define HIDD  128
#define NHEAD 4
#define HH    512   // NHEAD*HIDD
#define CAP   160   // max staged in-degree per node (mean 32, max ~70 for this graph)
#define AW    132   // padded LDS row stride (ushorts) for proj A tiles

typedef unsigned short ushort_t;
typedef short frag8 __attribute__((ext_vector_type(8)));
typedef float f32x4 __attribute__((ext_vector_type(4)));

__device__ inline ushort_t f2bf(float f){
  unsigned x = __float_as_uint(f);
  unsigned r = (x + 0x7fffu + ((x>>16)&1u)) >> 16;
  return (ushort_t)r;
}
__device__ inline float bf2f(ushort_t u){ return __uint_as_float(((unsigned)u)<<16); }
__device__ inline float lo_of(unsigned v){ return __uint_as_float(v<<16); }
__device__ inline float hi_of(unsigned v){ return __uint_as_float(v & 0xffff0000u); }

// ---------------- fused prep ----------------
__global__ void prep(const int* __restrict__ ei, int* __restrict__ cnt,
                     const float* __restrict__ x, ushort_t* __restrict__ xb,
                     const float* __restrict__ W1, ushort_t* __restrict__ W1t,
                     const float* __restrict__ W2, ushort_t* __restrict__ W2t,
                     const float* __restrict__ P1, ushort_t* __restrict__ P1th, ushort_t* __restrict__ P1tl,
                     const float* __restrict__ P2, ushort_t* __restrict__ P2th, ushort_t* __restrict__ P2tl,
                     const float* __restrict__ We1, const float* __restrict__ ae1,
                     const float* __restrict__ We2, const float* __restrict__ ae2,
                     float* __restrict__ v1, float* __restrict__ v2){
  int b = blockIdx.x, tid = threadIdx.x;
  if(b < 2500){
    int e = b*256 + tid;
    int dst = (e < EE) ? ei[EE + e] : ei[e - EE];
    atomicAdd(&cnt[dst], 1);
  } else if(b < 7500){
    int i = (b-2500)*256 + tid;
    float4 v = ((const float4*)x)[i];
    ushort4 o; o.x=f2bf(v.x); o.y=f2bf(v.y); o.z=f2bf(v.z); o.w=f2bf(v.w);
    ((ushort4*)xb)[i] = o;
  } else if(b < 8012){
    int idx = (b-7500)*256 + tid;               // FIN*HH
    int k = idx>>9, n = idx&511;
    W1t[n*FIN + k] = f2bf(W1[idx]);
  } else if(b < 8268){
    int idx = (b-8012)*256 + tid;               // HH*HIDD
    int k = idx>>7, n = idx&127;
    W2t[n*HH + k] = f2bf(W2[idx]);
  } else if(b < 8332){
    int idx = (b-8268)*256 + tid;               // HIDD*HIDD
    int k = idx>>7, n = idx&127;
    float v = P1[idx];
    ushort_t h = f2bf(v);
    P1th[n*HIDD + k] = h;
    P1tl[n*HIDD + k] = f2bf(v - bf2f(h));
  } else if(b < 8396){
    int idx = (b-8332)*256 + tid;
    int k = idx>>7, n = idx&127;
    float v = P2[idx];
    ushort_t h = f2bf(v);
    P2th[n*HIDD + k] = h;
    P2tl[n*HIDD + k] = f2bf(v - bf2f(h));
  } else {
    if(tid < FE*NHEAD){
      int f = tid>>2, h = tid&3;
      float s = 0.f;
      for(int c=0;c<HIDD;c++) s += We1[f*HH + h*HIDD + c] * ae1[h*HIDD + c];
      v1[f*4+h] = s;
    } else if(tid < FE*NHEAD + FE){
      int f = tid - FE*NHEAD;
      float s = 0.f;
      for(int c=0;c<HIDD;c++) s += We2[f*HIDD + c] * ae2[c];
      v2[f] = s;
    }
  }
}

__global__ void scan_k(const int* __restrict__ cnt, int* __restrict__ rowptr){
  __shared__ int sums[1024];
  int tid = threadIdx.x;
  const int per = (NN + 1023)/1024;
  int base = tid*per;
  int s = 0;
  for(int i=0;i<per;i++){ int idx=base+i; if(idx<NN) s += cnt[idx]; }
  sums[tid] = s; __syncthreads();
  for(int off=1; off<1024; off<<=1){
    int v = (tid>=off)? sums[tid-off] : 0;
    __syncthreads();
    sums[tid] += v;
    __syncthreads();
  }
  int run = (tid==0)? 0 : sums[tid-1];
  for(int i=0;i<per;i++){
    int idx = base+i;
    if(idx<=NN) rowptr[idx] = run;
    if(idx<NN)  run += cnt[idx];
  }
}

// ---------------- fused csr_fill | gemm1(+attn) ----------------
// blocks [0,1250): csr_fill.  [1250,1878): gemm1_attn (g=b-1250, head=g&3, mblk=g>>2).
__global__ __launch_bounds__(256) void csr_gemm1(
    const int* __restrict__ ei, const float* __restrict__ ea,
    const float* __restrict__ v1, const float* __restrict__ v2,
    const int* __restrict__ rowptr, int* __restrict__ fcnt,
    int* __restrict__ csrc, float* __restrict__ cae1, float* __restrict__ cae2,
    const ushort_t* __restrict__ A, const ushort_t* __restrict__ Bt,
    ushort_t* __restrict__ C, int M,
    const float* __restrict__ as1, const float* __restrict__ ad1,
    float* __restrict__ s1n, float* __restrict__ d1n){
  __shared__ ushort_t As[128*32];
  __shared__ ushort_t Bs[128*32];
  __shared__ float sred[2][128], dred[2][128];
  __shared__ float sv1[FE*NHEAD];
  __shared__ float sv2[FE];
  int tid = threadIdx.x;
  int b = blockIdx.x;
  if(b < 1250){
    // ---- csr_fill ----
    if(tid < FE*NHEAD) sv1[tid] = v1[tid];
    if(tid < FE)       sv2[tid] = v2[tid];
    __syncthreads();
    int e = b*256 + tid;
    int a = ei[e], bb = ei[EE+e];
    const float4* er4 = (const float4*)(ea + (long)e*FE);
    float a0=0,a1=0,a2=0,a3=0,ab=0;
    #pragma unroll
    for(int f4=0; f4<FE/4; f4++){
      float4 t = er4[f4];
      float tv[4] = {t.x, t.y, t.z, t.w};
      #pragma unroll
      for(int c=0;c<4;c++){
        int f = f4*4+c;
        float t1 = tv[c];
        a0 += t1*sv1[f*4+0]; a1 += t1*sv1[f*4+1]; a2 += t1*sv1[f*4+2]; a3 += t1*sv1[f*4+3];
        ab += t1*sv2[f];
      }
    }
    float4 c4; c4.x=a0; c4.y=a1; c4.z=a2; c4.w=a3;
    int pos = rowptr[bb] + atomicAdd(&fcnt[bb], 1);    // fwd
    csrc[pos] = a;
    *(float4*)(cae1 + (size_t)pos*4) = c4;
    cae2[pos] = ab;
    pos = rowptr[a] + atomicAdd(&fcnt[a], 1);          // rev
    csrc[pos] = bb;
    *(float4*)(cae1 + (size_t)pos*4) = c4;
    cae2[pos] = ab;
    return;
  }
  // ---- gemm1_attn ----
  int g = b - 1250;
  int head = g & 3;
  int m0 = (g>>2)*128, n0 = head*128;
  int w = tid>>6, lane = tid&63;
  int qr = (w>>1)*64, qc = (w&1)*64;
  int lrow = lane&15, koff = (lane>>4)*8;
  f32x4 acc[4][4] = {};
  for(int k0=0; k0<FIN; k0+=32){
    #pragma unroll
    for(int rep=0;rep<2;rep++){
      int segid = tid + rep*256;
      int row = segid>>2, off = (segid&3)*8;
      int gr = m0 + row;
      int4 va = (gr<M) ? *(const int4*)(A + (long)gr*FIN + k0 + off) : int4{0,0,0,0};
      *(int4*)&As[row*32 + off] = va;
      int4 vb = *(const int4*)(Bt + (long)(n0+row)*FIN + k0 + off);
      *(int4*)&Bs[row*32 + off] = vb;
    }
    __syncthreads();
    frag8 af[4], bfr[4];
    #pragma unroll
    for(int i=0;i<4;i++) af[i]  = *(const frag8*)&As[(qr + i*16 + lrow)*32 + koff];
    #pragma unroll
    for(int j=0;j<4;j++) bfr[j] = *(const frag8*)&Bs[(qc + j*16 + lrow)*32 + koff];
    #pragma unroll
    for(int i=0;i<4;i++)
      #pragma unroll
      for(int j=0;j<4;j++)
        acc[i][j] = __builtin_amdgcn_mfma_f32_16x16x32_bf16(af[i], bfr[j], acc[i][j], 0,0,0);
    __syncthreads();
  }
  #pragma unroll
  for(int i=0;i<4;i++)
    #pragma unroll
    for(int j=0;j<4;j++)
      #pragma unroll
      for(int r=0;r<4;r++){
        int row = m0 + qr + i*16 + (lane>>4)*4 + r;
        int col = n0 + qc + j*16 + (lane&15);
        if(row<M) C[(long)row*HH + col] = f2bf(acc[i][j][r]);
      }
  float a_s[4], a_d[4];
  #pragma unroll
  for(int j=0;j<4;j++){
    a_s[j] = as1[head*HIDD + qc + j*16 + (lane&15)];
    a_d[j] = ad1[head*HIDD + qc + j*16 + (lane&15)];
  }
  #pragma unroll
  for(int i=0;i<4;i++)
    #pragma unroll
    for(int r=0;r<4;r++){
      float sp = acc[i][0][r]*a_s[0] + acc[i][1][r]*a_s[1] + acc[i][2][r]*a_s[2] + acc[i][3][r]*a_s[3];
      float dp = acc[i][0][r]*a_d[0] + acc[i][1][r]*a_d[1] + acc[i][2][r]*a_d[2] + acc[i][3][r]*a_d[3];
      #pragma unroll
      for(int o=1;o<=8;o<<=1){ sp += __shfl_xor(sp,o,64); dp += __shfl_xor(dp,o,64); }
      if((lane&15)==0){
        int rl = qr + i*16 + (lane>>4)*4 + r;
        sred[w&1][rl] = sp;
        dred[w&1][rl] = dp;
      }
    }
  __syncthreads();
  if(tid < 128){
    int gr = m0 + tid;
    if(gr < M){
      s1n[gr*4 + head] = sred[0][tid] + sred[1][tid];
      d1n[gr*4 + head] = dred[0][tid] + dred[1][tid];
    }
  }
}

// ---------------- gemm64 (+fused node_attn2) ----------------
__global__ __launch_bounds__(256) void gemm64_attn(const ushort_t* __restrict__ A, const ushort_t* __restrict__ Bt,
                                                   ushort_t* __restrict__ C, int M,
                                                   const float* __restrict__ as2, const float* __restrict__ ad2,
                                                   float* __restrict__ s2n, float* __restrict__ d2n){
  __shared__ ushort_t As[64*32];
  __shared__ ushort_t Bs[128*32];
  __shared__ float sred[4][64], dred[4][64];
  int tid = threadIdx.x;
  int m0 = blockIdx.y*64;
  int w = tid>>6, lane = tid&63;
  int qc = w*32;
  int lrow = lane&15, koff = (lane>>4)*8;
  f32x4 acc[4][2] = {};
  for(int k0=0; k0<HH; k0+=32){
    {
      int row = tid>>2, off = (tid&3)*8;
      int gr = m0 + row;
      int4 va = (gr<M) ? *(const int4*)(A + (long)gr*HH + k0 + off) : int4{0,0,0,0};
      *(int4*)&As[row*32 + off] = va;
    }
    #pragma unroll
    for(int rep=0;rep<2;rep++){
      int segid = tid + rep*256;
      int row = segid>>2, off = (segid&3)*8;
      int4 vb = *(const int4*)(Bt + (long)row*HH + k0 + off);
      *(int4*)&Bs[row*32 + off] = vb;
    }
    __syncthreads();
    frag8 af[4], bfr[2];
    #pragma unroll
    for(int i=0;i<4;i++) af[i]  = *(const frag8*)&As[(i*16 + lrow)*32 + koff];
    #pragma unroll
    for(int j=0;j<2;j++) bfr[j] = *(const frag8*)&Bs[(qc + j*16 + lrow)*32 + koff];
    #pragma unroll
    for(int i=0;i<4;i++)
      #pragma unroll
      for(int j=0;j<2;j++)
        acc[i][j] = __builtin_amdgcn_mfma_f32_16x16x32_bf16(af[i], bfr[j], acc[i][j], 0,0,0);
    __syncthreads();
  }
  #pragma unroll
  for(int i=0;i<4;i++)
    #pragma unroll
    for(int j=0;j<2;j++)
      #pragma unroll
      for(int r=0;r<4;r++){
        int row = m0 + i*16 + (lane>>4)*4 + r;
        int col = qc + j*16 + (lane&15);
        if(row<M) C[(long)row*HIDD + col] = f2bf(acc[i][j][r]);
      }
  float a_s[2], a_d[2];
  #pragma unroll
  for(int j=0;j<2;j++){
    a_s[j] = as2[qc + j*16 + (lane&15)];
    a_d[j] = ad2[qc + j*16 + (lane&15)];
  }
  #pragma unroll
  for(int i=0;i<4;i++)
    #pragma unroll
    for(int r=0;r<4;r++){
      float sp = acc[i][0][r]*a_s[0] + acc[i][1][r]*a_s[1];
      float dp = acc[i][0][r]*a_d[0] + acc[i][1][r]*a_d[1];
      #pragma unroll
      for(int o=1;o<=8;o<<=1){ sp += __shfl_xor(sp,o,64); dp += __shfl_xor(dp,o,64); }
      if((lane&15)==0){
        int rl = i*16 + (lane>>4)*4 + r;
        sred[w][rl] = sp;
        dred[w][rl] = dp;
      }
    }
  __syncthreads();
  if(tid < 64){
    int gr = m0 + tid;
    if(gr < M){
      s2n[gr] = sred[0][tid]+sred[1][tid]+sred[2][tid]+sred[3][tid];
      d2n[gr] = dred[0][tid]+dred[1][tid]+dred[2][tid]+dred[3][tid];
    }
  }
}

// ---------------- agg1: LDS-staged softmax, 1 wave/node, x4 gather ----------------
__global__ __launch_bounds__(256) void agg1(const ushort_t* __restrict__ h1b, const int* __restrict__ rowptr,
                     const int* __restrict__ csrc,
                     const float* __restrict__ s1n, const float* __restrict__ d1n,
                     const float* __restrict__ cae1,
                     const float* __restrict__ b1, ushort_t* __restrict__ out1b){
  __shared__ float stlog[4][CAP*4];    // raw logits per (edge,head)
  __shared__ int   sidx[4][CAP];       // src indices
  int tid = threadIdx.x;
  int wv = tid>>6, lane = tid&63;
  int n = blockIdx.x*4 + wv;
  int beg = rowptr[n], end = rowptr[n+1];
  int deg = end - beg;
  int h12 = lane&3;
  float dh = d1n[n*4 + h12];
  float m = -1e30f, ss = 0.f;
  for(int base=beg; base<end; base+=16){
    int e = base + (lane>>2);
    if(e<end){
      int s = csrc[e];
      float t = s1n[s*4 + h12] + dh + cae1[e*4 + h12];
      t = t>0.f? t : 0.2f*t;
      int j = e - beg;
      if(j < CAP){
        stlog[wv][j*4 + h12] = t;
        if(h12==0) sidx[wv][j] = s;
      }
      float nm = fmaxf(m, t);
      ss = ss*__expf(m-nm) + __expf(t-nm);
      m = nm;
    }
  }
  #pragma unroll
  for(int o=4;o<=32;o<<=1){
    float mo = __shfl_xor(m, o, 64), so = __shfl_xor(ss, o, 64);
    float nm = fmaxf(m, mo);
    ss = ss*__expf(m-nm) + so*__expf(mo-nm);
    m = nm;
  }
  float inv = ss>0.f ? 1.f/ss : 0.f;
  int hq = lane>>4;
  float mq   = __shfl(m,   hq, 64);
  float invq = __shfl(inv, hq, 64);
  float dhq  = d1n[n*4 + hq];
  int capn = deg < CAP ? deg : CAP;
  float acc[8] = {};
  int j = 0;
  for(; j+3<capn; j+=4){
    int s0 = sidx[wv][j], s1 = sidx[wv][j+1], s2 = sidx[wv][j+2], s3 = sidx[wv][j+3];
    float w0 = __expf(stlog[wv][(j  )*4 + hq] - mq)*invq;
    float w1 = __expf(stlog[wv][(j+1)*4 + hq] - mq)*invq;
    float w2 = __expf(stlog[wv][(j+2)*4 + hq] - mq)*invq;
    float w3 = __expf(stlog[wv][(j+3)*4 + hq] - mq)*invq;
    uint4 v0 = *(const uint4*)(h1b + (long)s0*HH + lane*8);
    uint4 v1 = *(const uint4*)(h1b + (long)s1*HH + lane*8);
    uint4 v2 = *(const uint4*)(h1b + (long)s2*HH + lane*8);
    uint4 v3 = *(const uint4*)(h1b + (long)s3*HH + lane*8);
    acc[0] += w0*lo_of(v0.x) + w1*lo_of(v1.x) + w2*lo_of(v2.x) + w3*lo_of(v3.x);
    acc[1] += w0*hi_of(v0.x) + w1*hi_of(v1.x) + w2*hi_of(v2.x) + w3*hi_of(v3.x);
    acc[2] += w0*lo_of(v0.y) + w1*lo_of(v1.y) + w2*lo_of(v2.y) + w3*lo_of(v3.y);
    acc[3] += w0*hi_of(v0.y) + w1*hi_of(v1.y) + w2*hi_of(v2.y) + w3*hi_of(v3.y);
    acc[4] += w0*lo_of(v0.z) + w1*lo_of(v1.z) + w2*lo_of(v2.z) + w3*lo_of(v3.z);
    acc[5] += w0*hi_of(v0.z) + w1*hi_of(v1.z) + w2*hi_of(v2.z) + w3*hi_of(v3.z);
    acc[6] += w0*lo_of(v0.w) + w1*lo_of(v1.w) + w2*lo_of(v2.w) + w3*lo_of(v3.w);
    acc[7] += w0*hi_of(v0.w) + w1*hi_of(v1.w) + w2*hi_of(v2.w) + w3*hi_of(v3.w);
  }
  for(; j<capn; j++){
    int s0 = sidx[wv][j];
    float w0 = __expf(stlog[wv][j*4 + hq] - mq)*invq;
    uint4 v0 = *(const uint4*)(h1b + (long)s0*HH + lane*8);
    acc[0] += w0*lo_of(v0.x); acc[1] += w0*hi_of(v0.x);
    acc[2] += w0*lo_of(v0.y); acc[3] += w0*hi_of(v0.y);
    acc[4] += w0*lo_of(v0.z); acc[5] += w0*hi_of(v0.z);
    acc[6] += w0*lo_of(v0.w); acc[7] += w0*hi_of(v0.w);
  }
  for(; j<deg; j++){   // overflow fallback (deg > CAP, never for this graph)
    int e = beg + j;
    int s0 = csrc[e];
    float t = s1n[s0*4 + hq] + dhq + cae1[e*4 + hq];
    t = t>0.f? t : 0.2f*t;
    float w0 = __expf(t - mq)*invq;
    uint4 v0 = *(const uint4*)(h1b + (long)s0*HH + lane*8);
    acc[0] += w0*lo_of(v0.x); acc[1] += w0*hi_of(v0.x);
    acc[2] += w0*lo_of(v0.y); acc[3] += w0*hi_of(v0.y);
    acc[4] += w0*lo_of(v0.z); acc[5] += w0*hi_of(v0.z);
    acc[6] += w0*lo_of(v0.w); acc[7] += w0*hi_of(v0.w);
  }
  float4 bl = ((const float4*)b1)[lane*2];
  float4 bh = ((const float4*)b1)[lane*2+1];
  float bb[8] = {bl.x,bl.y,bl.z,bl.w,bh.x,bh.y,bh.z,bh.w};
  ushort_t o8[8];
  #pragma unroll
  for(int c=0;c<8;c++){
    float o = acc[c] + bb[c];
    o8[c] = f2bf(o>0.f? o : __expf(o)-1.f);   // ELU
  }
  uint4 pk;
  pk.x = (unsigned)o8[0] | ((unsigned)o8[1]<<16);
  pk.y = (unsigned)o8[2] | ((unsigned)o8[3]<<16);
  pk.z = (unsigned)o8[4] | ((unsigned)o8[5]<<16);
  pk.w = (unsigned)o8[6] | ((unsigned)o8[7]<<16);
  *(uint4*)(out1b + (long)n*HH + lane*8) = pk;
}

// ---------------- agg2: LDS-staged softmax ----------------
__global__ __launch_bounds__(256) void agg2(const ushort_t* __restrict__ h2b, const int* __restrict__ rowptr,
                     const int* __restrict__ csrc,
                     const float* __restrict__ s2n, const float* __restrict__ d2n,
                     const float* __restrict__ cae2,
                     const float* __restrict__ b2, float* __restrict__ out2){
  __shared__ float stl[4][CAP];
  __shared__ int   sid[4][CAP];
  int tid = threadIdx.x;
  int wv = tid>>6, lane = tid&63;
  int n = blockIdx.x*4 + wv;
  int beg = rowptr[n], end = rowptr[n+1];
  int deg = end - beg;
  float dn = d2n[n];
  float m = -1e30f, ss = 0.f;
  for(int e=beg+lane; e<end; e+=64){
    int s = csrc[e];
    float t = s2n[s] + dn + cae2[e];
    t = t>0.f? t : 0.2f*t;
    int j = e - beg;
    if(j < CAP){ stl[wv][j] = t; sid[wv][j] = s; }
    float nm = fmaxf(m, t);
    ss = ss*__expf(m-nm) + __expf(t-nm);
    m = nm;
  }
  #pragma unroll
  for(int o=1;o<=32;o<<=1){
    float mo = __shfl_xor(m, o, 64), so = __shfl_xor(ss, o, 64);
    float nm = fmaxf(m, mo);
    ss = ss*__expf(m-nm) + so*__expf(mo-nm);
    m = nm;
  }
  float inv = ss>0.f ? 1.f/ss : 0.f;
  int capn = deg < CAP ? deg : CAP;
  float a0=0.f, a1=0.f;
  int j = 0;
  for(; j+3<capn; j+=4){
    int s0 = sid[wv][j], s1 = sid[wv][j+1], s2 = sid[wv][j+2], s3 = sid[wv][j+3];
    float w0 = __expf(stl[wv][j]  -m)*inv;
    float w1 = __expf(stl[wv][j+1]-m)*inv;
    float w2 = __expf(stl[wv][j+2]-m)*inv;
    float w3 = __expf(stl[wv][j+3]-m)*inv;
    unsigned v0 = *(const unsigned*)(h2b + (long)s0*HIDD + 2*lane);
    unsigned v1 = *(const unsigned*)(h2b + (long)s1*HIDD + 2*lane);
    unsigned v2 = *(const unsigned*)(h2b + (long)s2*HIDD + 2*lane);
    unsigned v3 = *(const unsigned*)(h2b + (long)s3*HIDD + 2*lane);
    a0 += w0*lo_of(v0) + w1*lo_of(v1) + w2*lo_of(v2) + w3*lo_of(v3);
    a1 += w0*hi_of(v0) + w1*hi_of(v1) + w2*hi_of(v2) + w3*hi_of(v3);
  }
  for(; j<capn; j++){
    float w0 = __expf(stl[wv][j]-m)*inv;
    unsigned v0 = *(const unsigned*)(h2b + (long)sid[wv][j]*HIDD + 2*lane);
    a0 += w0*lo_of(v0); a1 += w0*hi_of(v0);
  }
  for(; j<deg; j++){   // overflow fallback
    int e = beg + j;
    int s0 = csrc[e];
    float t = s2n[s0] + dn + cae2[e];
    t = t>0.f? t : 0.2f*t;
    float w0 = __expf(t-m)*inv;
    unsigned v0 = *(const unsigned*)(h2b + (long)s0*HIDD + 2*lane);
    a0 += w0*lo_of(v0); a1 += w0*hi_of(v0);
  }
  float o0 = a0 + b2[2*lane];
  float o1 = a1 + b2[2*lane+1];
  float2 pk;
  pk.x = o0>0.f? o0 : __expf(o0)-1.f;
  pk.y = o1>0.f? o1 : __expf(o1)-1.f;
  *(float2*)(out2 + (long)n*HIDD + 2*lane) = pk;
}

// ---------------- fused projection head: z=PReLU(A@P1+pb1); out=z@P2+pb2; colsum ------
__global__ __launch_bounds__(256) void proj_fused(const float* __restrict__ A,
    const ushort_t* __restrict__ P1th, const ushort_t* __restrict__ P1tl,
    const ushort_t* __restrict__ P2th, const ushort_t* __restrict__ P2tl,
    const float* __restrict__ pb1, const float* __restrict__ pra,
    const float* __restrict__ pb2, float* __restrict__ OUT, int M,
    float* __restrict__ gbuf){
  __shared__ ushort_t Ah[64*AW], Al[64*AW];     // split A tile (then z tile); stride 132
  __shared__ ushort_t Bh[128*32], Bl[128*32];
  int tid = threadIdx.x;
  int m0 = blockIdx.x*64;
  int w = tid>>6, lane = tid&63;
  int qc = w*32;
  int lrow = lane&15, koff2 = (lane>>4)*8;
  f32x4 acc[4][2] = {};
  // stage all of A (split) once
  {
    int row = tid>>2, cb = (tid&3)*8;
    int gr = m0 + row;
    for(int c0=0;c0<HIDD;c0+=32){
      float4 u0{0,0,0,0}, u1{0,0,0,0};
      if(gr<M){
        u0 = *(const float4*)(A + (long)gr*HIDD + c0 + cb);
        u1 = *(const float4*)(A + (long)gr*HIDD + c0 + cb + 4);
      }
      float vv[8] = {u0.x,u0.y,u0.z,u0.w,u1.x,u1.y,u1.z,u1.w};
      unsigned ph[4], pl[4];
      #pragma unroll
      for(int c=0;c<4;c++){
        ushort_t h0 = f2bf(vv[2*c]),   l0 = f2bf(vv[2*c]   - bf2f(h0));
        ushort_t h1 = f2bf(vv[2*c+1]), l1 = f2bf(vv[2*c+1] - bf2f(h1));
        ph[c] = (unsigned)h0 | ((unsigned)h1<<16);
        pl[c] = (unsigned)l0 | ((unsigned)l1<<16);
      }
      *(uint4*)&Ah[row*AW + c0 + cb] = *(uint4*)ph;
      *(uint4*)&Al[row*AW + c0 + cb] = *(uint4*)pl;
    }
  }
  __syncthreads();
  // phase A: z = A@P1^T
  for(int k0=0;k0<HIDD;k0+=32){
    #pragma unroll
    for(int rep=0;rep<2;rep++){
      int segid = tid + rep*256;
      int row = segid>>2, off = (segid&3)*8;
      *(int4*)&Bh[row*32 + off] = *(const int4*)(P1th + (long)row*HIDD + k0 + off);
      *(int4*)&Bl[row*32 + off] = *(const int4*)(P1tl + (long)row*HIDD + k0 + off);
    }
    __syncthreads();
    frag8 afh[4], afl[4], bfh[2], bfl[2];
    #pragma unroll
    for(int i=0;i<4;i++){
      afh[i] = *(const frag8*)&Ah[(i*16 + lrow)*AW + k0 + koff2];
      afl[i] = *(const frag8*)&Al[(i*16 + lrow)*AW + k0 + koff2];
    }
    #pragma unroll
    for(int j=0;j<2;j++){
      bfh[j] = *(const frag8*)&Bh[(qc + j*16 + lrow)*32 + koff2];
      bfl[j] = *(const frag8*)&Bl[(qc + j*16 + lrow)*32 + koff2];
    }
    #pragma unroll
    for(int i=0;i<4;i++)
      #pragma unroll
      for(int j=0;j<2;j++){
        acc[i][j] = __builtin_amdgcn_mfma_f32_16x16x32_bf16(afh[i], bfh[j], acc[i][j], 0,0,0);
        acc[i][j] = __builtin_amdgcn_mfma_f32_16x16x32_bf16(afh[i], bfl[j], acc[i][j], 0,0,0);
        acc[i][j] = __builtin_amdgcn_mfma_f32_16x16x32_bf16(afl[i], bfh[j], acc[i][j], 0,0,0);
      }
    __syncthreads();
  }
  // epilogue 1: z -> split back into Ah/Al
  float ap = pra[0];
  #pragma unroll
  for(int i=0;i<4;i++)
    #pragma unroll
    for(int j=0;j<2;j++)
      #pragma unroll
      for(int r=0;r<4;r++){
        int row = i*16 + (lane>>4)*4 + r;
        int col = qc + j*16 + (lane&15);
        float v = acc[i][j][r] + pb1[col];
        v = v>0.f? v : ap*v;
        ushort_t h = f2bf(v);
        Ah[row*AW + col] = h;
        Al[row*AW + col] = f2bf(v - bf2f(h));
        acc[i][j][r] = 0.f;
      }
  __syncthreads();
  // phase B: out = z@P2^T
  for(int k0=0;k0<HIDD;k0+=32){
    #pragma unroll
    for(int rep=0;rep<2;rep++){
      int segid = tid + rep*256;
      int row = segid>>2, off = (segid&3)*8;
      *(int4*)&Bh[row*32 + off] = *(const int4*)(P2th + (long)row*HIDD + k0 + off);
      *(int4*)&Bl[row*32 + off] = *(const int4*)(P2tl + (long)row*HIDD + k0 + off);
    }
    __syncthreads();
    frag8 afh[4], afl[4], bfh[2], bfl[2];
    #pragma unroll
    for(int i=0;i<4;i++){
      afh[i] = *(const frag8*)&Ah[(i*16 + lrow)*AW + k0 + koff2];
      afl[i] = *(const frag8*)&Al[(i*16 + lrow)*AW + k0 + koff2];
    }
    #pragma unroll
    for(int j=0;j<2;j++){
      bfh[j] = *(const frag8*)&Bh[(qc + j*16 + lrow)*32 + koff2];
      bfl[j] = *(const frag8*)&Bl[(qc + j*16 + lrow)*32 + koff2];
    }
    #pragma unroll
    for(int i=0;i<4;i++)
      #pragma unroll
      for(int j=0;j<2;j++){
        acc[i][j] = __builtin_amdgcn_mfma_f32_16x16x32_bf16(afh[i], bfh[j], acc[i][j], 0,0,0);
        acc[i][j] = __builtin_amdgcn_mfma_f32_16x16x32_bf16(afh[i], bfl[j], acc[i][j], 0,0,0);
        acc[i][j] = __builtin_amdgcn_mfma_f32_16x16x32_bf16(afl[i], bfh[j], acc[i][j], 0,0,0);
      }
    __syncthreads();
  }
  // epilogue 2: bias + store + colsum
  float cs[2] = {0.f, 0.f};
  #pragma unroll
  for(int i=0;i<4;i++)
    #pragma unroll
    for(int j=0;j<2;j++)
      #pragma unroll
      for(int r=0;r<4;r++){
        int rowg = m0 + i*16 + (lane>>4)*4 + r;
        int col = qc + j*16 + (lane&15);
        if(rowg<M){
          float v = acc[i][j][r] + pb2[col];
          OUT[(long)rowg*HIDD + col] = v;
          cs[j] += v;
        }
      }
  #pragma unroll
  for(int j=0;j<2;j++){
    cs[j] += __shfl_xor(cs[j],16,64);
    cs[j] += __shfl_xor(cs[j],32,64);
    if((lane>>4)==0) atomicAdd(&gbuf[qc + j*16 + (lane&15)], cs[j]);
  }
}

__global__ void sigmoid_g(const float* __restrict__ gbuf, float* __restrict__ gout){
  int c = threadIdx.x;
  float m = gbuf[c] * (1.0f/NN);
  gout[c] = 1.f/(1.f+__expf(-m));
}

// ---------------- launch ----------------

extern "C" void kernel_launch(void* const* d_in, const int* in_sizes, int n_in,
                              void* d_out, int out_size, void* d_ws, size_t ws_size,
                              hipStream_t stream){
  const float* x    = (const float*)d_in[0];
  const int*   ei   = (const int*)  d_in[1];
  const float* ea   = (const float*)d_in[2];
  const float* W1   = (const float*)d_in[3];
  const float* We1  = (const float*)d_in[4];
  const float* as1  = (const float*)d_in[5];
  const float* ad1  = (const float*)d_in[6];
  const float* ae1  = (const float*)d_in[7];
  const float* b1   = (const float*)d_in[8];
  const float* W2   = (const float*)d_in[9];
  const float* We2  = (const float*)d_in[10];
  const float* as2  = (const float*)d_in[11];
  const float* ad2  = (const float*)d_in[12];
  const float* ae2  = (const float*)d_in[13];
  const float* b2   = (const float*)d_in[14];
  const float* P1   = (const float*)d_in[15];
  const float* pb1  = (const float*)d_in[16];
  const float* pra  = (const float*)d_in[17];
  const float* P2   = (const float*)d_in[18];
  const float* pb2  = (const float*)d_in[19];
  float* out = (float*)d_out;

  char* wsp = (char*)d_ws;
  size_t off = 0;
  auto alloc = [&](size_t bytes)->char*{
    char* p = wsp + off;
    off += (bytes + 255) & ~(size_t)255;
    return p;
  };
  ushort_t* h1b  = (ushort_t*)alloc(sizeof(ushort_t)*(size_t)NN*HH);
  ushort_t* out1b= (ushort_t*)alloc(sizeof(ushort_t)*(size_t)NN*HH);
  ushort_t* h2b  = (ushort_t*)alloc(sizeof(ushort_t)*(size_t)NN*HIDD);
  float*    out2 = (float*)  alloc(sizeof(float)*(size_t)NN*HIDD);
  ushort_t* xb   = (ushort_t*)alloc(sizeof(ushort_t)*(size_t)NN*FIN);
  ushort_t* W1t  = (ushort_t*)alloc(sizeof(ushort_t)*(size_t)HH*FIN);
  ushort_t* W2t  = (ushort_t*)alloc(sizeof(ushort_t)*(size_t)HIDD*HH);
  ushort_t* P1th = (ushort_t*)alloc(sizeof(ushort_t)*(size_t)HIDD*HIDD);
  ushort_t* P1tl = (ushort_t*)alloc(sizeof(ushort_t)*(size_t)HIDD*HIDD);
  ushort_t* P2th = (ushort_t*)alloc(sizeof(ushort_t)*(size_t)HIDD*HIDD);
  ushort_t* P2tl = (ushort_t*)alloc(sizeof(ushort_t)*(size_t)HIDD*HIDD);
  float* s1n   = (float*)alloc(sizeof(float)*NN*NHEAD);
  float* d1n   = (float*)alloc(sizeof(float)*NN*NHEAD);
  float* s2n   = (float*)alloc(sizeof(float)*NN);
  float* d2n   = (float*)alloc(sizeof(float)*NN);
  float* v1    = (float*)alloc(sizeof(float)*FE*NHEAD);
  float* v2    = (float*)alloc(sizeof(float)*FE);
  float* cae1  = (float*)alloc(sizeof(float)*(size_t)E2*NHEAD);
  float* cae2  = (float*)alloc(sizeof(float)*(size_t)E2);
  int*   rowptr= (int*)  alloc(sizeof(int)*(NN+1));
  int*   csrc  = (int*)  alloc(sizeof(int)*(size_t)E2);
  // zero-init trio: adjacent for one memset
  int*   cnt   = (int*)  alloc(sizeof(int)*NN);
  int*   fcnt  = (int*)  alloc(sizeof(int)*NN);
  float* gbuf  = (float*)alloc(sizeof(float)*HIDD);

  hipMemsetAsync(cnt, 0, 80128 + 80128 + 512, stream);

  prep     <<<8397, 256, 0, stream>>>(ei, cnt, x, xb, W1, W1t, W2, W2t,
                                      P1, P1th, P1tl, P2, P2th, P2tl,
                                      We1, ae1, We2, ae2, v1, v2);
  scan_k   <<<1, 1024, 0, stream>>>(cnt, rowptr);
  csr_gemm1<<<1250 + 628, 256, 0, stream>>>(ei, ea, v1, v2, rowptr, fcnt, csrc, cae1, cae2,
                                            xb, W1t, h1b, NN, as1, ad1, s1n, d1n);
  agg1     <<<NN/4, 256, 0, stream>>>(h1b, rowptr, csrc, s1n, d1n, cae1, b1, out1b);
  gemm64_attn<<<dim3(1, (NN+63)/64), 256, 0, stream>>>(out1b, W2t, h2b, NN, as2, ad2, s2n, d2n);
  agg2     <<<NN/4, 256, 0, stream>>>(h2b, rowptr, csrc, s2n, d2n, cae2, b2, out2);
  proj_fused<<<(NN+63)/64, 256, 0, stream>>>(out2, P1th, P1tl, P2th, P2tl,
                                             pb1, pra, pb2, out, NN, gbuf);
  sigmoid_g<<<1, 128, 0, stream>>>(gbuf, out + (size_t)NN*HIDD);
}

// Round 9
// 373.425 us; speedup vs baseline: 2.1241x; 1.0573x over previous
//
#include <hip/hip_runtime.h>
#include <hip/hip_bf16.h>

// GRN_GAT_Encoder round 9:
// r8: agg1 86us, latency-bound at 2x its 44us FETCH floor (random gather misses 4MB/XCD L2).
// r9: agg1 restructured — 2 waves per node own DISJOINT 256-channel halves (8B/lane):
//     logit pass split by edge halves (LDS-merged partial online softmax), staged logits
//     converted ONCE to normalized weights in LDS (kills 16x-redundant exp in gather),
//     2x independent gather chains per node. agg2 gets the weight-precompute too
//     (64x-redundant exp). scan_k int4 loads/stores (was stride-80B scalar).

#define NN    20000
#define EE    320000
#define E2    640000
#define FIN   256
#define FE    32
#define HIDD  128
#define NHEAD 4
#define HH    512   // NHEAD*HIDD
#define CAP   160   // max staged in-degree (mean 32, max ~70 for random graph)
#define AW    132   // padded LDS row stride (ushorts) for proj A tiles

typedef unsigned short ushort_t;
typedef short frag8 __attribute__((ext_vector_type(8)));
typedef float f32x4 __attribute__((ext_vector_type(4)));

__device__ inline ushort_t f2bf(float f){
  unsigned x = __float_as_uint(f);
  unsigned r = (x + 0x7fffu + ((x>>16)&1u)) >> 16;
  return (ushort_t)r;
}
__device__ inline float bf2f(ushort_t u){ return __uint_as_float(((unsigned)u)<<16); }
__device__ inline float lo_of(unsigned v){ return __uint_as_float(v<<16); }
__device__ inline float hi_of(unsigned v){ return __uint_as_float(v & 0xffff0000u); }

// ---------------- fused prep ----------------
__global__ void prep(const int* __restrict__ ei, int* __restrict__ cnt,
                     const float* __restrict__ x, ushort_t* __restrict__ xb,
                     const float* __restrict__ W1, ushort_t* __restrict__ W1t,
                     const float* __restrict__ W2, ushort_t* __restrict__ W2t,
                     const float* __restrict__ P1, ushort_t* __restrict__ P1th, ushort_t* __restrict__ P1tl,
                     const float* __restrict__ P2, ushort_t* __restrict__ P2th, ushort_t* __restrict__ P2tl,
                     const float* __restrict__ We1, const float* __restrict__ ae1,
                     const float* __restrict__ We2, const float* __restrict__ ae2,
                     float* __restrict__ v1, float* __restrict__ v2){
  int b = blockIdx.x, tid = threadIdx.x;
  if(b < 2500){
    int e = b*256 + tid;
    int dst = (e < EE) ? ei[EE + e] : ei[e - EE];
    atomicAdd(&cnt[dst], 1);
  } else if(b < 7500){
    int i = (b-2500)*256 + tid;
    float4 v = ((const float4*)x)[i];
    ushort4 o; o.x=f2bf(v.x); o.y=f2bf(v.y); o.z=f2bf(v.z); o.w=f2bf(v.w);
    ((ushort4*)xb)[i] = o;
  } else if(b < 8012){
    int idx = (b-7500)*256 + tid;               // FIN*HH
    int k = idx>>9, n = idx&511;
    W1t[n*FIN + k] = f2bf(W1[idx]);
  } else if(b < 8268){
    int idx = (b-8012)*256 + tid;               // HH*HIDD
    int k = idx>>7, n = idx&127;
    W2t[n*HH + k] = f2bf(W2[idx]);
  } else if(b < 8332){
    int idx = (b-8268)*256 + tid;               // HIDD*HIDD
    int k = idx>>7, n = idx&127;
    float v = P1[idx];
    ushort_t h = f2bf(v);
    P1th[n*HIDD + k] = h;
    P1tl[n*HIDD + k] = f2bf(v - bf2f(h));
  } else if(b < 8396){
    int idx = (b-8332)*256 + tid;
    int k = idx>>7, n = idx&127;
    float v = P2[idx];
    ushort_t h = f2bf(v);
    P2th[n*HIDD + k] = h;
    P2tl[n*HIDD + k] = f2bf(v - bf2f(h));
  } else {
    if(tid < FE*NHEAD){
      int f = tid>>2, h = tid&3;
      float s = 0.f;
      for(int c=0;c<HIDD;c++) s += We1[f*HH + h*HIDD + c] * ae1[h*HIDD + c];
      v1[f*4+h] = s;
    } else if(tid < FE*NHEAD + FE){
      int f = tid - FE*NHEAD;
      float s = 0.f;
      for(int c=0;c<HIDD;c++) s += We2[f*HIDD + c] * ae2[c];
      v2[f] = s;
    }
  }
}

// int4-vectorized scan (was stride-80B scalar loads)
__global__ void scan_k(const int* __restrict__ cnt, int* __restrict__ rowptr){
  __shared__ int sums[1024];
  int tid = threadIdx.x;
  const int per = 20;   // 5 int4
  int base = tid*per;
  int v[20];
  if(base + per <= NN){
    #pragma unroll
    for(int q=0;q<5;q++) *(int4*)&v[q*4] = *(const int4*)&cnt[base + q*4];
  } else {
    for(int i=0;i<per;i++) v[i] = (base+i<NN)? cnt[base+i] : 0;
  }
  int s = 0;
  #pragma unroll
  for(int i=0;i<per;i++) s += v[i];
  sums[tid] = s; __syncthreads();
  for(int off=1; off<1024; off<<=1){
    int t = (tid>=off)? sums[tid-off] : 0;
    __syncthreads();
    sums[tid] += t;
    __syncthreads();
  }
  int run = (tid==0)? 0 : sums[tid-1];
  int rp[20];
  #pragma unroll
  for(int i=0;i<per;i++){ rp[i] = run; run += v[i]; }
  if(base + per <= NN){
    #pragma unroll
    for(int q=0;q<5;q++) *(int4*)&rowptr[base + q*4] = *(const int4*)&rp[q*4];
  } else {
    for(int i=0;i<per;i++) if(base+i<=NN) rowptr[base+i] = rp[i];
  }
  if(base == NN) rowptr[NN] = rp[0];
  if(tid == 1023 && base + per == NN) rowptr[NN] = run;
  if(tid == 1000) rowptr[NN] = rp[0];   // base=20000 exactly for NN=20000
}

// ---------------- fused csr_fill | gemm1(+attn) ----------------
__global__ __launch_bounds__(256) void csr_gemm1(
    const int* __restrict__ ei, const float* __restrict__ ea,
    const float* __restrict__ v1, const float* __restrict__ v2,
    const int* __restrict__ rowptr, int* __restrict__ fcnt,
    int* __restrict__ csrc, float* __restrict__ cae1, float* __restrict__ cae2,
    const ushort_t* __restrict__ A, const ushort_t* __restrict__ Bt,
    ushort_t* __restrict__ C, int M,
    const float* __restrict__ as1, const float* __restrict__ ad1,
    float* __restrict__ s1n, float* __restrict__ d1n){
  __shared__ ushort_t As[128*32];
  __shared__ ushort_t Bs[128*32];
  __shared__ float sred[2][128], dred[2][128];
  __shared__ float sv1[FE*NHEAD];
  __shared__ float sv2[FE];
  int tid = threadIdx.x;
  int b = blockIdx.x;
  if(b < 1250){
    if(tid < FE*NHEAD) sv1[tid] = v1[tid];
    if(tid < FE)       sv2[tid] = v2[tid];
    __syncthreads();
    int e = b*256 + tid;
    int a = ei[e], bb = ei[EE+e];
    const float4* er4 = (const float4*)(ea + (long)e*FE);
    float a0=0,a1=0,a2=0,a3=0,ab=0;
    #pragma unroll
    for(int f4=0; f4<FE/4; f4++){
      float4 t = er4[f4];
      float tv[4] = {t.x, t.y, t.z, t.w};
      #pragma unroll
      for(int c=0;c<4;c++){
        int f = f4*4+c;
        float t1 = tv[c];
        a0 += t1*sv1[f*4+0]; a1 += t1*sv1[f*4+1]; a2 += t1*sv1[f*4+2]; a3 += t1*sv1[f*4+3];
        ab += t1*sv2[f];
      }
    }
    float4 c4; c4.x=a0; c4.y=a1; c4.z=a2; c4.w=a3;
    int pos = rowptr[bb] + atomicAdd(&fcnt[bb], 1);    // fwd
    csrc[pos] = a;
    *(float4*)(cae1 + (size_t)pos*4) = c4;
    cae2[pos] = ab;
    pos = rowptr[a] + atomicAdd(&fcnt[a], 1);          // rev
    csrc[pos] = bb;
    *(float4*)(cae1 + (size_t)pos*4) = c4;
    cae2[pos] = ab;
    return;
  }
  int g = b - 1250;
  int head = g & 3;
  int m0 = (g>>2)*128, n0 = head*128;
  int w = tid>>6, lane = tid&63;
  int qr = (w>>1)*64, qc = (w&1)*64;
  int lrow = lane&15, koff = (lane>>4)*8;
  f32x4 acc[4][4] = {};
  for(int k0=0; k0<FIN; k0+=32){
    #pragma unroll
    for(int rep=0;rep<2;rep++){
      int segid = tid + rep*256;
      int row = segid>>2, off = (segid&3)*8;
      int gr = m0 + row;
      int4 va = (gr<M) ? *(const int4*)(A + (long)gr*FIN + k0 + off) : int4{0,0,0,0};
      *(int4*)&As[row*32 + off] = va;
      int4 vb = *(const int4*)(Bt + (long)(n0+row)*FIN + k0 + off);
      *(int4*)&Bs[row*32 + off] = vb;
    }
    __syncthreads();
    frag8 af[4], bfr[4];
    #pragma unroll
    for(int i=0;i<4;i++) af[i]  = *(const frag8*)&As[(qr + i*16 + lrow)*32 + koff];
    #pragma unroll
    for(int j=0;j<4;j++) bfr[j] = *(const frag8*)&Bs[(qc + j*16 + lrow)*32 + koff];
    #pragma unroll
    for(int i=0;i<4;i++)
      #pragma unroll
      for(int j=0;j<4;j++)
        acc[i][j] = __builtin_amdgcn_mfma_f32_16x16x32_bf16(af[i], bfr[j], acc[i][j], 0,0,0);
    __syncthreads();
  }
  #pragma unroll
  for(int i=0;i<4;i++)
    #pragma unroll
    for(int j=0;j<4;j++)
      #pragma unroll
      for(int r=0;r<4;r++){
        int row = m0 + qr + i*16 + (lane>>4)*4 + r;
        int col = n0 + qc + j*16 + (lane&15);
        if(row<M) C[(long)row*HH + col] = f2bf(acc[i][j][r]);
      }
  float a_s[4], a_d[4];
  #pragma unroll
  for(int j=0;j<4;j++){
    a_s[j] = as1[head*HIDD + qc + j*16 + (lane&15)];
    a_d[j] = ad1[head*HIDD + qc + j*16 + (lane&15)];
  }
  #pragma unroll
  for(int i=0;i<4;i++)
    #pragma unroll
    for(int r=0;r<4;r++){
      float sp = acc[i][0][r]*a_s[0] + acc[i][1][r]*a_s[1] + acc[i][2][r]*a_s[2] + acc[i][3][r]*a_s[3];
      float dp = acc[i][0][r]*a_d[0] + acc[i][1][r]*a_d[1] + acc[i][2][r]*a_d[2] + acc[i][3][r]*a_d[3];
      #pragma unroll
      for(int o=1;o<=8;o<<=1){ sp += __shfl_xor(sp,o,64); dp += __shfl_xor(dp,o,64); }
      if((lane&15)==0){
        int rl = qr + i*16 + (lane>>4)*4 + r;
        sred[w&1][rl] = sp;
        dred[w&1][rl] = dp;
      }
    }
  __syncthreads();
  if(tid < 128){
    int gr = m0 + tid;
    if(gr < M){
      s1n[gr*4 + head] = sred[0][tid] + sred[1][tid];
      d1n[gr*4 + head] = dred[0][tid] + dred[1][tid];
    }
  }
}

// ---------------- gemm64 (+fused node_attn2) ----------------
__global__ __launch_bounds__(256) void gemm64_attn(const ushort_t* __restrict__ A, const ushort_t* __restrict__ Bt,
                                                   ushort_t* __restrict__ C, int M,
                                                   const float* __restrict__ as2, const float* __restrict__ ad2,
                                                   float* __restrict__ s2n, float* __restrict__ d2n){
  __shared__ ushort_t As[64*32];
  __shared__ ushort_t Bs[128*32];
  __shared__ float sred[4][64], dred[4][64];
  int tid = threadIdx.x;
  int m0 = blockIdx.y*64;
  int w = tid>>6, lane = tid&63;
  int qc = w*32;
  int lrow = lane&15, koff = (lane>>4)*8;
  f32x4 acc[4][2] = {};
  for(int k0=0; k0<HH; k0+=32){
    {
      int row = tid>>2, off = (tid&3)*8;
      int gr = m0 + row;
      int4 va = (gr<M) ? *(const int4*)(A + (long)gr*HH + k0 + off) : int4{0,0,0,0};
      *(int4*)&As[row*32 + off] = va;
    }
    #pragma unroll
    for(int rep=0;rep<2;rep++){
      int segid = tid + rep*256;
      int row = segid>>2, off = (segid&3)*8;
      int4 vb = *(const int4*)(Bt + (long)row*HH + k0 + off);
      *(int4*)&Bs[row*32 + off] = vb;
    }
    __syncthreads();
    frag8 af[4], bfr[2];
    #pragma unroll
    for(int i=0;i<4;i++) af[i]  = *(const frag8*)&As[(i*16 + lrow)*32 + koff];
    #pragma unroll
    for(int j=0;j<2;j++) bfr[j] = *(const frag8*)&Bs[(qc + j*16 + lrow)*32 + koff];
    #pragma unroll
    for(int i=0;i<4;i++)
      #pragma unroll
      for(int j=0;j<2;j++)
        acc[i][j] = __builtin_amdgcn_mfma_f32_16x16x32_bf16(af[i], bfr[j], acc[i][j], 0,0,0);
    __syncthreads();
  }
  #pragma unroll
  for(int i=0;i<4;i++)
    #pragma unroll
    for(int j=0;j<2;j++)
      #pragma unroll
      for(int r=0;r<4;r++){
        int row = m0 + i*16 + (lane>>4)*4 + r;
        int col = qc + j*16 + (lane&15);
        if(row<M) C[(long)row*HIDD + col] = f2bf(acc[i][j][r]);
      }
  float a_s[2], a_d[2];
  #pragma unroll
  for(int j=0;j<2;j++){
    a_s[j] = as2[qc + j*16 + (lane&15)];
    a_d[j] = ad2[qc + j*16 + (lane&15)];
  }
  #pragma unroll
  for(int i=0;i<4;i++)
    #pragma unroll
    for(int r=0;r<4;r++){
      float sp = acc[i][0][r]*a_s[0] + acc[i][1][r]*a_s[1];
      float dp = acc[i][0][r]*a_d[0] + acc[i][1][r]*a_d[1];
      #pragma unroll
      for(int o=1;o<=8;o<<=1){ sp += __shfl_xor(sp,o,64); dp += __shfl_xor(dp,o,64); }
      if((lane&15)==0){
        int rl = i*16 + (lane>>4)*4 + r;
        sred[w][rl] = sp;
        dred[w][rl] = dp;
      }
    }
  __syncthreads();
  if(tid < 64){
    int gr = m0 + tid;
    if(gr < M){
      s2n[gr] = sred[0][tid]+sred[1][tid]+sred[2][tid]+sred[3][tid];
      d2n[gr] = dred[0][tid]+dred[1][tid]+dred[2][tid]+dred[3][tid];
    }
  }
}

// ---------------- agg1: 2 waves/node with DISJOINT channel halves ----------------
// Logit pass split by edge halves (interleaved 16-blocks), partial (m,ss) merged in LDS;
// staged logits converted once to normalized weights; each wave gathers its 256 channels.
__global__ __launch_bounds__(256) void agg1(const ushort_t* __restrict__ h1b, const int* __restrict__ rowptr,
                     const int* __restrict__ csrc,
                     const float* __restrict__ s1n, const float* __restrict__ d1n,
                     const float* __restrict__ cae1,
                     const float* __restrict__ b1, ushort_t* __restrict__ out1b){
  __shared__ float stw[2][CAP*4];     // logits -> normalized weights
  __shared__ int   sidx[2][CAP];
  __shared__ float pm[2][2][4], ps[2][2][4];
  int tid = threadIdx.x;
  int nodeLoc = tid>>7;               // 0..1 (2 nodes/block)
  int wv2 = (tid>>6)&1;               // channel-half / edge-half index
  int lane = tid&63;
  int n = blockIdx.x*2 + nodeLoc;
  int beg = rowptr[n], end = rowptr[n+1];
  int deg = end - beg;
  int h12 = lane&3;
  float dh = d1n[n*4 + h12];
  // logit pass over this wave's edge half (interleaved blocks of 16)
  float m = -1e30f, ss = 0.f;
  for(int base=beg + wv2*16; base<end; base+=32){
    int e = base + (lane>>2);
    if(e<end){
      int s = csrc[e];
      float t = s1n[s*4 + h12] + dh + cae1[e*4 + h12];
      t = t>0.f? t : 0.2f*t;
      int j = e - beg;
      if(j < CAP){
        stw[nodeLoc][j*4 + h12] = t;
        if(h12==0) sidx[nodeLoc][j] = s;
      }
      float nm = fmaxf(m, t);
      ss = ss*__expf(m-nm) + __expf(t-nm);
      m = nm;
    }
  }
  #pragma unroll
  for(int o=4;o<=32;o<<=1){
    float mo = __shfl_xor(m, o, 64), so = __shfl_xor(ss, o, 64);
    float nm = fmaxf(m, mo);
    ss = ss*__expf(m-nm) + so*__expf(mo-nm);
    m = nm;
  }
  if(lane<4){ pm[nodeLoc][wv2][lane] = m; ps[nodeLoc][wv2][lane] = ss; }
  __syncthreads();
  // merge halves; all 4 heads per thread
  float m4[4], i4[4];
  #pragma unroll
  for(int h=0;h<4;h++){
    float mA = pm[nodeLoc][0][h], mB = pm[nodeLoc][1][h];
    float sA = ps[nodeLoc][0][h], sB = ps[nodeLoc][1][h];
    float mf = fmaxf(mA, mB);
    float sf = sA*__expf(mA-mf) + sB*__expf(mB-mf);
    m4[h] = mf; i4[h] = sf>0.f ? 1.f/sf : 0.f;
  }
  // convert staged logits -> normalized weights (flat index f == tid mod 4 keeps head fixed)
  int capn = deg < CAP ? deg : CAP;
  int tln = tid & 127;
  float mh = m4[h12], ih = i4[h12];   // tln&3 == lane&3 == h12
  for(int f=tln; f<capn*4; f+=128) stw[nodeLoc][f] = __expf(stw[nodeLoc][f]-mh)*ih;
  __syncthreads();
  // gather: this wave owns channels [wv2*256, wv2*256+256); lane -> 4 channels (8B)
  int hq = wv2*2 + (lane>>5);
  long cOff = (long)(wv2*256 + lane*4);
  float acc0=0.f, acc1=0.f, acc2=0.f, acc3=0.f;
  int j = 0;
  for(; j+3<capn; j+=4){
    int s0 = sidx[nodeLoc][j],   s1 = sidx[nodeLoc][j+1];
    int s2 = sidx[nodeLoc][j+2], s3 = sidx[nodeLoc][j+3];
    float w0 = stw[nodeLoc][(j  )*4 + hq];
    float w1 = stw[nodeLoc][(j+1)*4 + hq];
    float w2 = stw[nodeLoc][(j+2)*4 + hq];
    float w3 = stw[nodeLoc][(j+3)*4 + hq];
    uint2 v0 = *(const uint2*)(h1b + (long)s0*HH + cOff);
    uint2 v1 = *(const uint2*)(h1b + (long)s1*HH + cOff);
    uint2 v2 = *(const uint2*)(h1b + (long)s2*HH + cOff);
    uint2 v3 = *(const uint2*)(h1b + (long)s3*HH + cOff);
    acc0 += w0*lo_of(v0.x) + w1*lo_of(v1.x) + w2*lo_of(v2.x) + w3*lo_of(v3.x);
    acc1 += w0*hi_of(v0.x) + w1*hi_of(v1.x) + w2*hi_of(v2.x) + w3*hi_of(v3.x);
    acc2 += w0*lo_of(v0.y) + w1*lo_of(v1.y) + w2*lo_of(v2.y) + w3*lo_of(v3.y);
    acc3 += w0*hi_of(v0.y) + w1*hi_of(v1.y) + w2*hi_of(v2.y) + w3*hi_of(v3.y);
  }
  for(; j<capn; j++){
    int s0 = sidx[nodeLoc][j];
    float w0 = stw[nodeLoc][j*4 + hq];
    uint2 v0 = *(const uint2*)(h1b + (long)s0*HH + cOff);
    acc0 += w0*lo_of(v0.x); acc1 += w0*hi_of(v0.x);
    acc2 += w0*lo_of(v0.y); acc3 += w0*hi_of(v0.y);
  }
  for(; j<deg; j++){      // overflow fallback (never for this graph)
    int e = beg + j;
    int s0 = csrc[e];
    float t = s1n[s0*4 + hq] + d1n[n*4 + hq] + cae1[e*4 + hq];
    t = t>0.f? t : 0.2f*t;
    float w0 = __expf(t - m4[hq])*i4[hq];
    uint2 v0 = *(const uint2*)(h1b + (long)s0*HH + cOff);
    acc0 += w0*lo_of(v0.x); acc1 += w0*hi_of(v0.x);
    acc2 += w0*lo_of(v0.y); acc3 += w0*hi_of(v0.y);
  }
  float4 bb = *(const float4*)(b1 + cOff);
  float o0 = acc0 + bb.x, o1 = acc1 + bb.y, o2 = acc2 + bb.z, o3 = acc3 + bb.w;
  o0 = o0>0.f? o0 : __expf(o0)-1.f;
  o1 = o1>0.f? o1 : __expf(o1)-1.f;
  o2 = o2>0.f? o2 : __expf(o2)-1.f;
  o3 = o3>0.f? o3 : __expf(o3)-1.f;
  uint2 pk;
  pk.x = (unsigned)f2bf(o0) | ((unsigned)f2bf(o1)<<16);
  pk.y = (unsigned)f2bf(o2) | ((unsigned)f2bf(o3)<<16);
  *(uint2*)(out1b + (long)n*HH + cOff) = pk;
}

// ---------------- agg2: LDS-staged softmax + weight precompute ----------------
__global__ __launch_bounds__(256) void agg2(const ushort_t* __restrict__ h2b, const int* __restrict__ rowptr,
                     const int* __restrict__ csrc,
                     const float* __restrict__ s2n, const float* __restrict__ d2n,
                     const float* __restrict__ cae2,
                     const float* __restrict__ b2, float* __restrict__ out2){
  __shared__ float stl[4][CAP];
  __shared__ int   sid[4][CAP];
  int tid = threadIdx.x;
  int wv = tid>>6, lane = tid&63;
  int n = blockIdx.x*4 + wv;
  int beg = rowptr[n], end = rowptr[n+1];
  int deg = end - beg;
  float dn = d2n[n];
  float m = -1e30f, ss = 0.f;
  for(int e=beg+lane; e<end; e+=64){
    int s = csrc[e];
    float t = s2n[s] + dn + cae2[e];
    t = t>0.f? t : 0.2f*t;
    int j = e - beg;
    if(j < CAP){ stl[wv][j] = t; sid[wv][j] = s; }
    float nm = fmaxf(m, t);
    ss = ss*__expf(m-nm) + __expf(t-nm);
    m = nm;
  }
  #pragma unroll
  for(int o=1;o<=32;o<<=1){
    float mo = __shfl_xor(m, o, 64), so = __shfl_xor(ss, o, 64);
    float nm = fmaxf(m, mo);
    ss = ss*__expf(m-nm) + so*__expf(mo-nm);
    m = nm;
  }
  float inv = ss>0.f ? 1.f/ss : 0.f;
  int capn = deg < CAP ? deg : CAP;
  // precompute normalized weights (1 exp per edge total, was 64x redundant)
  for(int j=lane; j<capn; j+=64) stl[wv][j] = __expf(stl[wv][j]-m)*inv;
  float a0=0.f, a1=0.f;
  int j = 0;
  for(; j+3<capn; j+=4){
    int s0 = sid[wv][j], s1 = sid[wv][j+1], s2 = sid[wv][j+2], s3 = sid[wv][j+3];
    float w0 = stl[wv][j], w1 = stl[wv][j+1], w2 = stl[wv][j+2], w3 = stl[wv][j+3];
    unsigned v0 = *(const unsigned*)(h2b + (long)s0*HIDD + 2*lane);
    unsigned v1 = *(const unsigned*)(h2b + (long)s1*HIDD + 2*lane);
    unsigned v2 = *(const unsigned*)(h2b + (long)s2*HIDD + 2*lane);
    unsigned v3 = *(const unsigned*)(h2b + (long)s3*HIDD + 2*lane);
    a0 += w0*lo_of(v0) + w1*lo_of(v1) + w2*lo_of(v2) + w3*lo_of(v3);
    a1 += w0*hi_of(v0) + w1*hi_of(v1) + w2*hi_of(v2) + w3*hi_of(v3);
  }
  for(; j<capn; j++){
    float w0 = stl[wv][j];
    unsigned v0 = *(const unsigned*)(h2b + (long)sid[wv][j]*HIDD + 2*lane);
    a0 += w0*lo_of(v0); a1 += w0*hi_of(v0);
  }
  for(; j<deg; j++){
    int e = beg + j;
    int s0 = csrc[e];
    float t = s2n[s0] + dn + cae2[e];
    t = t>0.f? t : 0.2f*t;
    float w0 = __expf(t-m)*inv;
    unsigned v0 = *(const unsigned*)(h2b + (long)s0*HIDD + 2*lane);
    a0 += w0*lo_of(v0); a1 += w0*hi_of(v0);
  }
  float o0 = a0 + b2[2*lane];
  float o1 = a1 + b2[2*lane+1];
  float2 pk;
  pk.x = o0>0.f? o0 : __expf(o0)-1.f;
  pk.y = o1>0.f? o1 : __expf(o1)-1.f;
  *(float2*)(out2 + (long)n*HIDD + 2*lane) = pk;
}

// ---------------- fused projection head ----------------
__global__ __launch_bounds__(256) void proj_fused(const float* __restrict__ A,
    const ushort_t* __restrict__ P1th, const ushort_t* __restrict__ P1tl,
    const ushort_t* __restrict__ P2th, const ushort_t* __restrict__ P2tl,
    const float* __restrict__ pb1, const float* __restrict__ pra,
    const float* __restrict__ pb2, float* __restrict__ OUT, int M,
    float* __restrict__ gbuf){
  __shared__ ushort_t Ah[64*AW], Al[64*AW];
  __shared__ ushort_t Bh[128*32], Bl[128*32];
  int tid = threadIdx.x;
  int m0 = blockIdx.x*64;
  int w = tid>>6, lane = tid&63;
  int qc = w*32;
  int lrow = lane&15, koff2 = (lane>>4)*8;
  f32x4 acc[4][2] = {};
  {
    int row = tid>>2, cb = (tid&3)*8;
    int gr = m0 + row;
    for(int c0=0;c0<HIDD;c0+=32){
      float4 u0{0,0,0,0}, u1{0,0,0,0};
      if(gr<M){
        u0 = *(const float4*)(A + (long)gr*HIDD + c0 + cb);
        u1 = *(const float4*)(A + (long)gr*HIDD + c0 + cb + 4);
      }
      float vv[8] = {u0.x,u0.y,u0.z,u0.w,u1.x,u1.y,u1.z,u1.w};
      unsigned ph[4], pl[4];
      #pragma unroll
      for(int c=0;c<4;c++){
        ushort_t h0 = f2bf(vv[2*c]),   l0 = f2bf(vv[2*c]   - bf2f(h0));
        ushort_t h1 = f2bf(vv[2*c+1]), l1 = f2bf(vv[2*c+1] - bf2f(h1));
        ph[c] = (unsigned)h0 | ((unsigned)h1<<16);
        pl[c] = (unsigned)l0 | ((unsigned)l1<<16);
      }
      *(uint4*)&Ah[row*AW + c0 + cb] = *(uint4*)ph;
      *(uint4*)&Al[row*AW + c0 + cb] = *(uint4*)pl;
    }
  }
  __syncthreads();
  for(int k0=0;k0<HIDD;k0+=32){
    #pragma unroll
    for(int rep=0;rep<2;rep++){
      int segid = tid + rep*256;
      int row = segid>>2, off = (segid&3)*8;
      *(int4*)&Bh[row*32 + off] = *(const int4*)(P1th + (long)row*HIDD + k0 + off);
      *(int4*)&Bl[row*32 + off] = *(const int4*)(P1tl + (long)row*HIDD + k0 + off);
    }
    __syncthreads();
    frag8 afh[4], afl[4], bfh[2], bfl[2];
    #pragma unroll
    for(int i=0;i<4;i++){
      afh[i] = *(const frag8*)&Ah[(i*16 + lrow)*AW + k0 + koff2];
      afl[i] = *(const frag8*)&Al[(i*16 + lrow)*AW + k0 + koff2];
    }
    #pragma unroll
    for(int j=0;j<2;j++){
      bfh[j] = *(const frag8*)&Bh[(qc + j*16 + lrow)*32 + koff2];
      bfl[j] = *(const frag8*)&Bl[(qc + j*16 + lrow)*32 + koff2];
    }
    #pragma unroll
    for(int i=0;i<4;i++)
      #pragma unroll
      for(int j=0;j<2;j++){
        acc[i][j] = __builtin_amdgcn_mfma_f32_16x16x32_bf16(afh[i], bfh[j], acc[i][j], 0,0,0);
        acc[i][j] = __builtin_amdgcn_mfma_f32_16x16x32_bf16(afh[i], bfl[j], acc[i][j], 0,0,0);
        acc[i][j] = __builtin_amdgcn_mfma_f32_16x16x32_bf16(afl[i], bfh[j], acc[i][j], 0,0,0);
      }
    __syncthreads();
  }
  float ap = pra[0];
  #pragma unroll
  for(int i=0;i<4;i++)
    #pragma unroll
    for(int j=0;j<2;j++)
      #pragma unroll
      for(int r=0;r<4;r++){
        int row = i*16 + (lane>>4)*4 + r;
        int col = qc + j*16 + (lane&15);
        float v = acc[i][j][r] + pb1[col];
        v = v>0.f? v : ap*v;
        ushort_t h = f2bf(v);
        Ah[row*AW + col] = h;
        Al[row*AW + col] = f2bf(v - bf2f(h));
        acc[i][j][r] = 0.f;
      }
  __syncthreads();
  for(int k0=0;k0<HIDD;k0+=32){
    #pragma unroll
    for(int rep=0;rep<2;rep++){
      int segid = tid + rep*256;
      int row = segid>>2, off = (segid&3)*8;
      *(int4*)&Bh[row*32 + off] = *(const int4*)(P2th + (long)row*HIDD + k0 + off);
      *(int4*)&Bl[row*32 + off] = *(const int4*)(P2tl + (long)row*HIDD + k0 + off);
    }
    __syncthreads();
    frag8 afh[4], afl[4], bfh[2], bfl[2];
    #pragma unroll
    for(int i=0;i<4;i++){
      afh[i] = *(const frag8*)&Ah[(i*16 + lrow)*AW + k0 + koff2];
      afl[i] = *(const frag8*)&Al[(i*16 + lrow)*AW + k0 + koff2];
    }
    #pragma unroll
    for(int j=0;j<2;j++){
      bfh[j] = *(const frag8*)&Bh[(qc + j*16 + lrow)*32 + koff2];
      bfl[j] = *(const frag8*)&Bl[(qc + j*16 + lrow)*32 + koff2];
    }
    #pragma unroll
    for(int i=0;i<4;i++)
      #pragma unroll
      for(int j=0;j<2;j++){
        acc[i][j] = __builtin_amdgcn_mfma_f32_16x16x32_bf16(afh[i], bfh[j], acc[i][j], 0,0,0);
        acc[i][j] = __builtin_amdgcn_mfma_f32_16x16x32_bf16(afh[i], bfl[j], acc[i][j], 0,0,0);
        acc[i][j] = __builtin_amdgcn_mfma_f32_16x16x32_bf16(afl[i], bfh[j], acc[i][j], 0,0,0);
      }
    __syncthreads();
  }
  float cs[2] = {0.f, 0.f};
  #pragma unroll
  for(int i=0;i<4;i++)
    #pragma unroll
    for(int j=0;j<2;j++)
      #pragma unroll
      for(int r=0;r<4;r++){
        int rowg = m0 + i*16 + (lane>>4)*4 + r;
        int col = qc + j*16 + (lane&15);
        if(rowg<M){
          float v = acc[i][j][r] + pb2[col];
          OUT[(long)rowg*HIDD + col] = v;
          cs[j] += v;
        }
      }
  #pragma unroll
  for(int j=0;j<2;j++){
    cs[j] += __shfl_xor(cs[j],16,64);
    cs[j] += __shfl_xor(cs[j],32,64);
    if((lane>>4)==0) atomicAdd(&gbuf[qc + j*16 + (lane&15)], cs[j]);
  }
}

__global__ void sigmoid_g(const float* __restrict__ gbuf, float* __restrict__ gout){
  int c = threadIdx.x;
  float m = gbuf[c] * (1.0f/NN);
  gout[c] = 1.f/(1.f+__expf(-m));
}

// ---------------- launch ----------------

extern "C" void kernel_launch(void* const* d_in, const int* in_sizes, int n_in,
                              void* d_out, int out_size, void* d_ws, size_t ws_size,
                              hipStream_t stream){
  const float* x    = (const float*)d_in[0];
  const int*   ei   = (const int*)  d_in[1];
  const float* ea   = (const float*)d_in[2];
  const float* W1   = (const float*)d_in[3];
  const float* We1  = (const float*)d_in[4];
  const float* as1  = (const float*)d_in[5];
  const float* ad1  = (const float*)d_in[6];
  const float* ae1  = (const float*)d_in[7];
  const float* b1   = (const float*)d_in[8];
  const float* W2   = (const float*)d_in[9];
  const float* We2  = (const float*)d_in[10];
  const float* as2  = (const float*)d_in[11];
  const float* ad2  = (const float*)d_in[12];
  const float* ae2  = (const float*)d_in[13];
  const float* b2   = (const float*)d_in[14];
  const float* P1   = (const float*)d_in[15];
  const float* pb1  = (const float*)d_in[16];
  const float* pra  = (const float*)d_in[17];
  const float* P2   = (const float*)d_in[18];
  const float* pb2  = (const float*)d_in[19];
  float* out = (float*)d_out;

  char* wsp = (char*)d_ws;
  size_t off = 0;
  auto alloc = [&](size_t bytes)->char*{
    char* p = wsp + off;
    off += (bytes + 255) & ~(size_t)255;
    return p;
  };
  ushort_t* h1b  = (ushort_t*)alloc(sizeof(ushort_t)*(size_t)NN*HH);
  ushort_t* out1b= (ushort_t*)alloc(sizeof(ushort_t)*(size_t)NN*HH);
  ushort_t* h2b  = (ushort_t*)alloc(sizeof(ushort_t)*(size_t)NN*HIDD);
  float*    out2 = (float*)  alloc(sizeof(float)*(size_t)NN*HIDD);
  ushort_t* xb   = (ushort_t*)alloc(sizeof(ushort_t)*(size_t)NN*FIN);
  ushort_t* W1t  = (ushort_t*)alloc(sizeof(ushort_t)*(size_t)HH*FIN);
  ushort_t* W2t  = (ushort_t*)alloc(sizeof(ushort_t)*(size_t)HIDD*HH);
  ushort_t* P1th = (ushort_t*)alloc(sizeof(ushort_t)*(size_t)HIDD*HIDD);
  ushort_t* P1tl = (ushort_t*)alloc(sizeof(ushort_t)*(size_t)HIDD*HIDD);
  ushort_t* P2th = (ushort_t*)alloc(sizeof(ushort_t)*(size_t)HIDD*HIDD);
  ushort_t* P2tl = (ushort_t*)alloc(sizeof(ushort_t)*(size_t)HIDD*HIDD);
  float* s1n   = (float*)alloc(sizeof(float)*NN*NHEAD);
  float* d1n   = (float*)alloc(sizeof(float)*NN*NHEAD);
  float* s2n   = (float*)alloc(sizeof(float)*NN);
  float* d2n   = (float*)alloc(sizeof(float)*NN);
  float* v1    = (float*)alloc(sizeof(float)*FE*NHEAD);
  float* v2    = (float*)alloc(sizeof(float)*FE);
  float* cae1  = (float*)alloc(sizeof(float)*(size_t)E2*NHEAD);
  float* cae2  = (float*)alloc(sizeof(float)*(size_t)E2);
  int*   rowptr= (int*)  alloc(sizeof(int)*(NN+1));
  int*   csrc  = (int*)  alloc(sizeof(int)*(size_t)E2);
  // zero-init trio: adjacent for one memset
  int*   cnt   = (int*)  alloc(sizeof(int)*NN);
  int*   fcnt  = (int*)  alloc(sizeof(int)*NN);
  float* gbuf  = (float*)alloc(sizeof(float)*HIDD);

  hipMemsetAsync(cnt, 0, 80128 + 80128 + 512, stream);

  prep     <<<8397, 256, 0, stream>>>(ei, cnt, x, xb, W1, W1t, W2, W2t,
                                      P1, P1th, P1tl, P2, P2th, P2tl,
                                      We1, ae1, We2, ae2, v1, v2);
  scan_k   <<<1, 1024, 0, stream>>>(cnt, rowptr);
  csr_gemm1<<<1250 + 628, 256, 0, stream>>>(ei, ea, v1, v2, rowptr, fcnt, csrc, cae1, cae2,
                                            xb, W1t, h1b, NN, as1, ad1, s1n, d1n);
  agg1     <<<NN/2, 256, 0, stream>>>(h1b, rowptr, csrc, s1n, d1n, cae1, b1, out1b);
  gemm64_attn<<<dim3(1, (NN+63)/64), 256, 0, stream>>>(out1b, W2t, h2b, NN, as2, ad2, s2n, d2n);
  agg2     <<<NN/4, 256, 0, stream>>>(h2b, rowptr, csrc, s2n, d2n, cae2, b2, out2);
  proj_fused<<<(NN+63)/64, 256, 0, stream>>>(out2, P1th, P1tl, P2th, P2tl,
                                             pb1, pra, pb2, out, NN, gbuf);
  sigmoid_g<<<1, 128, 0, stream>>>(gbuf, out + (size_t)NN*HIDD);
}